// Round 1
// baseline (2503.141 us; speedup 1.0000x reference)
//
#include <hip/hip_runtime.h>
#include <hip/hip_bf16.h>
#include <math.h>

#define BGR 16
#define NPG 2048
#define HD  128
#define KNN 8
#define NTOT (BGR*NPG)   // 32768

// ---------------- encoder: h = x @ W_enc + b_enc  (no relu) ----------------
__global__ __launch_bounds__(256) void enc_kernel(const float* __restrict__ x,
                                                  const float* __restrict__ W,
                                                  const float* __restrict__ bias,
                                                  float* __restrict__ hout)
{
    int gid = blockIdx.x * 256 + threadIdx.x;      // over NTOT*HD
    int n = gid >> 7, o = gid & 127;
    float s = bias[o];
#pragma unroll
    for (int f = 0; f < 4; ++f)
        s = fmaf(x[n*4 + f], W[f*128 + o], s);
    hout[gid] = s;
}

// ---------------- per-node squared norms ----------------
__global__ __launch_bounds__(256) void sq_kernel(const float* __restrict__ h,
                                                 float* __restrict__ sqg)
{
    int wid  = (blockIdx.x * 256 + threadIdx.x) >> 6;   // wave id = node
    int lane = threadIdx.x & 63;
    const float* hp = h + (size_t)wid * HD;
    float v0 = hp[lane], v1 = hp[lane + 64];
    float s = fmaf(v0, v0, v1 * v1);
#pragma unroll
    for (int off = 32; off >= 1; off >>= 1)
        s += __shfl_xor(s, off);
    if (lane == 0) sqg[wid] = s;
}

// ---------------- kNN: per graph, top-8 smallest sq-distances ----------------
// 64 rows per block, col tiles of 64, 4x4 register blocking.
__global__ __launch_bounds__(256) void knn_kernel(const float* __restrict__ h,
                                                  const float* __restrict__ sqg,
                                                  int* __restrict__ nbr)
{
    __shared__ float xi[64*129];
    __shared__ float xj[64*129];
    __shared__ float sqi[64];
    __shared__ float sqj[64];

    const int t    = threadIdx.x;
    const int b    = blockIdx.x >> 5;          // 32 row-blocks per graph
    const int row0 = (blockIdx.x & 31) * 64;
    const int gbase = b * NPG;
    const float* hb = h + (size_t)gbase * HD;

    // load xi tile (64 rows x 128)
#pragma unroll
    for (int q = 0; q < 8; ++q) {
        int fi = t + 256*q;                    // float4 index 0..2047
        int r = fi >> 5, p = fi & 31;
        float4 v = *(const float4*)(hb + (size_t)(row0 + r)*HD + p*4);
        float* dst = &xi[r*129 + p*4];
        dst[0]=v.x; dst[1]=v.y; dst[2]=v.z; dst[3]=v.w;
    }
    if (t < 64) sqi[t] = sqg[gbase + row0 + t];

    const int rg = t >> 4;   // rows rg*4 .. rg*4+3
    const int cg = t & 15;   // cols cg*4 .. cg*4+3

    float bd[4][8];
    int   bi[4][8];
#pragma unroll
    for (int r = 0; r < 4; ++r)
#pragma unroll
        for (int s = 0; s < 8; ++s) { bd[r][s] = 3.4e38f; bi[r][s] = 0x7fffffff; }

    for (int jt = 0; jt < 32; ++jt) {
        __syncthreads();                       // previous compute done before overwrite
#pragma unroll
        for (int q = 0; q < 8; ++q) {
            int fi = t + 256*q;
            int r = fi >> 5, p = fi & 31;
            float4 v = *(const float4*)(hb + (size_t)(jt*64 + r)*HD + p*4);
            float* dst = &xj[r*129 + p*4];
            dst[0]=v.x; dst[1]=v.y; dst[2]=v.z; dst[3]=v.w;
        }
        if (t < 64) sqj[t] = sqg[gbase + jt*64 + t];
        __syncthreads();

        float acc[4][4] = {};
        const float* xip = &xi[(rg*4)*129];
        const float* xjp = &xj[(cg*4)*129];
#pragma unroll 4
        for (int d = 0; d < HD; ++d) {
            float a0 = xip[0*129+d], a1 = xip[1*129+d], a2 = xip[2*129+d], a3 = xip[3*129+d];
            float c0 = xjp[0*129+d], c1 = xjp[1*129+d], c2 = xjp[2*129+d], c3 = xjp[3*129+d];
            acc[0][0]=fmaf(a0,c0,acc[0][0]); acc[0][1]=fmaf(a0,c1,acc[0][1]);
            acc[0][2]=fmaf(a0,c2,acc[0][2]); acc[0][3]=fmaf(a0,c3,acc[0][3]);
            acc[1][0]=fmaf(a1,c0,acc[1][0]); acc[1][1]=fmaf(a1,c1,acc[1][1]);
            acc[1][2]=fmaf(a1,c2,acc[1][2]); acc[1][3]=fmaf(a1,c3,acc[1][3]);
            acc[2][0]=fmaf(a2,c0,acc[2][0]); acc[2][1]=fmaf(a2,c1,acc[2][1]);
            acc[2][2]=fmaf(a2,c2,acc[2][2]); acc[2][3]=fmaf(a2,c3,acc[2][3]);
            acc[3][0]=fmaf(a3,c0,acc[3][0]); acc[3][1]=fmaf(a3,c1,acc[3][1]);
            acc[3][2]=fmaf(a3,c2,acc[3][2]); acc[3][3]=fmaf(a3,c3,acc[3][3]);
        }

#pragma unroll
        for (int r = 0; r < 4; ++r) {
            float sir = sqi[rg*4 + r];
#pragma unroll
            for (int c = 0; c < 4; ++c) {
                float dist = sir + sqj[cg*4 + c] - 2.0f*acc[r][c];
                int j = jt*64 + cg*4 + c;
                if (dist < bd[r][7]) {         // rare -> branch ok
#pragma unroll
                    for (int s = 7; s > 0; --s) {
                        bool up   = dist < bd[r][s-1];
                        bool here = (!up) && (dist < bd[r][s]);
                        float nd = up ? bd[r][s-1] : (here ? dist : bd[r][s]);
                        int   ni = up ? bi[r][s-1] : (here ? j    : bi[r][s]);
                        bd[r][s] = nd; bi[r][s] = ni;
                    }
                    if (dist < bd[r][0]) { bd[r][0] = dist; bi[r][0] = j; }
                }
            }
        }
    }

    __syncthreads();
    // dump 16x8 candidates per row, then per-row serial select (stable ties: lower index)
    float* cd = xi;           // [64][128]
    int*   ci = (int*)xj;     // [64][128]
#pragma unroll
    for (int r = 0; r < 4; ++r)
#pragma unroll
        for (int s = 0; s < 8; ++s) {
            cd[(rg*4+r)*128 + cg*8 + s] = bd[r][s];
            ci[(rg*4+r)*128 + cg*8 + s] = bi[r][s];
        }
    __syncthreads();
    if (t < 64) {
        int row = t;
        int* outp = nbr + (size_t)(gbase + row0 + row) * KNN;
        for (int sel = 0; sel < KNN; ++sel) {
            float best = 3.5e38f; int besti = 0x7fffffff; int bestpos = 0;
            for (int c2 = 0; c2 < 128; ++c2) {
                float dv = cd[row*128 + c2];
                int   iv = ci[row*128 + c2];
                if (dv < best || (dv == best && iv < besti)) { best = dv; besti = iv; bestpos = c2; }
            }
            cd[row*128 + bestpos] = 3.5e38f;
            outp[sel] = gbase + besti;         // store GLOBAL node index
        }
    }
}

// ---------------- fused edge-MLP + max-aggregate ----------------
// 8 nodes/block, 64 e-rows of 256 (xi-half shared per node -> phase A once).
template<bool FINAL>
__global__ __launch_bounds__(256) void mlp_kernel(const float* __restrict__ h,
                                                  const int* __restrict__ nbr,
                                                  const float* __restrict__ Wa,
                                                  const float* __restrict__ ba,
                                                  const float* __restrict__ Wb,
                                                  const float* __restrict__ bb,
                                                  float* __restrict__ out)
{
    __shared__ float xi[8*129];
    __shared__ float e2[64*129];   // xj - xi
    __shared__ float h1[64*129];

    const int t = threadIdx.x;
    const int node0 = blockIdx.x * 8;

    // load xi (8 x 128)
    {
        int r = t >> 5, p = t & 31;
        float4 v = *(const float4*)(h + (size_t)(node0 + r)*HD + p*4);
        float* dst = &xi[r*129 + p*4];
        dst[0]=v.x; dst[1]=v.y; dst[2]=v.z; dst[3]=v.w;
    }
    __syncthreads();
    // load e2 = x_j - x_i (64 rows x 128)
    {
        int r = t >> 2, p = t & 3;
        int j = nbr[(size_t)(node0 + (r >> 3))*KNN + (r & 7)];
        const float* src = h + (size_t)j*HD;
        const float* xir = &xi[(r >> 3)*129];
        float* dst = &e2[r*129];
#pragma unroll
        for (int q = 0; q < 8; ++q) {
            int d = p*32 + q*4;
            float4 v = *(const float4*)(src + d);
            dst[d+0]=v.x-xir[d+0]; dst[d+1]=v.y-xir[d+1];
            dst[d+2]=v.z-xir[d+2]; dst[d+3]=v.w-xir[d+3];
        }
    }
    __syncthreads();

    const int rg = t >> 5;   // node 0..7
    const int og = t & 31;   // output cols og*4..og*4+3

    // GEMM1 phase A: xi half (shared across the 8 neighbors)
    float tA[4] = {0.f,0.f,0.f,0.f};
    {
        const float* xir = &xi[rg*129];
#pragma unroll 4
        for (int d = 0; d < 128; ++d) {
            float a = xir[d];
            float4 w = *(const float4*)(Wa + (size_t)d*128 + og*4);
            tA[0]=fmaf(a,w.x,tA[0]); tA[1]=fmaf(a,w.y,tA[1]);
            tA[2]=fmaf(a,w.z,tA[2]); tA[3]=fmaf(a,w.w,tA[3]);
        }
    }
    float acc[8][4];
#pragma unroll
    for (int k = 0; k < 8; ++k)
#pragma unroll
        for (int c = 0; c < 4; ++c) acc[k][c] = tA[c];

    // GEMM1 phase B: (xj - xi) half
    {
        const float* e2p = &e2[(rg*8)*129];
#pragma unroll 2
        for (int d = 0; d < 128; ++d) {
            float4 w = *(const float4*)(Wa + (size_t)(128+d)*128 + og*4);
#pragma unroll
            for (int k = 0; k < 8; ++k) {
                float a = e2p[k*129 + d];
                acc[k][0]=fmaf(a,w.x,acc[k][0]); acc[k][1]=fmaf(a,w.y,acc[k][1]);
                acc[k][2]=fmaf(a,w.z,acc[k][2]); acc[k][3]=fmaf(a,w.w,acc[k][3]);
            }
        }
    }
    // bias + relu -> h1
    {
        float b0 = ba[og*4+0], b1 = ba[og*4+1], b2 = ba[og*4+2], b3 = ba[og*4+3];
#pragma unroll
        for (int k = 0; k < 8; ++k) {
            h1[(rg*8+k)*129 + og*4+0] = fmaxf(acc[k][0]+b0, 0.f);
            h1[(rg*8+k)*129 + og*4+1] = fmaxf(acc[k][1]+b1, 0.f);
            h1[(rg*8+k)*129 + og*4+2] = fmaxf(acc[k][2]+b2, 0.f);
            h1[(rg*8+k)*129 + og*4+3] = fmaxf(acc[k][3]+b3, 0.f);
        }
    }
    __syncthreads();

    if (!FINAL) {
        float acc2[8][4];
#pragma unroll
        for (int k = 0; k < 8; ++k)
#pragma unroll
            for (int c = 0; c < 4; ++c) acc2[k][c] = 0.f;
        const float* h1p = &h1[(rg*8)*129];
#pragma unroll 2
        for (int d = 0; d < 128; ++d) {
            float4 w = *(const float4*)(Wb + (size_t)d*128 + og*4);
#pragma unroll
            for (int k = 0; k < 8; ++k) {
                float a = h1p[k*129 + d];
                acc2[k][0]=fmaf(a,w.x,acc2[k][0]); acc2[k][1]=fmaf(a,w.y,acc2[k][1]);
                acc2[k][2]=fmaf(a,w.z,acc2[k][2]); acc2[k][3]=fmaf(a,w.w,acc2[k][3]);
            }
        }
        float b0 = bb[og*4+0], b1 = bb[og*4+1], b2 = bb[og*4+2], b3 = bb[og*4+3];
        float m0=0.f, m1=0.f, m2=0.f, m3=0.f;   // relu(..)>=0, max over k
#pragma unroll
        for (int k = 0; k < 8; ++k) {
            m0 = fmaxf(m0, acc2[k][0]+b0);
            m1 = fmaxf(m1, acc2[k][1]+b1);
            m2 = fmaxf(m2, acc2[k][2]+b2);
            m3 = fmaxf(m3, acc2[k][3]+b3);
        }
        float* op = out + (size_t)(node0 + rg)*HD + og*4;
        op[0]=m0; op[1]=m1; op[2]=m2; op[3]=m3;
    } else {
        if (t < 64) {
            int r = t;
            float s = 0.f;
            const float* h1p = &h1[r*129];
#pragma unroll 4
            for (int d = 0; d < 128; ++d)
                s = fmaf(h1p[d], Wb[d], s);
            s = fmaxf(s + bb[0], 0.f);
#pragma unroll
            for (int m = 1; m < 8; m <<= 1)
                s = fmaxf(s, __shfl_xor(s, m));
            if ((t & 7) == 0)
                out[node0 + (t >> 3)] = 1.f / (1.f + expf(-s));
        }
    }
}

extern "C" void kernel_launch(void* const* d_in, const int* in_sizes, int n_in,
                              void* d_out, int out_size, void* d_ws, size_t ws_size,
                              hipStream_t stream) {
    const float* x     = (const float*)d_in[0];
    const float* W_enc = (const float*)d_in[3];
    const float* b_enc = (const float*)d_in[4];
    const float* W1a = (const float*)d_in[5];
    const float* b1a = (const float*)d_in[6];
    const float* W1b = (const float*)d_in[7];
    const float* b1b = (const float*)d_in[8];
    const float* W2a = (const float*)d_in[9];
    const float* b2a = (const float*)d_in[10];
    const float* W2b = (const float*)d_in[11];
    const float* b2b = (const float*)d_in[12];
    const float* W5a = (const float*)d_in[13];
    const float* b5a = (const float*)d_in[14];
    const float* W5b = (const float*)d_in[15];
    const float* b5b = (const float*)d_in[16];

    float* h0  = (float*)d_ws;                 // 16 MB
    float* h1  = h0 + (size_t)NTOT*HD;         // 16 MB
    float* sqg = h1 + (size_t)NTOT*HD;         // 128 KB
    int*  idxb = (int*)(sqg + NTOT);           // 1 MB

    enc_kernel<<<NTOT*HD/256, 256, 0, stream>>>(x, W_enc, b_enc, h0);

    // layer 1
    sq_kernel <<<NTOT/4, 256, 0, stream>>>(h0, sqg);
    knn_kernel<<<BGR*32, 256, 0, stream>>>(h0, sqg, idxb);
    mlp_kernel<false><<<NTOT/8, 256, 0, stream>>>(h0, idxb, W1a, b1a, W1b, b1b, h1);

    // layer 2
    sq_kernel <<<NTOT/4, 256, 0, stream>>>(h1, sqg);
    knn_kernel<<<BGR*32, 256, 0, stream>>>(h1, sqg, idxb);
    mlp_kernel<false><<<NTOT/8, 256, 0, stream>>>(h1, idxb, W2a, b2a, W2b, b2b, h0);

    // layer 5 (final)
    sq_kernel <<<NTOT/4, 256, 0, stream>>>(h0, sqg);
    knn_kernel<<<BGR*32, 256, 0, stream>>>(h0, sqg, idxb);
    mlp_kernel<true><<<NTOT/8, 256, 0, stream>>>(h0, idxb, W5a, b5a, W5b, b5b, (float*)d_out);
}

// Round 2
// 2037.608 us; speedup vs baseline: 1.2285x; 1.2285x over previous
//
#include <hip/hip_runtime.h>
#include <hip/hip_bf16.h>
#include <math.h>

#define BGR 16
#define NPG 2048
#define HD  128
#define KNN 8
#define NTOT (BGR*NPG)   // 32768

using bf16x8 = __attribute__((ext_vector_type(8))) short;
using f32x4  = __attribute__((ext_vector_type(4))) float;

// ---------------- encoder: h = x @ W_enc + b_enc  (no relu) ----------------
__global__ __launch_bounds__(256) void enc_kernel(const float* __restrict__ x,
                                                  const float* __restrict__ W,
                                                  const float* __restrict__ bias,
                                                  float* __restrict__ hout)
{
    int gid = blockIdx.x * 256 + threadIdx.x;      // over NTOT*HD
    int n = gid >> 7, o = gid & 127;
    float s = bias[o];
#pragma unroll
    for (int f = 0; f < 4; ++f)
        s = fmaf(x[n*4 + f], W[f*128 + o], s);
    hout[gid] = s;
}

// ---------------- fused: exact f32 sq-norm + 3-way bf16 split ----------------
__device__ inline unsigned short bf16rn(float f) {
    unsigned u = __float_as_uint(f);
    unsigned r = (u + 0x7FFFu + ((u >> 16) & 1u)) >> 16;
    return (unsigned short)r;
}
__device__ inline float bf16tof(unsigned short h) {
    return __uint_as_float(((unsigned)h) << 16);
}

__global__ __launch_bounds__(256) void split_kernel(const float* __restrict__ h,
                                                    unsigned short* __restrict__ hs,  // [3][NTOT][HD]
                                                    float* __restrict__ sqg)
{
    const size_t plane = (size_t)NTOT * HD;
    int node = (blockIdx.x * 256 + threadIdx.x) >> 6;
    int lane = threadIdx.x & 63;
    const float* hp = h + (size_t)node * HD;
    float v0 = hp[lane], v1 = hp[lane + 64];
    // exact f32 squared norm
    float s = fmaf(v0, v0, v1 * v1);
#pragma unroll
    for (int off = 32; off >= 1; off >>= 1)
        s += __shfl_xor(s, off);
    if (lane == 0) sqg[node] = s;
    // 3-way split (each residual subtraction is exact)
#pragma unroll
    for (int q = 0; q < 2; ++q) {
        float v = q ? v1 : v0;
        int   d = lane + q * 64;
        unsigned short b1 = bf16rn(v);  float r1 = v  - bf16tof(b1);
        unsigned short b2 = bf16rn(r1); float r2 = r1 - bf16tof(b2);
        unsigned short b3 = bf16rn(r2);
        size_t base = (size_t)node * HD + d;
        hs[base]             = b1;
        hs[base + plane]     = b2;
        hs[base + 2 * plane] = b3;
    }
}

// ---------------- kNN via MFMA (bf16x3 split, 6 passes) ----------------
// No LDS, no barriers. Block = 4 independent waves; wave = 16 rows x 2048 cols.
// Top-8 per (row, col mod 16) in registers; width-16 shuffle merge at end.
__global__ __launch_bounds__(256) void knn_mfma(const unsigned short* __restrict__ hs,
                                                const float* __restrict__ sqg,
                                                int* __restrict__ nbr)
{
    const size_t plane = (size_t)NTOT * HD;
    // bijective XCD swizzle: 512 blocks = 8 XCDs x 64
    const int lb   = (blockIdx.x & 7) * 64 + (blockIdx.x >> 3);
    const int g    = lb >> 5;                 // graph
    const int rb   = lb & 31;                 // row-block (64 rows)
    const int wv   = threadIdx.x >> 6;
    const int lane = threadIdx.x & 63;
    const int row0 = rb * 64 + wv * 16;       // this wave's 16 rows
    const int gbase = g * NPG;
    const int lrow = lane & 15;               // A-row / B-col within tile
    const int kgrp = lane >> 4;               // k-chunk group 0..3

    // A fragments: 3 splits x 4 K-chunks, pinned in VGPRs
    const unsigned short* arow = hs + (size_t)(gbase + row0 + lrow) * HD + kgrp * 8;
    bf16x8 A0[4], A1[4], A2[4];
#pragma unroll
    for (int kc = 0; kc < 4; ++kc) {
        A0[kc] = *(const bf16x8*)(arow + kc * 32);
        A1[kc] = *(const bf16x8*)(arow + plane + kc * 32);
        A2[kc] = *(const bf16x8*)(arow + 2 * plane + kc * 32);
    }
    // sq norms of this lane-group's 4 C-rows (C row = (lane>>4)*4 + reg)
    float sqi4[4];
#pragma unroll
    for (int r = 0; r < 4; ++r)
        sqi4[r] = sqg[gbase + row0 + kgrp * 4 + r];

    const float INF = __uint_as_float(0x7F800000u);
    float bd[4][8];
    int   bi[4][8];
#pragma unroll
    for (int r = 0; r < 4; ++r)
#pragma unroll
        for (int s = 0; s < 8; ++s) { bd[r][s] = INF; bi[r][s] = 0x7fffffff; }

    for (int c0 = 0; c0 < NPG; c0 += 32) {
        const unsigned short* bb0 = hs + (size_t)(gbase + c0 + lrow) * HD + kgrp * 8;
        const unsigned short* bb1 = bb0 + 16 * HD;
        f32x4 acc0 = {0.f, 0.f, 0.f, 0.f};
        f32x4 acc1 = {0.f, 0.f, 0.f, 0.f};
#pragma unroll
        for (int kc = 0; kc < 4; ++kc) {
            bf16x8 c0_0 = *(const bf16x8*)(bb0 + kc * 32);
            bf16x8 c0_1 = *(const bf16x8*)(bb1 + kc * 32);
            bf16x8 c1_0 = *(const bf16x8*)(bb0 + plane + kc * 32);
            bf16x8 c1_1 = *(const bf16x8*)(bb1 + plane + kc * 32);
            bf16x8 c2_0 = *(const bf16x8*)(bb0 + 2 * plane + kc * 32);
            bf16x8 c2_1 = *(const bf16x8*)(bb1 + 2 * plane + kc * 32);
            // 6 passes: (s,t) with s+t error order <= 2^-18
            acc0 = __builtin_amdgcn_mfma_f32_16x16x32_bf16(A0[kc], c0_0, acc0, 0, 0, 0);
            acc1 = __builtin_amdgcn_mfma_f32_16x16x32_bf16(A0[kc], c0_1, acc1, 0, 0, 0);
            acc0 = __builtin_amdgcn_mfma_f32_16x16x32_bf16(A0[kc], c1_0, acc0, 0, 0, 0);
            acc1 = __builtin_amdgcn_mfma_f32_16x16x32_bf16(A0[kc], c1_1, acc1, 0, 0, 0);
            acc0 = __builtin_amdgcn_mfma_f32_16x16x32_bf16(A1[kc], c0_0, acc0, 0, 0, 0);
            acc1 = __builtin_amdgcn_mfma_f32_16x16x32_bf16(A1[kc], c0_1, acc1, 0, 0, 0);
            acc0 = __builtin_amdgcn_mfma_f32_16x16x32_bf16(A0[kc], c2_0, acc0, 0, 0, 0);
            acc1 = __builtin_amdgcn_mfma_f32_16x16x32_bf16(A0[kc], c2_1, acc1, 0, 0, 0);
            acc0 = __builtin_amdgcn_mfma_f32_16x16x32_bf16(A1[kc], c1_0, acc0, 0, 0, 0);
            acc1 = __builtin_amdgcn_mfma_f32_16x16x32_bf16(A1[kc], c1_1, acc1, 0, 0, 0);
            acc0 = __builtin_amdgcn_mfma_f32_16x16x32_bf16(A2[kc], c0_0, acc0, 0, 0, 0);
            acc1 = __builtin_amdgcn_mfma_f32_16x16x32_bf16(A2[kc], c0_1, acc1, 0, 0, 0);
        }
        float sqj0 = sqg[gbase + c0 + lrow];
        float sqj1 = sqg[gbase + c0 + 16 + lrow];
        int j0 = c0 + lrow, j1 = c0 + 16 + lrow;
#pragma unroll
        for (int r = 0; r < 4; ++r) {
            float d0 = fmaf(-2.f, acc0[r], sqi4[r] + sqj0);
            if (d0 < bd[r][7]) {
#pragma unroll
                for (int s = 7; s > 0; --s) {
                    bool up   = d0 < bd[r][s-1];
                    bool here = (!up) && (d0 < bd[r][s]);
                    float nd = up ? bd[r][s-1] : (here ? d0 : bd[r][s]);
                    int   ni = up ? bi[r][s-1] : (here ? j0 : bi[r][s]);
                    bd[r][s] = nd; bi[r][s] = ni;
                }
                if (d0 < bd[r][0]) { bd[r][0] = d0; bi[r][0] = j0; }
            }
            float d1 = fmaf(-2.f, acc1[r], sqi4[r] + sqj1);
            if (d1 < bd[r][7]) {
#pragma unroll
                for (int s = 7; s > 0; --s) {
                    bool up   = d1 < bd[r][s-1];
                    bool here = (!up) && (d1 < bd[r][s]);
                    float nd = up ? bd[r][s-1] : (here ? d1 : bd[r][s]);
                    int   ni = up ? bi[r][s-1] : (here ? j1 : bi[r][s]);
                    bd[r][s] = nd; bi[r][s] = ni;
                }
                if (d1 < bd[r][0]) { bd[r][0] = d1; bi[r][0] = j1; }
            }
        }
    }

    // merge 16 sorted lists per row via width-16 shuffles; tie-break lower index
#pragma unroll
    for (int r = 0; r < 4; ++r) {
        float hd = bd[r][0]; int hi = bi[r][0];
#pragma unroll
        for (int sel = 0; sel < 8; ++sel) {
            float md = hd; int mi = hi;
#pragma unroll
            for (int m = 1; m < 16; m <<= 1) {
                float od = __shfl_xor(md, m, 16);
                int   oi = __shfl_xor(mi, m, 16);
                bool tk = (od < md) || (od == md && oi < mi);
                md = tk ? od : md; mi = tk ? oi : mi;
            }
            if (lrow == sel)
                nbr[(size_t)(gbase + row0 + kgrp * 4 + r) * KNN + sel] = gbase + mi;
            bool win = (hd == md) && (hi == mi);
            if (win) {
                bd[r][0]=bd[r][1]; bi[r][0]=bi[r][1];
                bd[r][1]=bd[r][2]; bi[r][1]=bi[r][2];
                bd[r][2]=bd[r][3]; bi[r][2]=bi[r][3];
                bd[r][3]=bd[r][4]; bi[r][3]=bi[r][4];
                bd[r][4]=bd[r][5]; bi[r][4]=bi[r][5];
                bd[r][5]=bd[r][6]; bi[r][5]=bi[r][6];
                bd[r][6]=bd[r][7]; bi[r][6]=bi[r][7];
                bd[r][7]=INF;      bi[r][7]=0x7fffffff;
            }
            hd = bd[r][0]; hi = bi[r][0];
        }
    }
}

// ---------------- fused edge-MLP + max-aggregate ----------------
template<bool FINAL>
__global__ __launch_bounds__(256) void mlp_kernel(const float* __restrict__ h,
                                                  const int* __restrict__ nbr,
                                                  const float* __restrict__ Wa,
                                                  const float* __restrict__ ba,
                                                  const float* __restrict__ Wb,
                                                  const float* __restrict__ bb,
                                                  float* __restrict__ out)
{
    __shared__ float xi[8*129];
    __shared__ float e2[64*129];   // xj - xi
    __shared__ float h1[64*129];

    const int t = threadIdx.x;
    const int node0 = blockIdx.x * 8;

    {
        int r = t >> 5, p = t & 31;
        float4 v = *(const float4*)(h + (size_t)(node0 + r)*HD + p*4);
        float* dst = &xi[r*129 + p*4];
        dst[0]=v.x; dst[1]=v.y; dst[2]=v.z; dst[3]=v.w;
    }
    __syncthreads();
    {
        int r = t >> 2, p = t & 3;
        int j = nbr[(size_t)(node0 + (r >> 3))*KNN + (r & 7)];
        const float* src = h + (size_t)j*HD;
        const float* xir = &xi[(r >> 3)*129];
        float* dst = &e2[r*129];
#pragma unroll
        for (int q = 0; q < 8; ++q) {
            int d = p*32 + q*4;
            float4 v = *(const float4*)(src + d);
            dst[d+0]=v.x-xir[d+0]; dst[d+1]=v.y-xir[d+1];
            dst[d+2]=v.z-xir[d+2]; dst[d+3]=v.w-xir[d+3];
        }
    }
    __syncthreads();

    const int rg = t >> 5;   // node 0..7
    const int og = t & 31;   // output cols og*4..og*4+3

    float tA[4] = {0.f,0.f,0.f,0.f};
    {
        const float* xir = &xi[rg*129];
#pragma unroll 4
        for (int d = 0; d < 128; ++d) {
            float a = xir[d];
            float4 w = *(const float4*)(Wa + (size_t)d*128 + og*4);
            tA[0]=fmaf(a,w.x,tA[0]); tA[1]=fmaf(a,w.y,tA[1]);
            tA[2]=fmaf(a,w.z,tA[2]); tA[3]=fmaf(a,w.w,tA[3]);
        }
    }
    float acc[8][4];
#pragma unroll
    for (int k = 0; k < 8; ++k)
#pragma unroll
        for (int c = 0; c < 4; ++c) acc[k][c] = tA[c];

    {
        const float* e2p = &e2[(rg*8)*129];
#pragma unroll 2
        for (int d = 0; d < 128; ++d) {
            float4 w = *(const float4*)(Wa + (size_t)(128+d)*128 + og*4);
#pragma unroll
            for (int k = 0; k < 8; ++k) {
                float a = e2p[k*129 + d];
                acc[k][0]=fmaf(a,w.x,acc[k][0]); acc[k][1]=fmaf(a,w.y,acc[k][1]);
                acc[k][2]=fmaf(a,w.z,acc[k][2]); acc[k][3]=fmaf(a,w.w,acc[k][3]);
            }
        }
    }
    {
        float b0 = ba[og*4+0], b1 = ba[og*4+1], b2 = ba[og*4+2], b3 = ba[og*4+3];
#pragma unroll
        for (int k = 0; k < 8; ++k) {
            h1[(rg*8+k)*129 + og*4+0] = fmaxf(acc[k][0]+b0, 0.f);
            h1[(rg*8+k)*129 + og*4+1] = fmaxf(acc[k][1]+b1, 0.f);
            h1[(rg*8+k)*129 + og*4+2] = fmaxf(acc[k][2]+b2, 0.f);
            h1[(rg*8+k)*129 + og*4+3] = fmaxf(acc[k][3]+b3, 0.f);
        }
    }
    __syncthreads();

    if (!FINAL) {
        float acc2[8][4];
#pragma unroll
        for (int k = 0; k < 8; ++k)
#pragma unroll
            for (int c = 0; c < 4; ++c) acc2[k][c] = 0.f;
        const float* h1p = &h1[(rg*8)*129];
#pragma unroll 2
        for (int d = 0; d < 128; ++d) {
            float4 w = *(const float4*)(Wb + (size_t)d*128 + og*4);
#pragma unroll
            for (int k = 0; k < 8; ++k) {
                float a = h1p[k*129 + d];
                acc2[k][0]=fmaf(a,w.x,acc2[k][0]); acc2[k][1]=fmaf(a,w.y,acc2[k][1]);
                acc2[k][2]=fmaf(a,w.z,acc2[k][2]); acc2[k][3]=fmaf(a,w.w,acc2[k][3]);
            }
        }
        float b0 = bb[og*4+0], b1 = bb[og*4+1], b2 = bb[og*4+2], b3 = bb[og*4+3];
        float m0=0.f, m1=0.f, m2=0.f, m3=0.f;
#pragma unroll
        for (int k = 0; k < 8; ++k) {
            m0 = fmaxf(m0, acc2[k][0]+b0);
            m1 = fmaxf(m1, acc2[k][1]+b1);
            m2 = fmaxf(m2, acc2[k][2]+b2);
            m3 = fmaxf(m3, acc2[k][3]+b3);
        }
        float* op = out + (size_t)(node0 + rg)*HD + og*4;
        op[0]=m0; op[1]=m1; op[2]=m2; op[3]=m3;
    } else {
        if (t < 64) {
            int r = t;
            float s = 0.f;
            const float* h1p = &h1[r*129];
#pragma unroll 4
            for (int d = 0; d < 128; ++d)
                s = fmaf(h1p[d], Wb[d], s);
            s = fmaxf(s + bb[0], 0.f);
#pragma unroll
            for (int m = 1; m < 8; m <<= 1)
                s = fmaxf(s, __shfl_xor(s, m));
            if ((t & 7) == 0)
                out[node0 + (t >> 3)] = 1.f / (1.f + expf(-s));
        }
    }
}

extern "C" void kernel_launch(void* const* d_in, const int* in_sizes, int n_in,
                              void* d_out, int out_size, void* d_ws, size_t ws_size,
                              hipStream_t stream) {
    const float* x     = (const float*)d_in[0];
    const float* W_enc = (const float*)d_in[3];
    const float* b_enc = (const float*)d_in[4];
    const float* W1a = (const float*)d_in[5];
    const float* b1a = (const float*)d_in[6];
    const float* W1b = (const float*)d_in[7];
    const float* b1b = (const float*)d_in[8];
    const float* W2a = (const float*)d_in[9];
    const float* b2a = (const float*)d_in[10];
    const float* W2b = (const float*)d_in[11];
    const float* b2b = (const float*)d_in[12];
    const float* W5a = (const float*)d_in[13];
    const float* b5a = (const float*)d_in[14];
    const float* W5b = (const float*)d_in[15];
    const float* b5b = (const float*)d_in[16];

    float* h0  = (float*)d_ws;                          // 16 MB
    float* h1  = h0 + (size_t)NTOT*HD;                  // 16 MB
    float* sqg = h1 + (size_t)NTOT*HD;                  // 128 KB
    int*  idxb = (int*)(sqg + NTOT);                    // 1 MB
    unsigned short* hs = (unsigned short*)(idxb + (size_t)NTOT*KNN);  // 24 MB (3 bf16 planes)

    enc_kernel<<<NTOT*HD/256, 256, 0, stream>>>(x, W_enc, b_enc, h0);

    // layer 1
    split_kernel<<<NTOT/4, 256, 0, stream>>>(h0, hs, sqg);
    knn_mfma   <<<BGR*32, 256, 0, stream>>>(hs, sqg, idxb);
    mlp_kernel<false><<<NTOT/8, 256, 0, stream>>>(h0, idxb, W1a, b1a, W1b, b1b, h1);

    // layer 2
    split_kernel<<<NTOT/4, 256, 0, stream>>>(h1, hs, sqg);
    knn_mfma   <<<BGR*32, 256, 0, stream>>>(hs, sqg, idxb);
    mlp_kernel<false><<<NTOT/8, 256, 0, stream>>>(h1, idxb, W2a, b2a, W2b, b2b, h0);

    // layer 5 (final)
    split_kernel<<<NTOT/4, 256, 0, stream>>>(h0, hs, sqg);
    knn_mfma   <<<BGR*32, 256, 0, stream>>>(hs, sqg, idxb);
    mlp_kernel<true><<<NTOT/8, 256, 0, stream>>>(h0, idxb, W5a, b5a, W5b, b5b, (float*)d_out);
}

// Round 3
// 1434.416 us; speedup vs baseline: 1.7451x; 1.4205x over previous
//
#include <hip/hip_runtime.h>
#include <hip/hip_bf16.h>
#include <math.h>

#define BGR 16
#define NPG 2048
#define HD  128
#define KNN 8
#define NTOT (BGR*NPG)   // 32768

using bf16x8 = __attribute__((ext_vector_type(8))) short;
using f32x4  = __attribute__((ext_vector_type(4))) float;

typedef __attribute__((address_space(3))) unsigned int lds_uint;
typedef const __attribute__((address_space(1))) unsigned int glob_uint;
#define GLOAD_LDS16(g, l) __builtin_amdgcn_global_load_lds((glob_uint*)(g), (lds_uint*)(l), 16, 0, 0)

// ---------------- encoder: h = x @ W_enc + b_enc  (no relu) ----------------
__global__ __launch_bounds__(256) void enc_kernel(const float* __restrict__ x,
                                                  const float* __restrict__ W,
                                                  const float* __restrict__ bias,
                                                  float* __restrict__ hout)
{
    int gid = blockIdx.x * 256 + threadIdx.x;
    int n = gid >> 7, o = gid & 127;
    float s = bias[o];
#pragma unroll
    for (int f = 0; f < 4; ++f)
        s = fmaf(x[n*4 + f], W[f*128 + o], s);
    hout[gid] = s;
}

// ---------------- fused: exact f32 sq-norm + 3-way bf16 split ----------------
__device__ inline unsigned short bf16rn(float f) {
    unsigned u = __float_as_uint(f);
    unsigned r = (u + 0x7FFFu + ((u >> 16) & 1u)) >> 16;
    return (unsigned short)r;
}
__device__ inline float bf16tof(unsigned short h) {
    return __uint_as_float(((unsigned)h) << 16);
}

__global__ __launch_bounds__(256) void split_kernel(const float* __restrict__ h,
                                                    unsigned short* __restrict__ hs,  // [3][NTOT][HD]
                                                    float* __restrict__ sqg)
{
    const size_t plane = (size_t)NTOT * HD;
    int node = (blockIdx.x * 256 + threadIdx.x) >> 6;
    int lane = threadIdx.x & 63;
    const float* hp = h + (size_t)node * HD;
    float v0 = hp[lane], v1 = hp[lane + 64];
    float s = fmaf(v0, v0, v1 * v1);
#pragma unroll
    for (int off = 32; off >= 1; off >>= 1)
        s += __shfl_xor(s, off);
    if (lane == 0) sqg[node] = s;
#pragma unroll
    for (int q = 0; q < 2; ++q) {
        float v = q ? v1 : v0;
        int   d = lane + q * 64;
        unsigned short b1 = bf16rn(v);  float r1 = v  - bf16tof(b1);
        unsigned short b2 = bf16rn(r1); float r2 = r1 - bf16tof(b2);
        unsigned short b3 = bf16rn(r2);
        size_t base = (size_t)node * HD + d;
        hs[base]             = b1;
        hs[base + plane]     = b2;
        hs[base + 2 * plane] = b3;
    }
}

// ---------------- kNN via MFMA, LDS-staged B, 4-way col split ----------------
// Block: 4 waves x 16 rows = 64 rows, cols = 512 (16 steps of 32).
// LDS buffer layout per 24KB buffer: [p(3)][kc(4)][c(32)][kgrp(4)][8 bf16]
//   -> wave's ds_read_b128 per (p,kc,h) is a dense contiguous 1KB: conflict-free,
//      all offsets immediate. Staged linearly by global_load_lds with
//      source addresses pre-permuted to match.
__global__ __launch_bounds__(256) void knn_mfma(const unsigned short* __restrict__ hs,
                                                const float* __restrict__ sqg,
                                                float* __restrict__ cand_d,
                                                int* __restrict__ cand_i)
{
    __shared__ ulong2 ldsraw[3200];    // 48KB B (2 buffers) + 2KB sq
    char* ldsc = (char*)ldsraw;
    float* sqs = (float*)(ldsc + 49152);

    const size_t plane = (size_t)NTOT * HD;
    const int t = threadIdx.x;
    const int b = blockIdx.x;
    // XCD-pinning swizzle: graph g -> XCD g&7 (heuristic only)
    const int slot = b >> 3;
    const int g   = (b & 7) | ((slot & 1) << 3);
    const int rb  = (slot >> 1) & 31;
    const int cs  = slot >> 6;
    const int gbase = g * NPG;
    const int cbase = cs * 512;
    const int wv = t >> 6, lane = t & 63;
    const int row0 = rb * 64 + wv * 16;
    const int lrow = lane & 15, kgrp = lane >> 4;

    // stage this block's col-range sq-norms
    sqs[t]       = sqg[gbase + cbase + t];
    sqs[t + 256] = sqg[gbase + cbase + 256 + t];

    // A fragments: 3 splits x 4 K-chunks pinned in VGPRs
    const unsigned short* arow = hs + (size_t)(gbase + row0 + lrow) * HD + kgrp * 8;
    bf16x8 A0[4], A1[4], A2[4];
#pragma unroll
    for (int kc = 0; kc < 4; ++kc) {
        A0[kc] = *(const bf16x8*)(arow + kc * 32);
        A1[kc] = *(const bf16x8*)(arow + plane + kc * 32);
        A2[kc] = *(const bf16x8*)(arow + 2 * plane + kc * 32);
    }
    float sqi4[4];
#pragma unroll
    for (int r = 0; r < 4; ++r)
        sqi4[r] = sqg[gbase + row0 + kgrp * 4 + r];

    // staging source pointers (6 x 4KB issues per 24KB step-tile)
    // LDS-linear slot (p,kc,c,kgrp,e) <- global elem (plane p, col c, dim kc*32+kgrp*8+e)
    const int col_t  = (t >> 2) & 31;
    const int kgrp_t = t & 3;
    const unsigned short* sbase[6];
#pragma unroll
    for (int i = 0; i < 6; ++i) {
        int p  = i >> 1;
        int kc = (i & 1) * 2 + (t >> 7);
        sbase[i] = hs + (size_t)p * plane + (size_t)(gbase + cbase + col_t) * HD
                 + kc * 32 + kgrp_t * 8;
    }
    char* ldsw = ldsc + wv * 1024;   // wave-uniform base; +bf*24576 +i*4096

    // prologue: stage step 0 into buffer 0
#pragma unroll
    for (int i = 0; i < 6; ++i)
        GLOAD_LDS16(sbase[i], ldsw + i * 4096);
    __syncthreads();

    const float INF = __uint_as_float(0x7F800000u);
    float bd[4][8];
    int   bi[4][8];
#pragma unroll
    for (int r = 0; r < 4; ++r)
#pragma unroll
        for (int s = 0; s < 8; ++s) { bd[r][s] = INF; bi[r][s] = 0x7fffffff; }

    int cur = 0;
    for (int s = 0; s < 16; ++s) {
        // prefetch next step into other buffer (lands before end-of-step barrier)
        if (s < 15) {
#pragma unroll
            for (int i = 0; i < 6; ++i) {
                sbase[i] += 32 * HD;
                GLOAD_LDS16(sbase[i], ldsw + (cur ^ 1) * 24576 + i * 4096);
            }
        }
        const char* pb = ldsc + cur * 24576 + lrow * 64 + kgrp * 16;
        float sqj0 = sqs[s * 32 + lrow];
        float sqj1 = sqs[s * 32 + 16 + lrow];
        f32x4 acc0 = {0.f,0.f,0.f,0.f};
        f32x4 acc1 = {0.f,0.f,0.f,0.f};
#pragma unroll
        for (int kc = 0; kc < 4; ++kc) {
            const char* pk = pb + kc * 2048;
            bf16x8 b0h0 = *(const bf16x8*)(pk);
            bf16x8 b0h1 = *(const bf16x8*)(pk + 1024);
            bf16x8 b1h0 = *(const bf16x8*)(pk + 8192);
            bf16x8 b1h1 = *(const bf16x8*)(pk + 8192 + 1024);
            bf16x8 b2h0 = *(const bf16x8*)(pk + 16384);
            bf16x8 b2h1 = *(const bf16x8*)(pk + 16384 + 1024);
            acc0 = __builtin_amdgcn_mfma_f32_16x16x32_bf16(A0[kc], b0h0, acc0, 0, 0, 0);
            acc1 = __builtin_amdgcn_mfma_f32_16x16x32_bf16(A0[kc], b0h1, acc1, 0, 0, 0);
            acc0 = __builtin_amdgcn_mfma_f32_16x16x32_bf16(A0[kc], b1h0, acc0, 0, 0, 0);
            acc1 = __builtin_amdgcn_mfma_f32_16x16x32_bf16(A0[kc], b1h1, acc1, 0, 0, 0);
            acc0 = __builtin_amdgcn_mfma_f32_16x16x32_bf16(A1[kc], b0h0, acc0, 0, 0, 0);
            acc1 = __builtin_amdgcn_mfma_f32_16x16x32_bf16(A1[kc], b0h1, acc1, 0, 0, 0);
            acc0 = __builtin_amdgcn_mfma_f32_16x16x32_bf16(A0[kc], b2h0, acc0, 0, 0, 0);
            acc1 = __builtin_amdgcn_mfma_f32_16x16x32_bf16(A0[kc], b2h1, acc1, 0, 0, 0);
            acc0 = __builtin_amdgcn_mfma_f32_16x16x32_bf16(A1[kc], b1h0, acc0, 0, 0, 0);
            acc1 = __builtin_amdgcn_mfma_f32_16x16x32_bf16(A1[kc], b1h1, acc1, 0, 0, 0);
            acc0 = __builtin_amdgcn_mfma_f32_16x16x32_bf16(A2[kc], b0h0, acc0, 0, 0, 0);
            acc1 = __builtin_amdgcn_mfma_f32_16x16x32_bf16(A2[kc], b0h1, acc1, 0, 0, 0);
        }
        int j0 = cbase + s * 32 + lrow, j1 = j0 + 16;
#pragma unroll
        for (int r = 0; r < 4; ++r) {
            float d0 = fmaf(-2.f, acc0[r], sqi4[r] + sqj0);
            if (d0 < bd[r][7]) {
#pragma unroll
                for (int q = 7; q > 0; --q) {
                    bool up   = d0 < bd[r][q-1];
                    bool here = (!up) && (d0 < bd[r][q]);
                    float nd = up ? bd[r][q-1] : (here ? d0 : bd[r][q]);
                    int   ni = up ? bi[r][q-1] : (here ? j0 : bi[r][q]);
                    bd[r][q] = nd; bi[r][q] = ni;
                }
                if (d0 < bd[r][0]) { bd[r][0] = d0; bi[r][0] = j0; }
            }
            float d1 = fmaf(-2.f, acc1[r], sqi4[r] + sqj1);
            if (d1 < bd[r][7]) {
#pragma unroll
                for (int q = 7; q > 0; --q) {
                    bool up   = d1 < bd[r][q-1];
                    bool here = (!up) && (d1 < bd[r][q]);
                    float nd = up ? bd[r][q-1] : (here ? d1 : bd[r][q]);
                    int   ni = up ? bi[r][q-1] : (here ? j1 : bi[r][q]);
                    bd[r][q] = nd; bi[r][q] = ni;
                }
                if (d1 < bd[r][0]) { bd[r][0] = d1; bi[r][0] = j1; }
            }
        }
        __syncthreads();
        cur ^= 1;
    }

    // per-wave merge of 16 sorted lists per row -> top-8 of this col-slice
#pragma unroll
    for (int r = 0; r < 4; ++r) {
        float hd = bd[r][0]; int hi = bi[r][0];
        const size_t growout = (size_t)(gbase + row0 + kgrp * 4 + r) * 32 + cs * 8;
#pragma unroll
        for (int sel = 0; sel < 8; ++sel) {
            float md = hd; int mi = hi;
#pragma unroll
            for (int m = 1; m < 16; m <<= 1) {
                float od = __shfl_xor(md, m, 16);
                int   oi = __shfl_xor(mi, m, 16);
                bool tk = (od < md) || (od == md && oi < mi);
                md = tk ? od : md; mi = tk ? oi : mi;
            }
            if (lrow == sel) {
                cand_d[growout + sel] = md;
                cand_i[growout + sel] = gbase + mi;
            }
            bool win = (hd == md) && (hi == mi);
            if (win) {
                bd[r][0]=bd[r][1]; bi[r][0]=bi[r][1];
                bd[r][1]=bd[r][2]; bi[r][1]=bi[r][2];
                bd[r][2]=bd[r][3]; bi[r][2]=bi[r][3];
                bd[r][3]=bd[r][4]; bi[r][3]=bi[r][4];
                bd[r][4]=bd[r][5]; bi[r][4]=bi[r][5];
                bd[r][5]=bd[r][6]; bi[r][5]=bi[r][6];
                bd[r][6]=bd[r][7]; bi[r][6]=bi[r][7];
                bd[r][7]=INF;      bi[r][7]=0x7fffffff;
            }
            hd = bd[r][0]; hi = bi[r][0];
        }
    }
}

// ---------------- merge 4 col-split candidate lists -> final top-8 ----------------
__global__ __launch_bounds__(256) void knn_merge(const float* __restrict__ cand_d,
                                                 const int* __restrict__ cand_i,
                                                 int* __restrict__ nbr)
{
    int row = blockIdx.x * 256 + threadIdx.x;
    const float* pd = cand_d + (size_t)row * 32;
    const int*   pi = cand_i + (size_t)row * 32;
    float d[32]; int ix[32];
#pragma unroll
    for (int k = 0; k < 32; ++k) { d[k] = pd[k]; ix[k] = pi[k]; }
    int* op = nbr + (size_t)row * KNN;
    const float INF = __uint_as_float(0x7F800000u);
#pragma unroll
    for (int sel = 0; sel < 8; ++sel) {
        float md = d[0]; int mi = ix[0];
#pragma unroll
        for (int k = 1; k < 32; ++k) {
            bool tk = (d[k] < md) || (d[k] == md && ix[k] < mi);
            md = tk ? d[k] : md; mi = tk ? ix[k] : mi;
        }
        op[sel] = mi;
#pragma unroll
        for (int k = 0; k < 32; ++k) {
            bool rm = (d[k] == md) && (ix[k] == mi);
            d[k] = rm ? INF : d[k];
        }
    }
}

// ---------------- fused edge-MLP + max-aggregate ----------------
template<bool FINAL>
__global__ __launch_bounds__(256) void mlp_kernel(const float* __restrict__ h,
                                                  const int* __restrict__ nbr,
                                                  const float* __restrict__ Wa,
                                                  const float* __restrict__ ba,
                                                  const float* __restrict__ Wb,
                                                  const float* __restrict__ bb,
                                                  float* __restrict__ out)
{
    __shared__ float xi[8*129];
    __shared__ float e2[64*129];   // xj - xi
    __shared__ float h1[64*129];

    const int t = threadIdx.x;
    const int node0 = blockIdx.x * 8;

    {
        int r = t >> 5, p = t & 31;
        float4 v = *(const float4*)(h + (size_t)(node0 + r)*HD + p*4);
        float* dst = &xi[r*129 + p*4];
        dst[0]=v.x; dst[1]=v.y; dst[2]=v.z; dst[3]=v.w;
    }
    __syncthreads();
    {
        int r = t >> 2, p = t & 3;
        int j = nbr[(size_t)(node0 + (r >> 3))*KNN + (r & 7)];
        const float* src = h + (size_t)j*HD;
        const float* xir = &xi[(r >> 3)*129];
        float* dst = &e2[r*129];
#pragma unroll
        for (int q = 0; q < 8; ++q) {
            int d = p*32 + q*4;
            float4 v = *(const float4*)(src + d);
            dst[d+0]=v.x-xir[d+0]; dst[d+1]=v.y-xir[d+1];
            dst[d+2]=v.z-xir[d+2]; dst[d+3]=v.w-xir[d+3];
        }
    }
    __syncthreads();

    const int rg = t >> 5;   // node 0..7
    const int og = t & 31;   // output cols og*4..og*4+3

    float tA[4] = {0.f,0.f,0.f,0.f};
    {
        const float* xir = &xi[rg*129];
#pragma unroll 4
        for (int d = 0; d < 128; ++d) {
            float a = xir[d];
            float4 w = *(const float4*)(Wa + (size_t)d*128 + og*4);
            tA[0]=fmaf(a,w.x,tA[0]); tA[1]=fmaf(a,w.y,tA[1]);
            tA[2]=fmaf(a,w.z,tA[2]); tA[3]=fmaf(a,w.w,tA[3]);
        }
    }
    float acc[8][4];
#pragma unroll
    for (int k = 0; k < 8; ++k)
#pragma unroll
        for (int c = 0; c < 4; ++c) acc[k][c] = tA[c];

    {
        const float* e2p = &e2[(rg*8)*129];
#pragma unroll 2
        for (int d = 0; d < 128; ++d) {
            float4 w = *(const float4*)(Wa + (size_t)(128+d)*128 + og*4);
#pragma unroll
            for (int k = 0; k < 8; ++k) {
                float a = e2p[k*129 + d];
                acc[k][0]=fmaf(a,w.x,acc[k][0]); acc[k][1]=fmaf(a,w.y,acc[k][1]);
                acc[k][2]=fmaf(a,w.z,acc[k][2]); acc[k][3]=fmaf(a,w.w,acc[k][3]);
            }
        }
    }
    {
        float b0 = ba[og*4+0], b1 = ba[og*4+1], b2 = ba[og*4+2], b3 = ba[og*4+3];
#pragma unroll
        for (int k = 0; k < 8; ++k) {
            h1[(rg*8+k)*129 + og*4+0] = fmaxf(acc[k][0]+b0, 0.f);
            h1[(rg*8+k)*129 + og*4+1] = fmaxf(acc[k][1]+b1, 0.f);
            h1[(rg*8+k)*129 + og*4+2] = fmaxf(acc[k][2]+b2, 0.f);
            h1[(rg*8+k)*129 + og*4+3] = fmaxf(acc[k][3]+b3, 0.f);
        }
    }
    __syncthreads();

    if (!FINAL) {
        float acc2[8][4];
#pragma unroll
        for (int k = 0; k < 8; ++k)
#pragma unroll
            for (int c = 0; c < 4; ++c) acc2[k][c] = 0.f;
        const float* h1p = &h1[(rg*8)*129];
#pragma unroll 2
        for (int d = 0; d < 128; ++d) {
            float4 w = *(const float4*)(Wb + (size_t)d*128 + og*4);
#pragma unroll
            for (int k = 0; k < 8; ++k) {
                float a = h1p[k*129 + d];
                acc2[k][0]=fmaf(a,w.x,acc2[k][0]); acc2[k][1]=fmaf(a,w.y,acc2[k][1]);
                acc2[k][2]=fmaf(a,w.z,acc2[k][2]); acc2[k][3]=fmaf(a,w.w,acc2[k][3]);
            }
        }
        float b0 = bb[og*4+0], b1 = bb[og*4+1], b2 = bb[og*4+2], b3 = bb[og*4+3];
        float m0=0.f, m1=0.f, m2=0.f, m3=0.f;
#pragma unroll
        for (int k = 0; k < 8; ++k) {
            m0 = fmaxf(m0, acc2[k][0]+b0);
            m1 = fmaxf(m1, acc2[k][1]+b1);
            m2 = fmaxf(m2, acc2[k][2]+b2);
            m3 = fmaxf(m3, acc2[k][3]+b3);
        }
        float* op = out + (size_t)(node0 + rg)*HD + og*4;
        op[0]=m0; op[1]=m1; op[2]=m2; op[3]=m3;
    } else {
        if (t < 64) {
            int r = t;
            float s = 0.f;
            const float* h1p = &h1[r*129];
#pragma unroll 4
            for (int d = 0; d < 128; ++d)
                s = fmaf(h1p[d], Wb[d], s);
            s = fmaxf(s + bb[0], 0.f);
#pragma unroll
            for (int m = 1; m < 8; m <<= 1)
                s = fmaxf(s, __shfl_xor(s, m));
            if ((t & 7) == 0)
                out[node0 + (t >> 3)] = 1.f / (1.f + expf(-s));
        }
    }
}

extern "C" void kernel_launch(void* const* d_in, const int* in_sizes, int n_in,
                              void* d_out, int out_size, void* d_ws, size_t ws_size,
                              hipStream_t stream) {
    const float* x     = (const float*)d_in[0];
    const float* W_enc = (const float*)d_in[3];
    const float* b_enc = (const float*)d_in[4];
    const float* W1a = (const float*)d_in[5];
    const float* b1a = (const float*)d_in[6];
    const float* W1b = (const float*)d_in[7];
    const float* b1b = (const float*)d_in[8];
    const float* W2a = (const float*)d_in[9];
    const float* b2a = (const float*)d_in[10];
    const float* W2b = (const float*)d_in[11];
    const float* b2b = (const float*)d_in[12];
    const float* W5a = (const float*)d_in[13];
    const float* b5a = (const float*)d_in[14];
    const float* W5b = (const float*)d_in[15];
    const float* b5b = (const float*)d_in[16];

    float* h0  = (float*)d_ws;                          // 16 MB
    float* h1  = h0 + (size_t)NTOT*HD;                  // 16 MB
    float* sqg = h1 + (size_t)NTOT*HD;                  // 128 KB
    int*  idxb = (int*)(sqg + NTOT);                    // 1 MB
    unsigned short* hs = (unsigned short*)(idxb + (size_t)NTOT*KNN);  // 24 MB

    // candidate buffers overlay the layer's OUTPUT buffer (idle during knn+merge):
    // layer1 out = h1, layer2 out = h0, layer3 out = d_out (tiny) -> use h1.
    float* c1d = h1;                 int* c1i = (int*)(h1 + (size_t)NTOT*32);
    float* c2d = h0;                 int* c2i = (int*)(h0 + (size_t)NTOT*32);

    enc_kernel<<<NTOT*HD/256, 256, 0, stream>>>(x, W_enc, b_enc, h0);

    // layer 1
    split_kernel<<<NTOT/4, 256, 0, stream>>>(h0, hs, sqg);
    knn_mfma   <<<BGR*128, 256, 0, stream>>>(hs, sqg, c1d, c1i);
    knn_merge  <<<NTOT/256, 256, 0, stream>>>(c1d, c1i, idxb);
    mlp_kernel<false><<<NTOT/8, 256, 0, stream>>>(h0, idxb, W1a, b1a, W1b, b1b, h1);

    // layer 2
    split_kernel<<<NTOT/4, 256, 0, stream>>>(h1, hs, sqg);
    knn_mfma   <<<BGR*128, 256, 0, stream>>>(hs, sqg, c2d, c2i);
    knn_merge  <<<NTOT/256, 256, 0, stream>>>(c2d, c2i, idxb);
    mlp_kernel<false><<<NTOT/8, 256, 0, stream>>>(h1, idxb, W2a, b2a, W2b, b2b, h0);

    // layer 5 (final)
    split_kernel<<<NTOT/4, 256, 0, stream>>>(h0, hs, sqg);
    knn_mfma   <<<BGR*128, 256, 0, stream>>>(hs, sqg, c1d, c1i);
    knn_merge  <<<NTOT/256, 256, 0, stream>>>(c1d, c1i, idxb);
    mlp_kernel<true><<<NTOT/8, 256, 0, stream>>>(h0, idxb, W5a, b5a, W5b, b5b, (float*)d_out);
}

// Round 4
// 823.409 us; speedup vs baseline: 3.0400x; 1.7420x over previous
//
#include <hip/hip_runtime.h>
#include <hip/hip_bf16.h>
#include <math.h>

#define BGR 16
#define NPG 2048
#define HD  128
#define KNN 8
#define NTOT (BGR*NPG)   // 32768

using bf16x8 = __attribute__((ext_vector_type(8))) short;
using f32x4  = __attribute__((ext_vector_type(4))) float;

typedef __attribute__((address_space(3))) unsigned int lds_uint;
typedef const __attribute__((address_space(1))) unsigned int glob_uint;
#define GLOAD_LDS16(g, l) __builtin_amdgcn_global_load_lds((glob_uint*)(g), (lds_uint*)(l), 16, 0, 0)

__device__ inline unsigned short bf16rn(float f) {
    unsigned u = __float_as_uint(f);
    unsigned r = (u + 0x7FFFu + ((u >> 16) & 1u)) >> 16;
    return (unsigned short)r;
}
__device__ inline float bf16tof(unsigned short h) {
    return __uint_as_float(((unsigned)h) << 16);
}

// ---------------- encoder ----------------
__global__ __launch_bounds__(256) void enc_kernel(const float* __restrict__ x,
                                                  const float* __restrict__ W,
                                                  const float* __restrict__ bias,
                                                  float* __restrict__ hout)
{
    int gid = blockIdx.x * 256 + threadIdx.x;
    int n = gid >> 7, o = gid & 127;
    float s = bias[o];
#pragma unroll
    for (int f = 0; f < 4; ++f)
        s = fmaf(x[n*4 + f], W[f*128 + o], s);
    hout[gid] = s;
}

// ---------------- exact f32 sq-norm + 3-way bf16 split ----------------
__global__ __launch_bounds__(256) void split_kernel(const float* __restrict__ h,
                                                    unsigned short* __restrict__ hs,
                                                    float* __restrict__ sqg)
{
    const size_t plane = (size_t)NTOT * HD;
    int node = (blockIdx.x * 256 + threadIdx.x) >> 6;
    int lane = threadIdx.x & 63;
    const float* hp = h + (size_t)node * HD;
    float v0 = hp[lane], v1 = hp[lane + 64];
    float s = fmaf(v0, v0, v1 * v1);
#pragma unroll
    for (int off = 32; off >= 1; off >>= 1)
        s += __shfl_xor(s, off);
    if (lane == 0) sqg[node] = s;
#pragma unroll
    for (int q = 0; q < 2; ++q) {
        float v = q ? v1 : v0;
        int   d = lane + q * 64;
        unsigned short b1 = bf16rn(v);  float r1 = v  - bf16tof(b1);
        unsigned short b2 = bf16rn(r1); float r2 = r1 - bf16tof(b2);
        unsigned short b3 = bf16rn(r2);
        size_t base = (size_t)node * HD + d;
        hs[base]             = b1;
        hs[base + plane]     = b2;
        hs[base + 2 * plane] = b3;
    }
}

// ---------------- weight prep: tile+split for LDS staging ----------------
// Wt layout: [cs][p(3)][kc(4)][c(32)][kgrp(4)][e(8)] bf16, 12288 elems per cs.
// prep_wcat: n<128 -> Wp[k][n]=Wa[128+k][n]; n>=128 -> Wd[k][n-128]=Wa[k][:]-Wa[128+k][:]
__global__ __launch_bounds__(256) void prep_wcat(const float* __restrict__ Wa,
                                                 unsigned short* __restrict__ Wt)
{
    int gid = blockIdx.x * 256 + threadIdx.x;   // 32768 = 128k x 256n
    int k = gid >> 8, n = gid & 255;
    float w;
    if (n < 128) w = Wa[(128 + k) * 128 + n];
    else { int nn = n - 128; w = Wa[k * 128 + nn] - Wa[(128 + k) * 128 + nn]; }
    unsigned short b1 = bf16rn(w);  float r1 = w  - bf16tof(b1);
    unsigned short b2 = bf16rn(r1); float r2 = r1 - bf16tof(b2);
    unsigned short b3 = bf16rn(r2);
    int cs = n >> 5, c = n & 31, kc = k >> 5, kg = (k >> 3) & 3, e = k & 7;
    size_t off = (size_t)cs * 12288 + kc * 1024 + c * 32 + kg * 8 + e;
    Wt[off] = b1; Wt[off + 4096] = b2; Wt[off + 8192] = b3;
}

__global__ __launch_bounds__(256) void prep_wb(const float* __restrict__ Wb,
                                               unsigned short* __restrict__ Wt)
{
    int gid = blockIdx.x * 256 + threadIdx.x;   // 16384 = 128k x 128n
    int k = gid >> 7, n = gid & 127;
    float w = Wb[k * 128 + n];
    unsigned short b1 = bf16rn(w);  float r1 = w  - bf16tof(b1);
    unsigned short b2 = bf16rn(r1); float r2 = r1 - bf16tof(b2);
    unsigned short b3 = bf16rn(r2);
    int cs = n >> 5, c = n & 31, kc = k >> 5, kg = (k >> 3) & 3, e = k & 7;
    size_t off = (size_t)cs * 12288 + kc * 1024 + c * 32 + kg * 8 + e;
    Wt[off] = b1; Wt[off + 4096] = b2; Wt[off + 8192] = b3;
}

#define SIXPASS(B00,B01,B10,B11,B20,B21) \
    acc0 = __builtin_amdgcn_mfma_f32_16x16x32_bf16(A0[kc], B00, acc0, 0, 0, 0); \
    acc1 = __builtin_amdgcn_mfma_f32_16x16x32_bf16(A0[kc], B01, acc1, 0, 0, 0); \
    acc0 = __builtin_amdgcn_mfma_f32_16x16x32_bf16(A0[kc], B10, acc0, 0, 0, 0); \
    acc1 = __builtin_amdgcn_mfma_f32_16x16x32_bf16(A0[kc], B11, acc1, 0, 0, 0); \
    acc0 = __builtin_amdgcn_mfma_f32_16x16x32_bf16(A1[kc], B00, acc0, 0, 0, 0); \
    acc1 = __builtin_amdgcn_mfma_f32_16x16x32_bf16(A1[kc], B01, acc1, 0, 0, 0); \
    acc0 = __builtin_amdgcn_mfma_f32_16x16x32_bf16(A0[kc], B20, acc0, 0, 0, 0); \
    acc1 = __builtin_amdgcn_mfma_f32_16x16x32_bf16(A0[kc], B21, acc1, 0, 0, 0); \
    acc0 = __builtin_amdgcn_mfma_f32_16x16x32_bf16(A1[kc], B10, acc0, 0, 0, 0); \
    acc1 = __builtin_amdgcn_mfma_f32_16x16x32_bf16(A1[kc], B11, acc1, 0, 0, 0); \
    acc0 = __builtin_amdgcn_mfma_f32_16x16x32_bf16(A2[kc], B00, acc0, 0, 0, 0); \
    acc1 = __builtin_amdgcn_mfma_f32_16x16x32_bf16(A2[kc], B01, acc1, 0, 0, 0);

// ---------------- kNN via MFMA (unchanged from round 3) ----------------
__global__ __launch_bounds__(256) void knn_mfma(const unsigned short* __restrict__ hs,
                                                const float* __restrict__ sqg,
                                                float* __restrict__ cand_d,
                                                int* __restrict__ cand_i)
{
    __shared__ ulong2 ldsraw[3200];
    char* ldsc = (char*)ldsraw;
    float* sqs = (float*)(ldsc + 49152);

    const size_t plane = (size_t)NTOT * HD;
    const int t = threadIdx.x;
    const int b = blockIdx.x;
    const int slot = b >> 3;
    const int g   = (b & 7) | ((slot & 1) << 3);
    const int rb  = (slot >> 1) & 31;
    const int cs  = slot >> 6;
    const int gbase = g * NPG;
    const int cbase = cs * 512;
    const int wv = t >> 6, lane = t & 63;
    const int row0 = rb * 64 + wv * 16;
    const int lrow = lane & 15, kgrp = lane >> 4;

    sqs[t]       = sqg[gbase + cbase + t];
    sqs[t + 256] = sqg[gbase + cbase + 256 + t];

    const unsigned short* arow = hs + (size_t)(gbase + row0 + lrow) * HD + kgrp * 8;
    bf16x8 A0[4], A1[4], A2[4];
#pragma unroll
    for (int kc = 0; kc < 4; ++kc) {
        A0[kc] = *(const bf16x8*)(arow + kc * 32);
        A1[kc] = *(const bf16x8*)(arow + plane + kc * 32);
        A2[kc] = *(const bf16x8*)(arow + 2 * plane + kc * 32);
    }
    float sqi4[4];
#pragma unroll
    for (int r = 0; r < 4; ++r)
        sqi4[r] = sqg[gbase + row0 + kgrp * 4 + r];

    const int col_t  = (t >> 2) & 31;
    const int kgrp_t = t & 3;
    const unsigned short* sbase[6];
#pragma unroll
    for (int i = 0; i < 6; ++i) {
        int p  = i >> 1;
        int kc = (i & 1) * 2 + (t >> 7);
        sbase[i] = hs + (size_t)p * plane + (size_t)(gbase + cbase + col_t) * HD
                 + kc * 32 + kgrp_t * 8;
    }
    char* ldsw = ldsc + wv * 1024;

#pragma unroll
    for (int i = 0; i < 6; ++i)
        GLOAD_LDS16(sbase[i], ldsw + i * 4096);
    __syncthreads();

    const float INF = __uint_as_float(0x7F800000u);
    float bd[4][8];
    int   bi[4][8];
#pragma unroll
    for (int r = 0; r < 4; ++r)
#pragma unroll
        for (int s = 0; s < 8; ++s) { bd[r][s] = INF; bi[r][s] = 0x7fffffff; }

    int cur = 0;
    for (int s = 0; s < 16; ++s) {
        if (s < 15) {
#pragma unroll
            for (int i = 0; i < 6; ++i) {
                sbase[i] += 32 * HD;
                GLOAD_LDS16(sbase[i], ldsw + (cur ^ 1) * 24576 + i * 4096);
            }
        }
        const char* pb = ldsc + cur * 24576 + lrow * 64 + kgrp * 16;
        float sqj0 = sqs[s * 32 + lrow];
        float sqj1 = sqs[s * 32 + 16 + lrow];
        f32x4 acc0 = {0.f,0.f,0.f,0.f};
        f32x4 acc1 = {0.f,0.f,0.f,0.f};
#pragma unroll
        for (int kc = 0; kc < 4; ++kc) {
            const char* pk = pb + kc * 2048;
            bf16x8 b0h0 = *(const bf16x8*)(pk);
            bf16x8 b0h1 = *(const bf16x8*)(pk + 1024);
            bf16x8 b1h0 = *(const bf16x8*)(pk + 8192);
            bf16x8 b1h1 = *(const bf16x8*)(pk + 8192 + 1024);
            bf16x8 b2h0 = *(const bf16x8*)(pk + 16384);
            bf16x8 b2h1 = *(const bf16x8*)(pk + 16384 + 1024);
            SIXPASS(b0h0, b0h1, b1h0, b1h1, b2h0, b2h1)
        }
        int j0 = cbase + s * 32 + lrow, j1 = j0 + 16;
#pragma unroll
        for (int r = 0; r < 4; ++r) {
            float d0 = fmaf(-2.f, acc0[r], sqi4[r] + sqj0);
            if (d0 < bd[r][7]) {
#pragma unroll
                for (int q = 7; q > 0; --q) {
                    bool up   = d0 < bd[r][q-1];
                    bool here = (!up) && (d0 < bd[r][q]);
                    float nd = up ? bd[r][q-1] : (here ? d0 : bd[r][q]);
                    int   ni = up ? bi[r][q-1] : (here ? j0 : bi[r][q]);
                    bd[r][q] = nd; bi[r][q] = ni;
                }
                if (d0 < bd[r][0]) { bd[r][0] = d0; bi[r][0] = j0; }
            }
            float d1 = fmaf(-2.f, acc1[r], sqi4[r] + sqj1);
            if (d1 < bd[r][7]) {
#pragma unroll
                for (int q = 7; q > 0; --q) {
                    bool up   = d1 < bd[r][q-1];
                    bool here = (!up) && (d1 < bd[r][q]);
                    float nd = up ? bd[r][q-1] : (here ? d1 : bd[r][q]);
                    int   ni = up ? bi[r][q-1] : (here ? j1 : bi[r][q]);
                    bd[r][q] = nd; bi[r][q] = ni;
                }
                if (d1 < bd[r][0]) { bd[r][0] = d1; bi[r][0] = j1; }
            }
        }
        __syncthreads();
        cur ^= 1;
    }

#pragma unroll
    for (int r = 0; r < 4; ++r) {
        float hd = bd[r][0]; int hi = bi[r][0];
        const size_t growout = (size_t)(gbase + row0 + kgrp * 4 + r) * 32 + cs * 8;
#pragma unroll
        for (int sel = 0; sel < 8; ++sel) {
            float md = hd; int mi = hi;
#pragma unroll
            for (int m = 1; m < 16; m <<= 1) {
                float od = __shfl_xor(md, m, 16);
                int   oi = __shfl_xor(mi, m, 16);
                bool tk = (od < md) || (od == md && oi < mi);
                md = tk ? od : md; mi = tk ? oi : mi;
            }
            if (lrow == sel) {
                cand_d[growout + sel] = md;
                cand_i[growout + sel] = gbase + mi;
            }
            bool win = (hd == md) && (hi == mi);
            if (win) {
                bd[r][0]=bd[r][1]; bi[r][0]=bi[r][1];
                bd[r][1]=bd[r][2]; bi[r][1]=bi[r][2];
                bd[r][2]=bd[r][3]; bi[r][2]=bi[r][3];
                bd[r][3]=bd[r][4]; bi[r][3]=bi[r][4];
                bd[r][4]=bd[r][5]; bi[r][4]=bi[r][5];
                bd[r][5]=bd[r][6]; bi[r][5]=bi[r][6];
                bd[r][6]=bd[r][7]; bi[r][6]=bi[r][7];
                bd[r][7]=INF;      bi[r][7]=0x7fffffff;
            }
            hd = bd[r][0]; hi = bi[r][0];
        }
    }
}

__global__ __launch_bounds__(256) void knn_merge(const float* __restrict__ cand_d,
                                                 const int* __restrict__ cand_i,
                                                 int* __restrict__ nbr)
{
    int row = blockIdx.x * 256 + threadIdx.x;
    const float* pd = cand_d + (size_t)row * 32;
    const int*   pi = cand_i + (size_t)row * 32;
    float d[32]; int ix[32];
#pragma unroll
    for (int k = 0; k < 32; ++k) { d[k] = pd[k]; ix[k] = pi[k]; }
    int* op = nbr + (size_t)row * KNN;
    const float INF = __uint_as_float(0x7F800000u);
#pragma unroll
    for (int sel = 0; sel < 8; ++sel) {
        float md = d[0]; int mi = ix[0];
#pragma unroll
        for (int k = 1; k < 32; ++k) {
            bool tk = (d[k] < md) || (d[k] == md && ix[k] < mi);
            md = tk ? d[k] : md; mi = tk ? ix[k] : mi;
        }
        op[sel] = mi;
#pragma unroll
        for (int k = 0; k < 32; ++k) {
            bool rm = (d[k] == md) && (ix[k] == mi);
            d[k] = rm ? INF : d[k];
        }
    }
}

// ---------------- node GEMM: P = h@Wa_bot ; D = h@(Wa_top-Wa_bot) + ba ----------------
// Block: 4 waves x 16 nodes = 64 nodes. N=256 (cs 0-3 -> P, cs 4-7 -> D).
__global__ __launch_bounds__(256) void node_gemm(const unsigned short* __restrict__ hs,
                                                 const unsigned short* __restrict__ Wt,
                                                 const float* __restrict__ ba,
                                                 float* __restrict__ P,
                                                 float* __restrict__ D)
{
    __shared__ char lds[49152];
    const size_t plane = (size_t)NTOT * HD;
    const int t = threadIdx.x, wv = t >> 6, lane = t & 63;
    const int lrow = lane & 15, kg = lane >> 4;
    const int nodebase = blockIdx.x * 64 + wv * 16;

    const unsigned short* arow = hs + (size_t)(nodebase + lrow) * HD + kg * 8;
    bf16x8 A0[4], A1[4], A2[4];
#pragma unroll
    for (int kc = 0; kc < 4; ++kc) {
        A0[kc] = *(const bf16x8*)(arow + kc * 32);
        A1[kc] = *(const bf16x8*)(arow + plane + kc * 32);
        A2[kc] = *(const bf16x8*)(arow + 2 * plane + kc * 32);
    }

    char* ldsw = lds + wv * 1024;
    const unsigned short* wsrc = Wt + t * 8;
#pragma unroll
    for (int i = 0; i < 6; ++i)
        GLOAD_LDS16(wsrc + i * 2048, ldsw + i * 4096);
    __syncthreads();

    int cur = 0;
    for (int cs = 0; cs < 8; ++cs) {
        if (cs < 7) {
#pragma unroll
            for (int i = 0; i < 6; ++i)
                GLOAD_LDS16(wsrc + (size_t)(cs + 1) * 12288 + i * 2048,
                            ldsw + (cur ^ 1) * 24576 + i * 4096);
        }
        const char* pb = lds + cur * 24576 + lrow * 64 + kg * 16;
        f32x4 acc0 = {0.f,0.f,0.f,0.f};
        f32x4 acc1 = {0.f,0.f,0.f,0.f};
#pragma unroll
        for (int kc = 0; kc < 4; ++kc) {
            const char* pk = pb + kc * 2048;
            bf16x8 b00 = *(const bf16x8*)(pk);
            bf16x8 b01 = *(const bf16x8*)(pk + 1024);
            bf16x8 b10 = *(const bf16x8*)(pk + 8192);
            bf16x8 b11 = *(const bf16x8*)(pk + 9216);
            bf16x8 b20 = *(const bf16x8*)(pk + 16384);
            bf16x8 b21 = *(const bf16x8*)(pk + 17408);
            SIXPASS(b00, b01, b10, b11, b20, b21)
        }
        int n0 = cs * 32 + lrow;
        if (cs < 4) {
#pragma unroll
            for (int r = 0; r < 4; ++r) {
                size_t row = (size_t)(nodebase + kg * 4 + r) * HD;
                P[row + n0]      = acc0[r];
                P[row + n0 + 16] = acc1[r];
            }
        } else {
            float ba0 = ba[n0 - 128], ba1 = ba[n0 - 112];
#pragma unroll
            for (int r = 0; r < 4; ++r) {
                size_t row = (size_t)(nodebase + kg * 4 + r) * HD;
                D[row + n0 - 128] = acc0[r] + ba0;
                D[row + n0 - 112] = acc1[r] + ba1;
            }
        }
        __syncthreads();
        cur ^= 1;
    }
}

// ---------------- fused edge kernel: H1=relu(D[i]+P[j]) -> GEMM2 -> max -> out ----------------
// Block: 8 nodes = 64 edges; 4 waves x 16 edges (2 nodes each).
template<bool FINAL>
__global__ __launch_bounds__(256) void edge_mlp(const float* __restrict__ P,
                                                const float* __restrict__ D,
                                                const int* __restrict__ nbr,
                                                const unsigned short* __restrict__ Wbt,
                                                const float* __restrict__ bb,
                                                const float* __restrict__ w5,
                                                float* __restrict__ out)
{
    __shared__ char lds[49152];
    const int t = threadIdx.x, wv = t >> 6, lane = t & 63;
    const int lrow = lane & 15, kg = lane >> 4;
    const int nodeA = blockIdx.x * 8 + wv * 2;
    const int i_node = nodeA + (lrow >> 3);
    const int j = nbr[(size_t)i_node * KNN + (lrow & 7)];

    const float* dp = D + (size_t)i_node * HD + kg * 8;
    const float* pp = P + (size_t)j * HD + kg * 8;

    bf16x8 A0[4], A1[4], A2[4];
    float sdot = 0.f;
#pragma unroll
    for (int kc = 0; kc < 4; ++kc) {
        float4 d0 = *(const float4*)(dp + kc * 32);
        float4 d1 = *(const float4*)(dp + kc * 32 + 4);
        float4 p0 = *(const float4*)(pp + kc * 32);
        float4 p1 = *(const float4*)(pp + kc * 32 + 4);
        float v[8];
        v[0]=fmaxf(d0.x+p0.x,0.f); v[1]=fmaxf(d0.y+p0.y,0.f);
        v[2]=fmaxf(d0.z+p0.z,0.f); v[3]=fmaxf(d0.w+p0.w,0.f);
        v[4]=fmaxf(d1.x+p1.x,0.f); v[5]=fmaxf(d1.y+p1.y,0.f);
        v[6]=fmaxf(d1.z+p1.z,0.f); v[7]=fmaxf(d1.w+p1.w,0.f);
        if (FINAL) {
#pragma unroll
            for (int e = 0; e < 8; ++e)
                sdot = fmaf(v[e], w5[kc * 32 + kg * 8 + e], sdot);
        } else {
#pragma unroll
            for (int e = 0; e < 8; ++e) {
                unsigned short b1 = bf16rn(v[e]); float r1 = v[e] - bf16tof(b1);
                unsigned short b2 = bf16rn(r1);   float r2 = r1   - bf16tof(b2);
                unsigned short b3 = bf16rn(r2);
                A0[kc][e] = (short)b1; A1[kc][e] = (short)b2; A2[kc][e] = (short)b3;
            }
        }
    }

    if (!FINAL) {
        char* ldsw = lds + wv * 1024;
        const unsigned short* wsrc = Wbt + t * 8;
#pragma unroll
        for (int i = 0; i < 6; ++i)
            GLOAD_LDS16(wsrc + i * 2048, ldsw + i * 4096);
        __syncthreads();

        int cur = 0;
        for (int cs = 0; cs < 4; ++cs) {
            if (cs < 3) {
#pragma unroll
                for (int i = 0; i < 6; ++i)
                    GLOAD_LDS16(wsrc + (size_t)(cs + 1) * 12288 + i * 2048,
                                ldsw + (cur ^ 1) * 24576 + i * 4096);
            }
            const char* pb = lds + cur * 24576 + lrow * 64 + kg * 16;
            f32x4 acc0 = {0.f,0.f,0.f,0.f};
            f32x4 acc1 = {0.f,0.f,0.f,0.f};
#pragma unroll
            for (int kc = 0; kc < 4; ++kc) {
                const char* pk = pb + kc * 2048;
                bf16x8 b00 = *(const bf16x8*)(pk);
                bf16x8 b01 = *(const bf16x8*)(pk + 1024);
                bf16x8 b10 = *(const bf16x8*)(pk + 8192);
                bf16x8 b11 = *(const bf16x8*)(pk + 9216);
                bf16x8 b20 = *(const bf16x8*)(pk + 16384);
                bf16x8 b21 = *(const bf16x8*)(pk + 17408);
                SIXPASS(b00, b01, b10, b11, b20, b21)
            }
            // epilogue: bias, relu, max over 8 edges/node, store
            float bb0 = bb[cs * 32 + lrow];
            float bb1 = bb[cs * 32 + 16 + lrow];
            float m0 = fmaxf(fmaxf(acc0[0], acc0[1]), fmaxf(acc0[2], acc0[3]));
            float m1 = fmaxf(fmaxf(acc1[0], acc1[1]), fmaxf(acc1[2], acc1[3]));
            m0 = fmaxf(m0 + bb0, 0.f);
            m1 = fmaxf(m1 + bb1, 0.f);
            m0 = fmaxf(m0, __shfl_xor(m0, 16));
            m1 = fmaxf(m1, __shfl_xor(m1, 16));
            if (kg == 0) {
                out[(size_t)nodeA * HD + cs * 32 + lrow]      = m0;
                out[(size_t)nodeA * HD + cs * 32 + 16 + lrow] = m1;
            } else if (kg == 2) {
                out[(size_t)(nodeA + 1) * HD + cs * 32 + lrow]      = m0;
                out[(size_t)(nodeA + 1) * HD + cs * 32 + 16 + lrow] = m1;
            }
            __syncthreads();
            cur ^= 1;
        }
    } else {
        sdot += __shfl_xor(sdot, 16);
        sdot += __shfl_xor(sdot, 32);
        float s = fmaxf(sdot + bb[0], 0.f);
#pragma unroll
        for (int m = 1; m < 8; m <<= 1)
            s = fmaxf(s, __shfl_xor(s, m));
        if (lane == 0) out[nodeA]     = 1.f / (1.f + expf(-s));
        if (lane == 8) out[nodeA + 1] = 1.f / (1.f + expf(-s));
    }
}

extern "C" void kernel_launch(void* const* d_in, const int* in_sizes, int n_in,
                              void* d_out, int out_size, void* d_ws, size_t ws_size,
                              hipStream_t stream) {
    const float* x     = (const float*)d_in[0];
    const float* W_enc = (const float*)d_in[3];
    const float* b_enc = (const float*)d_in[4];
    const float* W1a = (const float*)d_in[5];
    const float* b1a = (const float*)d_in[6];
    const float* W1b = (const float*)d_in[7];
    const float* b1b = (const float*)d_in[8];
    const float* W2a = (const float*)d_in[9];
    const float* b2a = (const float*)d_in[10];
    const float* W2b = (const float*)d_in[11];
    const float* b2b = (const float*)d_in[12];
    const float* W5a = (const float*)d_in[13];
    const float* b5a = (const float*)d_in[14];
    const float* W5b = (const float*)d_in[15];
    const float* b5b = (const float*)d_in[16];

    float* h0   = (float*)d_ws;                                  // 16 MB
    float* h1   = h0 + (size_t)NTOT*HD;                          // 16 MB
    float* sqg  = h1 + (size_t)NTOT*HD;                          // 128 KB
    int*   idxb = (int*)(sqg + NTOT);                            // 1 MB
    unsigned short* hs = (unsigned short*)(idxb + (size_t)NTOT*KNN);  // 24 MB
    float* Dbuf = (float*)(hs + (size_t)3*NTOT*HD);              // 16 MB
    unsigned short* Wt1  = (unsigned short*)(Dbuf + (size_t)NTOT*HD);
    unsigned short* Wt2  = Wt1 + 98304;
    unsigned short* Wt5  = Wt2 + 98304;
    unsigned short* Wbt1 = Wt5 + 98304;
    unsigned short* Wbt2 = Wbt1 + 49152;

    // cand buffers overlay Dbuf (written by node_gemm AFTER merge consumed them)
    float* cd = Dbuf;
    int*   ci = (int*)(Dbuf + (size_t)NTOT*32);

    // weight prep (cheap, every call)
    prep_wcat<<<128, 256, 0, stream>>>(W1a, Wt1);
    prep_wcat<<<128, 256, 0, stream>>>(W2a, Wt2);
    prep_wcat<<<128, 256, 0, stream>>>(W5a, Wt5);
    prep_wb  <<< 64, 256, 0, stream>>>(W1b, Wbt1);
    prep_wb  <<< 64, 256, 0, stream>>>(W2b, Wbt2);

    enc_kernel<<<NTOT*HD/256, 256, 0, stream>>>(x, W_enc, b_enc, h0);

    // layer 1: h0 -> h1   (P overlays h0 after split)
    split_kernel<<<NTOT/4, 256, 0, stream>>>(h0, hs, sqg);
    knn_mfma   <<<BGR*128, 256, 0, stream>>>(hs, sqg, cd, ci);
    knn_merge  <<<NTOT/256, 256, 0, stream>>>(cd, ci, idxb);
    node_gemm  <<<NTOT/64, 256, 0, stream>>>(hs, Wt1, b1a, h0, Dbuf);
    edge_mlp<false><<<NTOT/8, 256, 0, stream>>>(h0, Dbuf, idxb, Wbt1, b1b, nullptr, h1);

    // layer 2: h1 -> h0
    split_kernel<<<NTOT/4, 256, 0, stream>>>(h1, hs, sqg);
    knn_mfma   <<<BGR*128, 256, 0, stream>>>(hs, sqg, cd, ci);
    knn_merge  <<<NTOT/256, 256, 0, stream>>>(cd, ci, idxb);
    node_gemm  <<<NTOT/64, 256, 0, stream>>>(hs, Wt2, b2a, h1, Dbuf);
    edge_mlp<false><<<NTOT/8, 256, 0, stream>>>(h1, Dbuf, idxb, Wbt2, b2b, nullptr, h0);

    // layer 5: h0 -> d_out
    split_kernel<<<NTOT/4, 256, 0, stream>>>(h0, hs, sqg);
    knn_mfma   <<<BGR*128, 256, 0, stream>>>(hs, sqg, cd, ci);
    knn_merge  <<<NTOT/256, 256, 0, stream>>>(cd, ci, idxb);
    node_gemm  <<<NTOT/64, 256, 0, stream>>>(hs, Wt5, b5a, h0, Dbuf);
    edge_mlp<true><<<NTOT/8, 256, 0, stream>>>(h0, Dbuf, idxb, nullptr, b5b, W5b, (float*)d_out);
}

// Round 5
// 685.635 us; speedup vs baseline: 3.6508x; 1.2009x over previous
//
#include <hip/hip_runtime.h>
#include <hip/hip_bf16.h>
#include <math.h>

#define BGR 16
#define NPG 2048
#define HD  128
#define KNN 8
#define NTOT (BGR*NPG)   // 32768

using bf16x8 = __attribute__((ext_vector_type(8))) short;
using f32x4  = __attribute__((ext_vector_type(4))) float;
using f32x16 = __attribute__((ext_vector_type(16))) float;

typedef __attribute__((address_space(3))) unsigned int lds_uint;
typedef const __attribute__((address_space(1))) unsigned int glob_uint;
#define GLOAD_LDS16(g, l) __builtin_amdgcn_global_load_lds((glob_uint*)(g), (lds_uint*)(l), 16, 0, 0)

__device__ inline unsigned short bf16rn(float f) {
    unsigned u = __float_as_uint(f);
    unsigned r = (u + 0x7FFFu + ((u >> 16) & 1u)) >> 16;
    return (unsigned short)r;
}
__device__ inline float bf16tof(unsigned short h) {
    return __uint_as_float(((unsigned)h) << 16);
}

// ---------------- encoder ----------------
__global__ __launch_bounds__(256) void enc_kernel(const float* __restrict__ x,
                                                  const float* __restrict__ W,
                                                  const float* __restrict__ bias,
                                                  float* __restrict__ hout)
{
    int gid = blockIdx.x * 256 + threadIdx.x;
    int n = gid >> 7, o = gid & 127;
    float s = bias[o];
#pragma unroll
    for (int f = 0; f < 4; ++f)
        s = fmaf(x[n*4 + f], W[f*128 + o], s);
    hout[gid] = s;
}

// ---------------- exact f32 sq-norm + 3-way bf16 split ----------------
__global__ __launch_bounds__(256) void split_kernel(const float* __restrict__ h,
                                                    unsigned short* __restrict__ hs,
                                                    float* __restrict__ sqg)
{
    const size_t plane = (size_t)NTOT * HD;
    int node = (blockIdx.x * 256 + threadIdx.x) >> 6;
    int lane = threadIdx.x & 63;
    const float* hp = h + (size_t)node * HD;
    float v0 = hp[lane], v1 = hp[lane + 64];
    float s = fmaf(v0, v0, v1 * v1);
#pragma unroll
    for (int off = 32; off >= 1; off >>= 1)
        s += __shfl_xor(s, off);
    if (lane == 0) sqg[node] = s;
#pragma unroll
    for (int q = 0; q < 2; ++q) {
        float v = q ? v1 : v0;
        int   d = lane + q * 64;
        unsigned short b1 = bf16rn(v);  float r1 = v  - bf16tof(b1);
        unsigned short b2 = bf16rn(r1); float r2 = r1 - bf16tof(b2);
        unsigned short b3 = bf16rn(r2);
        size_t base = (size_t)node * HD + d;
        hs[base]             = b1;
        hs[base + plane]     = b2;
        hs[base + 2 * plane] = b3;
    }
}

// ---------------- weight prep: tile+split for LDS staging ----------------
// NEW conflict-free layout per cs-block (12288 elems = 24KB):
//   elem off = kc*1024 + h*512 + kg*128 + c*8 + e   (n = cs*32 + h*16 + c, k = kc*32+kg*8+e)
//   -> LDS byte = kc*2048 + h*1024 + kg*256 + c*16 + e*2; a wave's ds_read_b128 at
//      kgrp*256 + lrow*16 is a contiguous 1KB: conflict-free. Planes at +4096 elems.
__global__ __launch_bounds__(256) void prep_wcat(const float* __restrict__ Wa,
                                                 unsigned short* __restrict__ Wt)
{
    int gid = blockIdx.x * 256 + threadIdx.x;   // 32768 = 128k x 256n
    int k = gid >> 8, n = gid & 255;
    float w;
    if (n < 128) w = Wa[(128 + k) * 128 + n];
    else { int nn = n - 128; w = Wa[k * 128 + nn] - Wa[(128 + k) * 128 + nn]; }
    unsigned short b1 = bf16rn(w);  float r1 = w  - bf16tof(b1);
    unsigned short b2 = bf16rn(r1); float r2 = r1 - bf16tof(b2);
    unsigned short b3 = bf16rn(r2);
    int cs = n >> 5, h = (n >> 4) & 1, c = n & 15, kc = k >> 5, kg = (k >> 3) & 3, e = k & 7;
    size_t off = (size_t)cs * 12288 + kc * 1024 + h * 512 + kg * 128 + c * 8 + e;
    Wt[off] = b1; Wt[off + 4096] = b2; Wt[off + 8192] = b3;
}

__global__ __launch_bounds__(256) void prep_wb(const float* __restrict__ Wb,
                                               unsigned short* __restrict__ Wt)
{
    int gid = blockIdx.x * 256 + threadIdx.x;   // 16384 = 128k x 128n
    int k = gid >> 7, n = gid & 127;
    float w = Wb[k * 128 + n];
    unsigned short b1 = bf16rn(w);  float r1 = w  - bf16tof(b1);
    unsigned short b2 = bf16rn(r1); float r2 = r1 - bf16tof(b2);
    unsigned short b3 = bf16rn(r2);
    int cs = n >> 5, h = (n >> 4) & 1, c = n & 15, kc = k >> 5, kg = (k >> 3) & 3, e = k & 7;
    size_t off = (size_t)cs * 12288 + kc * 1024 + h * 512 + kg * 128 + c * 8 + e;
    Wt[off] = b1; Wt[off + 4096] = b2; Wt[off + 8192] = b3;
}

#define SIXPASS(B00,B01,B10,B11,B20,B21) \
    acc0 = __builtin_amdgcn_mfma_f32_16x16x32_bf16(A0[kc], B00, acc0, 0, 0, 0); \
    acc1 = __builtin_amdgcn_mfma_f32_16x16x32_bf16(A0[kc], B01, acc1, 0, 0, 0); \
    acc0 = __builtin_amdgcn_mfma_f32_16x16x32_bf16(A0[kc], B10, acc0, 0, 0, 0); \
    acc1 = __builtin_amdgcn_mfma_f32_16x16x32_bf16(A0[kc], B11, acc1, 0, 0, 0); \
    acc0 = __builtin_amdgcn_mfma_f32_16x16x32_bf16(A1[kc], B00, acc0, 0, 0, 0); \
    acc1 = __builtin_amdgcn_mfma_f32_16x16x32_bf16(A1[kc], B01, acc1, 0, 0, 0); \
    acc0 = __builtin_amdgcn_mfma_f32_16x16x32_bf16(A0[kc], B20, acc0, 0, 0, 0); \
    acc1 = __builtin_amdgcn_mfma_f32_16x16x32_bf16(A0[kc], B21, acc1, 0, 0, 0); \
    acc0 = __builtin_amdgcn_mfma_f32_16x16x32_bf16(A1[kc], B10, acc0, 0, 0, 0); \
    acc1 = __builtin_amdgcn_mfma_f32_16x16x32_bf16(A1[kc], B11, acc1, 0, 0, 0); \
    acc0 = __builtin_amdgcn_mfma_f32_16x16x32_bf16(A2[kc], B00, acc0, 0, 0, 0); \
    acc1 = __builtin_amdgcn_mfma_f32_16x16x32_bf16(A2[kc], B01, acc1, 0, 0, 0);

// ---------------- kNN via 32x32x16 MFMA, rows-in-regs as B operand ----------------
// Block: 4 waves x 32 rows = 128 rows; cols slice = 512 (16 steps x 32).
// LDS per 24KB buffer (cols = A operand): [p(3)][kch(8)][kh(2)][col(32)][e(8)] bf16
//   -> read addr for (p,kch) = base + p*8192 + kch*1024 + lane*16 : contiguous 1KB.
// Rows (xi * -2, exact) live in VGPRs as the B operand. C map (32x32):
//   col=lane&31 -> row-node (one row per lane!), row=(reg&3)+8*(reg>>2)+4*(lane>>5) -> col-node.
// acc accumulates -2*dot; selection key dp = sqj + acc (sqi const per lane, added at end).
__global__ __launch_bounds__(256) void knn_mfma(const unsigned short* __restrict__ hs,
                                                const float* __restrict__ sqg,
                                                float* __restrict__ cand_d,
                                                int* __restrict__ cand_i)
{
    __shared__ ulong2 ldsraw[3200];   // 48KB dbuf + 2KB sq
    char* ldsc = (char*)ldsraw;
    float* sqs = (float*)(ldsc + 49152);

    const size_t plane = (size_t)NTOT * HD;
    const int t = threadIdx.x;
    const int b = blockIdx.x;           // 1024 blocks
    const int slot = b >> 3;
    const int g  = (b & 7) | ((slot & 1) << 3);
    const int rb = (slot >> 1) & 15;
    const int cs = (slot >> 5) & 3;
    const int gbase = g * NPG;
    const int cbase = cs * 512;
    const int wv = t >> 6, lane = t & 63;
    const int rl = lane & 31, kh = lane >> 5;
    const int myrow = rb * 128 + wv * 32 + rl;

    sqs[t]       = sqg[gbase + cbase + t];
    sqs[t + 256] = sqg[gbase + cbase + 256 + t];

    // row operand (B): hs * (-2), exact via exponent+1 & sign-flip (0 -> -2^-126, harmless)
    bf16x8 RB[3][8];
    {
        const unsigned short* rrow = hs + (size_t)(gbase + myrow) * HD + kh * 8;
#pragma unroll
        for (int p = 0; p < 3; ++p)
#pragma unroll
            for (int kch = 0; kch < 8; ++kch) {
                bf16x8 v = *(const bf16x8*)(rrow + (size_t)p * plane + kch * 16);
                unsigned* u = (unsigned*)&v;
#pragma unroll
                for (int w = 0; w < 4; ++w)
                    u[w] = (u[w] + 0x00800080u) ^ 0x80008000u;
                RB[p][kch] = v;
            }
    }
    const float sqi = sqg[gbase + myrow];

    // staging: thread t stages chunk i in [0,6): p=i>>1, kch=(i&1)*4+(t>>6);
    // within-1KB slot: kh_t=(t>>5)&1, col_t=t&31; dest byte = i*4096 + t*16 (linear).
    const int col_t = t & 31, kh_t = (t >> 5) & 1, tt = t >> 6;
    const unsigned short* sbase[6];
#pragma unroll
    for (int i = 0; i < 6; ++i) {
        int p = i >> 1, kch = (i & 1) * 4 + tt;
        sbase[i] = hs + (size_t)p * plane + (size_t)(gbase + cbase + col_t) * HD
                 + kch * 16 + kh_t * 8;
    }
    char* ldsw = ldsc + wv * 1024;

#pragma unroll
    for (int i = 0; i < 6; ++i)
        GLOAD_LDS16(sbase[i], ldsw + i * 4096);
    __syncthreads();

    const float INF = __uint_as_float(0x7F800000u);
    float bd[8];
    int   bi[8];
#pragma unroll
    for (int s = 0; s < 8; ++s) { bd[s] = INF; bi[s] = 0x7fffffff; }

    int cur = 0;
    for (int s = 0; s < 16; ++s) {
        if (s < 15) {
#pragma unroll
            for (int i = 0; i < 6; ++i) {
                sbase[i] += 32 * HD;
                GLOAD_LDS16(sbase[i], ldsw + (cur ^ 1) * 24576 + i * 4096);
            }
        }
        const char* pstep = ldsc + cur * 24576 + lane * 16;
        f32x16 acc = {0.f,0.f,0.f,0.f,0.f,0.f,0.f,0.f,0.f,0.f,0.f,0.f,0.f,0.f,0.f,0.f};
#pragma unroll
        for (int kch = 0; kch < 8; ++kch) {
            bf16x8 c0 = *(const bf16x8*)(pstep + kch * 1024);
            bf16x8 c1 = *(const bf16x8*)(pstep + 8192 + kch * 1024);
            bf16x8 c2 = *(const bf16x8*)(pstep + 16384 + kch * 1024);
            acc = __builtin_amdgcn_mfma_f32_32x32x16_bf16(c0, RB[0][kch], acc, 0, 0, 0);
            acc = __builtin_amdgcn_mfma_f32_32x32x16_bf16(c0, RB[1][kch], acc, 0, 0, 0);
            acc = __builtin_amdgcn_mfma_f32_32x32x16_bf16(c1, RB[0][kch], acc, 0, 0, 0);
            acc = __builtin_amdgcn_mfma_f32_32x32x16_bf16(c1, RB[1][kch], acc, 0, 0, 0);
            acc = __builtin_amdgcn_mfma_f32_32x32x16_bf16(c2, RB[0][kch], acc, 0, 0, 0);
            acc = __builtin_amdgcn_mfma_f32_32x32x16_bf16(c0, RB[2][kch], acc, 0, 0, 0);
        }
        // selection: col-node for reg = grp*4+e is s*32 + grp*8 + kh*4 + e (ascending in reg)
#pragma unroll
        for (int grp = 0; grp < 4; ++grp) {
            f32x4 sq4 = *(const f32x4*)(sqs + s * 32 + grp * 8 + kh * 4);
#pragma unroll
            for (int e = 0; e < 4; ++e) {
                float dp = sq4[e] + acc[grp * 4 + e];
                int j = cbase + s * 32 + grp * 8 + kh * 4 + e;
                if (dp < bd[7]) {
#pragma unroll
                    for (int q = 7; q > 0; --q) {
                        bool up   = dp < bd[q-1];
                        bool here = (!up) && (dp < bd[q]);
                        float nd = up ? bd[q-1] : (here ? dp : bd[q]);
                        int   ni = up ? bi[q-1] : (here ? j  : bi[q]);
                        bd[q] = nd; bi[q] = ni;
                    }
                    if (dp < bd[0]) { bd[0] = dp; bi[0] = j; }
                }
            }
        }
        __syncthreads();
        cur ^= 1;
    }

    // each lane writes its own sorted run of 8 (row, col-half kh, slice cs)
    const size_t ob = (size_t)(gbase + myrow) * 64 + cs * 16 + kh * 8;
#pragma unroll
    for (int sel = 0; sel < 8; ++sel) {
        cand_d[ob + sel] = sqi + bd[sel];
        cand_i[ob + sel] = gbase + bi[sel];
    }
}

// ---------------- merge 8 sorted runs of 8 per row -> final top-8 ----------------
__global__ __launch_bounds__(256) void knn_merge(const float* __restrict__ cand_d,
                                                 const int* __restrict__ cand_i,
                                                 int* __restrict__ nbr)
{
    const int t = threadIdx.x;
    const int row = blockIdx.x * 32 + (t >> 3);
    const int run = t & 7;
    const float* pd = cand_d + (size_t)row * 64 + run * 8;
    const int*   pi = cand_i + (size_t)row * 64 + run * 8;
    float d[8]; int ix[8];
#pragma unroll
    for (int k = 0; k < 8; ++k) { d[k] = pd[k]; ix[k] = pi[k]; }
    const float INF = __uint_as_float(0x7F800000u);
    int* op = nbr + (size_t)row * KNN;
    float hd = d[0]; int hi = ix[0];
#pragma unroll
    for (int sel = 0; sel < 8; ++sel) {
        float md = hd; int mi = hi;
#pragma unroll
        for (int m = 1; m < 8; m <<= 1) {
            float od = __shfl_xor(md, m, 8);
            int   oi = __shfl_xor(mi, m, 8);
            bool tk = (od < md) || (od == md && oi < mi);
            md = tk ? od : md; mi = tk ? oi : mi;
        }
        if (run == sel) op[sel] = mi;
        bool win = (hd == md) && (hi == mi);
        if (win) {
            d[0]=d[1]; ix[0]=ix[1]; d[1]=d[2]; ix[1]=ix[2];
            d[2]=d[3]; ix[2]=ix[3]; d[3]=d[4]; ix[3]=ix[4];
            d[4]=d[5]; ix[4]=ix[5]; d[5]=d[6]; ix[5]=ix[6];
            d[6]=d[7]; ix[6]=ix[7]; d[7]=INF;  ix[7]=0x7fffffff;
        }
        hd = d[0]; hi = ix[0];
    }
}

// ---------------- node GEMM: P = h@Wa_bot ; D = h@(Wa_top-Wa_bot) + ba ----------------
__global__ __launch_bounds__(256) void node_gemm(const unsigned short* __restrict__ hs,
                                                 const unsigned short* __restrict__ Wt,
                                                 const float* __restrict__ ba,
                                                 float* __restrict__ P,
                                                 float* __restrict__ D)
{
    __shared__ char lds[49152];
    const size_t plane = (size_t)NTOT * HD;
    const int t = threadIdx.x, wv = t >> 6, lane = t & 63;
    const int lrow = lane & 15, kg = lane >> 4;
    const int nodebase = blockIdx.x * 64 + wv * 16;

    const unsigned short* arow = hs + (size_t)(nodebase + lrow) * HD + kg * 8;
    bf16x8 A0[4], A1[4], A2[4];
#pragma unroll
    for (int kc = 0; kc < 4; ++kc) {
        A0[kc] = *(const bf16x8*)(arow + kc * 32);
        A1[kc] = *(const bf16x8*)(arow + plane + kc * 32);
        A2[kc] = *(const bf16x8*)(arow + 2 * plane + kc * 32);
    }

    char* ldsw = lds + wv * 1024;
    const unsigned short* wsrc = Wt + t * 8;
#pragma unroll
    for (int i = 0; i < 6; ++i)
        GLOAD_LDS16(wsrc + i * 2048, ldsw + i * 4096);
    __syncthreads();

    int cur = 0;
    for (int cs = 0; cs < 8; ++cs) {
        if (cs < 7) {
#pragma unroll
            for (int i = 0; i < 6; ++i)
                GLOAD_LDS16(wsrc + (size_t)(cs + 1) * 12288 + i * 2048,
                            ldsw + (cur ^ 1) * 24576 + i * 4096);
        }
        const char* pb = lds + cur * 24576 + kg * 256 + lrow * 16;   // conflict-free
        f32x4 acc0 = {0.f,0.f,0.f,0.f};
        f32x4 acc1 = {0.f,0.f,0.f,0.f};
#pragma unroll
        for (int kc = 0; kc < 4; ++kc) {
            const char* pk = pb + kc * 2048;
            bf16x8 b00 = *(const bf16x8*)(pk);
            bf16x8 b01 = *(const bf16x8*)(pk + 1024);
            bf16x8 b10 = *(const bf16x8*)(pk + 8192);
            bf16x8 b11 = *(const bf16x8*)(pk + 9216);
            bf16x8 b20 = *(const bf16x8*)(pk + 16384);
            bf16x8 b21 = *(const bf16x8*)(pk + 17408);
            SIXPASS(b00, b01, b10, b11, b20, b21)
        }
        int n0 = cs * 32 + lrow;
        if (cs < 4) {
#pragma unroll
            for (int r = 0; r < 4; ++r) {
                size_t row = (size_t)(nodebase + kg * 4 + r) * HD;
                P[row + n0]      = acc0[r];
                P[row + n0 + 16] = acc1[r];
            }
        } else {
            float ba0 = ba[n0 - 128], ba1 = ba[n0 - 112];
#pragma unroll
            for (int r = 0; r < 4; ++r) {
                size_t row = (size_t)(nodebase + kg * 4 + r) * HD;
                D[row + n0 - 128] = acc0[r] + ba0;
                D[row + n0 - 112] = acc1[r] + ba1;
            }
        }
        __syncthreads();
        cur ^= 1;
    }
}

// ---------------- fused edge kernel: H1=relu(D[i]+P[j]) -> GEMM2 -> max -> out ----------------
template<bool FINAL>
__global__ __launch_bounds__(256) void edge_mlp(const float* __restrict__ P,
                                                const float* __restrict__ D,
                                                const int* __restrict__ nbr,
                                                const unsigned short* __restrict__ Wbt,
                                                const float* __restrict__ bb,
                                                const float* __restrict__ w5,
                                                float* __restrict__ out)
{
    __shared__ char lds[49152];
    const int t = threadIdx.x, wv = t >> 6, lane = t & 63;
    const int lrow = lane & 15, kg = lane >> 4;
    const int nodeA = blockIdx.x * 8 + wv * 2;
    const int i_node = nodeA + (lrow >> 3);
    const int j = nbr[(size_t)i_node * KNN + (lrow & 7)];

    const float* dp = D + (size_t)i_node * HD + kg * 8;
    const float* pp = P + (size_t)j * HD + kg * 8;

    bf16x8 A0[4], A1[4], A2[4];
    float sdot = 0.f;
#pragma unroll
    for (int kc = 0; kc < 4; ++kc) {
        float4 d0 = *(const float4*)(dp + kc * 32);
        float4 d1 = *(const float4*)(dp + kc * 32 + 4);
        float4 p0 = *(const float4*)(pp + kc * 32);
        float4 p1 = *(const float4*)(pp + kc * 32 + 4);
        float v[8];
        v[0]=fmaxf(d0.x+p0.x,0.f); v[1]=fmaxf(d0.y+p0.y,0.f);
        v[2]=fmaxf(d0.z+p0.z,0.f); v[3]=fmaxf(d0.w+p0.w,0.f);
        v[4]=fmaxf(d1.x+p1.x,0.f); v[5]=fmaxf(d1.y+p1.y,0.f);
        v[6]=fmaxf(d1.z+p1.z,0.f); v[7]=fmaxf(d1.w+p1.w,0.f);
        if (FINAL) {
#pragma unroll
            for (int e = 0; e < 8; ++e)
                sdot = fmaf(v[e], w5[kc * 32 + kg * 8 + e], sdot);
        } else {
#pragma unroll
            for (int e = 0; e < 8; ++e) {
                unsigned short b1 = bf16rn(v[e]); float r1 = v[e] - bf16tof(b1);
                unsigned short b2 = bf16rn(r1);   float r2 = r1   - bf16tof(b2);
                unsigned short b3 = bf16rn(r2);
                A0[kc][e] = (short)b1; A1[kc][e] = (short)b2; A2[kc][e] = (short)b3;
            }
        }
    }

    if (!FINAL) {
        char* ldsw = lds + wv * 1024;
        const unsigned short* wsrc = Wbt + t * 8;
#pragma unroll
        for (int i = 0; i < 6; ++i)
            GLOAD_LDS16(wsrc + i * 2048, ldsw + i * 4096);
        __syncthreads();

        int cur = 0;
        for (int cs = 0; cs < 4; ++cs) {
            if (cs < 3) {
#pragma unroll
                for (int i = 0; i < 6; ++i)
                    GLOAD_LDS16(wsrc + (size_t)(cs + 1) * 12288 + i * 2048,
                                ldsw + (cur ^ 1) * 24576 + i * 4096);
            }
            const char* pb = lds + cur * 24576 + kg * 256 + lrow * 16;  // conflict-free
            f32x4 acc0 = {0.f,0.f,0.f,0.f};
            f32x4 acc1 = {0.f,0.f,0.f,0.f};
#pragma unroll
            for (int kc = 0; kc < 4; ++kc) {
                const char* pk = pb + kc * 2048;
                bf16x8 b00 = *(const bf16x8*)(pk);
                bf16x8 b01 = *(const bf16x8*)(pk + 1024);
                bf16x8 b10 = *(const bf16x8*)(pk + 8192);
                bf16x8 b11 = *(const bf16x8*)(pk + 9216);
                bf16x8 b20 = *(const bf16x8*)(pk + 16384);
                bf16x8 b21 = *(const bf16x8*)(pk + 17408);
                SIXPASS(b00, b01, b10, b11, b20, b21)
            }
            float bb0 = bb[cs * 32 + lrow];
            float bb1 = bb[cs * 32 + 16 + lrow];
            float m0 = fmaxf(fmaxf(acc0[0], acc0[1]), fmaxf(acc0[2], acc0[3]));
            float m1 = fmaxf(fmaxf(acc1[0], acc1[1]), fmaxf(acc1[2], acc1[3]));
            m0 = fmaxf(m0 + bb0, 0.f);
            m1 = fmaxf(m1 + bb1, 0.f);
            m0 = fmaxf(m0, __shfl_xor(m0, 16));
            m1 = fmaxf(m1, __shfl_xor(m1, 16));
            if (kg == 0) {
                out[(size_t)nodeA * HD + cs * 32 + lrow]      = m0;
                out[(size_t)nodeA * HD + cs * 32 + 16 + lrow] = m1;
            } else if (kg == 2) {
                out[(size_t)(nodeA + 1) * HD + cs * 32 + lrow]      = m0;
                out[(size_t)(nodeA + 1) * HD + cs * 32 + 16 + lrow] = m1;
            }
            __syncthreads();
            cur ^= 1;
        }
    } else {
        sdot += __shfl_xor(sdot, 16);
        sdot += __shfl_xor(sdot, 32);
        float s = fmaxf(sdot + bb[0], 0.f);
#pragma unroll
        for (int m = 1; m < 8; m <<= 1)
            s = fmaxf(s, __shfl_xor(s, m));
        if (lane == 0) out[nodeA]     = 1.f / (1.f + expf(-s));
        if (lane == 8) out[nodeA + 1] = 1.f / (1.f + expf(-s));
    }
}

extern "C" void kernel_launch(void* const* d_in, const int* in_sizes, int n_in,
                              void* d_out, int out_size, void* d_ws, size_t ws_size,
                              hipStream_t stream) {
    const float* x     = (const float*)d_in[0];
    const float* W_enc = (const float*)d_in[3];
    const float* b_enc = (const float*)d_in[4];
    const float* W1a = (const float*)d_in[5];
    const float* b1a = (const float*)d_in[6];
    const float* W1b = (const float*)d_in[7];
    const float* b1b = (const float*)d_in[8];
    const float* W2a = (const float*)d_in[9];
    const float* b2a = (const float*)d_in[10];
    const float* W2b = (const float*)d_in[11];
    const float* b2b = (const float*)d_in[12];
    const float* W5a = (const float*)d_in[13];
    const float* b5a = (const float*)d_in[14];
    const float* W5b = (const float*)d_in[15];
    const float* b5b = (const float*)d_in[16];

    float* h0   = (float*)d_ws;                                  // 16 MB
    float* h1   = h0 + (size_t)NTOT*HD;                          // 16 MB
    float* sqg  = h1 + (size_t)NTOT*HD;                          // 128 KB
    int*   idxb = (int*)(sqg + NTOT);                            // 1 MB
    unsigned short* hs = (unsigned short*)(idxb + (size_t)NTOT*KNN);  // 24 MB
    float* Dbuf = (float*)(hs + (size_t)3*NTOT*HD);              // 16 MB
    unsigned short* Wt1  = (unsigned short*)(Dbuf + (size_t)NTOT*HD);
    unsigned short* Wt2  = Wt1 + 98304;
    unsigned short* Wt5  = Wt2 + 98304;
    unsigned short* Wbt1 = Wt5 + 98304;
    unsigned short* Wbt2 = Wbt1 + 49152;

    // cand buffers (8MB + 8MB) overlay Dbuf; node_gemm writes Dbuf after merge consumed them
    float* cd = Dbuf;
    int*   ci = (int*)(Dbuf + (size_t)NTOT*64);

    prep_wcat<<<128, 256, 0, stream>>>(W1a, Wt1);
    prep_wcat<<<128, 256, 0, stream>>>(W2a, Wt2);
    prep_wcat<<<128, 256, 0, stream>>>(W5a, Wt5);
    prep_wb  <<< 64, 256, 0, stream>>>(W1b, Wbt1);
    prep_wb  <<< 64, 256, 0, stream>>>(W2b, Wbt2);

    enc_kernel<<<NTOT*HD/256, 256, 0, stream>>>(x, W_enc, b_enc, h0);

    // layer 1: h0 -> h1
    split_kernel<<<NTOT/4, 256, 0, stream>>>(h0, hs, sqg);
    knn_mfma   <<<1024, 256, 0, stream>>>(hs, sqg, cd, ci);
    knn_merge  <<<NTOT/32, 256, 0, stream>>>(cd, ci, idxb);
    node_gemm  <<<NTOT/64, 256, 0, stream>>>(hs, Wt1, b1a, h0, Dbuf);
    edge_mlp<false><<<NTOT/8, 256, 0, stream>>>(h0, Dbuf, idxb, Wbt1, b1b, nullptr, h1);

    // layer 2: h1 -> h0
    split_kernel<<<NTOT/4, 256, 0, stream>>>(h1, hs, sqg);
    knn_mfma   <<<1024, 256, 0, stream>>>(hs, sqg, cd, ci);
    knn_merge  <<<NTOT/32, 256, 0, stream>>>(cd, ci, idxb);
    node_gemm  <<<NTOT/64, 256, 0, stream>>>(hs, Wt2, b2a, h1, Dbuf);
    edge_mlp<false><<<NTOT/8, 256, 0, stream>>>(h1, Dbuf, idxb, Wbt2, b2b, nullptr, h0);

    // layer 5: h0 -> d_out
    split_kernel<<<NTOT/4, 256, 0, stream>>>(h0, hs, sqg);
    knn_mfma   <<<1024, 256, 0, stream>>>(hs, sqg, cd, ci);
    knn_merge  <<<NTOT/32, 256, 0, stream>>>(cd, ci, idxb);
    node_gemm  <<<NTOT/64, 256, 0, stream>>>(hs, Wt5, b5a, h0, Dbuf);
    edge_mlp<true><<<NTOT/8, 256, 0, stream>>>(h0, Dbuf, idxb, nullptr, b5b, W5b, (float*)d_out);
}

// Round 6
// 595.453 us; speedup vs baseline: 4.2038x; 1.1515x over previous
//
#include <hip/hip_runtime.h>
#include <hip/hip_bf16.h>
#include <math.h>

#define BGR 16
#define NPG 2048
#define HD  128
#define KNN 8
#define NTOT (BGR*NPG)   // 32768

using bf16x8 = __attribute__((ext_vector_type(8))) short;
using f32x4  = __attribute__((ext_vector_type(4))) float;
using f32x16 = __attribute__((ext_vector_type(16))) float;

typedef __attribute__((address_space(3))) unsigned int lds_uint;
typedef const __attribute__((address_space(1))) unsigned int glob_uint;
#define GLOAD_LDS16(g, l) __builtin_amdgcn_global_load_lds((glob_uint*)(g), (lds_uint*)(l), 16, 0, 0)

__device__ inline unsigned short bf16rn(float f) {
    unsigned u = __float_as_uint(f);
    unsigned r = (u + 0x7FFFu + ((u >> 16) & 1u)) >> 16;
    return (unsigned short)r;
}
__device__ inline float bf16tof(unsigned short h) {
    return __uint_as_float(((unsigned)h) << 16);
}

// ---------------- encoder ----------------
__global__ __launch_bounds__(256) void enc_kernel(const float* __restrict__ x,
                                                  const float* __restrict__ W,
                                                  const float* __restrict__ bias,
                                                  float* __restrict__ hout)
{
    int gid = blockIdx.x * 256 + threadIdx.x;
    int n = gid >> 7, o = gid & 127;
    float s = bias[o];
#pragma unroll
    for (int f = 0; f < 4; ++f)
        s = fmaf(x[n*4 + f], W[f*128 + o], s);
    hout[gid] = s;
}

// ---------------- exact f32 sq-norm + 3-way bf16 split ----------------
__global__ __launch_bounds__(256) void split_kernel(const float* __restrict__ h,
                                                    unsigned short* __restrict__ hs,
                                                    float* __restrict__ sqg)
{
    const size_t plane = (size_t)NTOT * HD;
    int node = (blockIdx.x * 256 + threadIdx.x) >> 6;
    int lane = threadIdx.x & 63;
    const float* hp = h + (size_t)node * HD;
    float v0 = hp[lane], v1 = hp[lane + 64];
    float s = fmaf(v0, v0, v1 * v1);
#pragma unroll
    for (int off = 32; off >= 1; off >>= 1)
        s += __shfl_xor(s, off);
    if (lane == 0) sqg[node] = s;
#pragma unroll
    for (int q = 0; q < 2; ++q) {
        float v = q ? v1 : v0;
        int   d = lane + q * 64;
        unsigned short b1 = bf16rn(v);  float r1 = v  - bf16tof(b1);
        unsigned short b2 = bf16rn(r1); float r2 = r1 - bf16tof(b2);
        unsigned short b3 = bf16rn(r2);
        size_t base = (size_t)node * HD + d;
        hs[base]             = b1;
        hs[base + plane]     = b2;
        hs[base + 2 * plane] = b3;
    }
}

// ---------------- weight prep (unchanged layout from round 5) ----------------
__global__ __launch_bounds__(256) void prep_wcat(const float* __restrict__ Wa,
                                                 unsigned short* __restrict__ Wt)
{
    int gid = blockIdx.x * 256 + threadIdx.x;   // 32768 = 128k x 256n
    int k = gid >> 8, n = gid & 255;
    float w;
    if (n < 128) w = Wa[(128 + k) * 128 + n];
    else { int nn = n - 128; w = Wa[k * 128 + nn] - Wa[(128 + k) * 128 + nn]; }
    unsigned short b1 = bf16rn(w);  float r1 = w  - bf16tof(b1);
    unsigned short b2 = bf16rn(r1); float r2 = r1 - bf16tof(b2);
    unsigned short b3 = bf16rn(r2);
    int cs = n >> 5, h = (n >> 4) & 1, c = n & 15, kc = k >> 5, kg = (k >> 3) & 3, e = k & 7;
    size_t off = (size_t)cs * 12288 + kc * 1024 + h * 512 + kg * 128 + c * 8 + e;
    Wt[off] = b1; Wt[off + 4096] = b2; Wt[off + 8192] = b3;
}

__global__ __launch_bounds__(256) void prep_wb(const float* __restrict__ Wb,
                                               unsigned short* __restrict__ Wt)
{
    int gid = blockIdx.x * 256 + threadIdx.x;   // 16384 = 128k x 128n
    int k = gid >> 7, n = gid & 127;
    float w = Wb[k * 128 + n];
    unsigned short b1 = bf16rn(w);  float r1 = w  - bf16tof(b1);
    unsigned short b2 = bf16rn(r1); float r2 = r1 - bf16tof(b2);
    unsigned short b3 = bf16rn(r2);
    int cs = n >> 5, h = (n >> 4) & 1, c = n & 15, kc = k >> 5, kg = (k >> 3) & 3, e = k & 7;
    size_t off = (size_t)cs * 12288 + kc * 1024 + h * 512 + kg * 128 + c * 8 + e;
    Wt[off] = b1; Wt[off + 4096] = b2; Wt[off + 8192] = b3;
}

#define SIXPASS(B00,B01,B10,B11,B20,B21) \
    acc0 = __builtin_amdgcn_mfma_f32_16x16x32_bf16(A0[kc], B00, acc0, 0, 0, 0); \
    acc1 = __builtin_amdgcn_mfma_f32_16x16x32_bf16(A0[kc], B01, acc1, 0, 0, 0); \
    acc0 = __builtin_amdgcn_mfma_f32_16x16x32_bf16(A0[kc], B10, acc0, 0, 0, 0); \
    acc1 = __builtin_amdgcn_mfma_f32_16x16x32_bf16(A0[kc], B11, acc1, 0, 0, 0); \
    acc0 = __builtin_amdgcn_mfma_f32_16x16x32_bf16(A1[kc], B00, acc0, 0, 0, 0); \
    acc1 = __builtin_amdgcn_mfma_f32_16x16x32_bf16(A1[kc], B01, acc1, 0, 0, 0); \
    acc0 = __builtin_amdgcn_mfma_f32_16x16x32_bf16(A0[kc], B20, acc0, 0, 0, 0); \
    acc1 = __builtin_amdgcn_mfma_f32_16x16x32_bf16(A0[kc], B21, acc1, 0, 0, 0); \
    acc0 = __builtin_amdgcn_mfma_f32_16x16x32_bf16(A1[kc], B10, acc0, 0, 0, 0); \
    acc1 = __builtin_amdgcn_mfma_f32_16x16x32_bf16(A1[kc], B11, acc1, 0, 0, 0); \
    acc0 = __builtin_amdgcn_mfma_f32_16x16x32_bf16(A2[kc], B00, acc0, 0, 0, 0); \
    acc1 = __builtin_amdgcn_mfma_f32_16x16x32_bf16(A2[kc], B01, acc1, 0, 0, 0);

// ---------------- kNN via 32x32x16 MFMA, rows-in-regs as B operand ----------------
// Round-6 changes: branchless med3 selection ladder; SGPR-folded staging offsets;
// s_setprio around MFMA cluster. Structure/layout identical to round 5.
__global__ __launch_bounds__(256) void knn_mfma(const unsigned short* __restrict__ hs,
                                                const float* __restrict__ sqg,
                                                float* __restrict__ cand_d,
                                                int* __restrict__ cand_i)
{
    __shared__ ulong2 ldsraw[3200];   // 48KB dbuf + 2KB sq
    char* ldsc = (char*)ldsraw;
    float* sqs = (float*)(ldsc + 49152);

    const size_t plane = (size_t)NTOT * HD;
    const int t = threadIdx.x;
    const int b = blockIdx.x;           // 1024 blocks
    const int slot = b >> 3;
    const int g  = (b & 7) | ((slot & 1) << 3);
    const int rb = (slot >> 1) & 15;
    const int cs = (slot >> 5) & 3;
    const int gbase = g * NPG;
    const int cbase = cs * 512;
    const int wv = t >> 6, lane = t & 63;
    const int rl = lane & 31, kh = lane >> 5;
    const int myrow = rb * 128 + wv * 32 + rl;

    sqs[t]       = sqg[gbase + cbase + t];
    sqs[t + 256] = sqg[gbase + cbase + 256 + t];

    // row operand (B): hs * (-2), exact via exponent+1 & sign-flip
    bf16x8 RB[3][8];
    {
        const unsigned short* rrow = hs + (size_t)(gbase + myrow) * HD + kh * 8;
#pragma unroll
        for (int p = 0; p < 3; ++p)
#pragma unroll
            for (int kch = 0; kch < 8; ++kch) {
                bf16x8 v = *(const bf16x8*)(rrow + (size_t)p * plane + kch * 16);
                unsigned* u = (unsigned*)&v;
#pragma unroll
                for (int w = 0; w < 4; ++w)
                    u[w] = (u[w] + 0x00800080u) ^ 0x80008000u;
                RB[p][kch] = v;
            }
    }
    const float sqi = sqg[gbase + myrow];

    // staging: single per-thread base + compile-time chunk offsets
    // chunk i: p=i>>1, kch=(i&1)*4 + (t>>6); dest byte = i*4096 + t*16 (linear)
    const unsigned short* sb = hs + (size_t)(gbase + cbase + (t & 31)) * HD
                             + (t >> 6) * 16 + ((t >> 5) & 1) * 8;
    char* ldsw = ldsc + wv * 1024;

#pragma unroll
    for (int i = 0; i < 6; ++i)
        GLOAD_LDS16(sb + (size_t)(i >> 1) * plane + (i & 1) * 64, ldsw + i * 4096);
    __syncthreads();

    const float INF = __uint_as_float(0x7F800000u);
    float bd[8];
    int   bi[8];
#pragma unroll
    for (int s = 0; s < 8; ++s) { bd[s] = INF; bi[s] = 0x7fffffff; }

    int cur = 0;
    for (int s = 0; s < 16; ++s) {
        if (s < 15) {
            const unsigned short* sbn = sb + (size_t)(s + 1) * 32 * HD;
#pragma unroll
            for (int i = 0; i < 6; ++i)
                GLOAD_LDS16(sbn + (size_t)(i >> 1) * plane + (i & 1) * 64,
                            ldsw + (cur ^ 1) * 24576 + i * 4096);
        }
        const char* pstep = ldsc + cur * 24576 + lane * 16;
        f32x16 acc = {0.f,0.f,0.f,0.f,0.f,0.f,0.f,0.f,0.f,0.f,0.f,0.f,0.f,0.f,0.f,0.f};
        __builtin_amdgcn_s_setprio(1);
#pragma unroll
        for (int kch = 0; kch < 8; ++kch) {
            bf16x8 c0 = *(const bf16x8*)(pstep + kch * 1024);
            bf16x8 c1 = *(const bf16x8*)(pstep + 8192 + kch * 1024);
            bf16x8 c2 = *(const bf16x8*)(pstep + 16384 + kch * 1024);
            acc = __builtin_amdgcn_mfma_f32_32x32x16_bf16(c0, RB[0][kch], acc, 0, 0, 0);
            acc = __builtin_amdgcn_mfma_f32_32x32x16_bf16(c0, RB[1][kch], acc, 0, 0, 0);
            acc = __builtin_amdgcn_mfma_f32_32x32x16_bf16(c1, RB[0][kch], acc, 0, 0, 0);
            acc = __builtin_amdgcn_mfma_f32_32x32x16_bf16(c1, RB[1][kch], acc, 0, 0, 0);
            acc = __builtin_amdgcn_mfma_f32_32x32x16_bf16(c2, RB[0][kch], acc, 0, 0, 0);
            acc = __builtin_amdgcn_mfma_f32_32x32x16_bf16(c0, RB[2][kch], acc, 0, 0, 0);
        }
        __builtin_amdgcn_s_setprio(0);
        // branchless top-8 insert: dist via med3 ladder, idx via cndmask ladder
        const int jb = cbase + s * 32 + kh * 4;
#pragma unroll
        for (int grp = 0; grp < 4; ++grp) {
            f32x4 sq4 = *(const f32x4*)(sqs + s * 32 + grp * 8 + kh * 4);
#pragma unroll
            for (int e = 0; e < 4; ++e) {
                float dp = sq4[e] + acc[grp * 4 + e];
                int j = jb + grp * 8 + e;
                bool u0 = dp < bd[0], u1 = dp < bd[1], u2 = dp < bd[2], u3 = dp < bd[3];
                bool u4 = dp < bd[4], u5 = dp < bd[5], u6 = dp < bd[6], u7 = dp < bd[7];
                bd[7] = __builtin_amdgcn_fmed3f(bd[6], dp, bd[7]);
                bd[6] = __builtin_amdgcn_fmed3f(bd[5], dp, bd[6]);
                bd[5] = __builtin_amdgcn_fmed3f(bd[4], dp, bd[5]);
                bd[4] = __builtin_amdgcn_fmed3f(bd[3], dp, bd[4]);
                bd[3] = __builtin_amdgcn_fmed3f(bd[2], dp, bd[3]);
                bd[2] = __builtin_amdgcn_fmed3f(bd[1], dp, bd[2]);
                bd[1] = __builtin_amdgcn_fmed3f(bd[0], dp, bd[1]);
                bd[0] = fminf(bd[0], dp);
                bi[7] = u6 ? bi[6] : (u7 ? j : bi[7]);
                bi[6] = u5 ? bi[5] : (u6 ? j : bi[6]);
                bi[5] = u4 ? bi[4] : (u5 ? j : bi[5]);
                bi[4] = u3 ? bi[3] : (u4 ? j : bi[4]);
                bi[3] = u2 ? bi[2] : (u3 ? j : bi[3]);
                bi[2] = u1 ? bi[1] : (u2 ? j : bi[2]);
                bi[1] = u0 ? bi[0] : (u1 ? j : bi[1]);
                bi[0] = u0 ? j : bi[0];
            }
        }
        __syncthreads();
        cur ^= 1;
    }

    // each lane writes its own sorted run of 8 (row, col-half kh, slice cs)
    const size_t ob = (size_t)(gbase + myrow) * 64 + cs * 16 + kh * 8;
#pragma unroll
    for (int sel = 0; sel < 8; ++sel) {
        cand_d[ob + sel] = sqi + bd[sel];
        cand_i[ob + sel] = gbase + bi[sel];
    }
}

// ---------------- merge 8 sorted runs of 8 per row -> final top-8 ----------------
__global__ __launch_bounds__(256) void knn_merge(const float* __restrict__ cand_d,
                                                 const int* __restrict__ cand_i,
                                                 int* __restrict__ nbr)
{
    const int t = threadIdx.x;
    const int row = blockIdx.x * 32 + (t >> 3);
    const int run = t & 7;
    const float* pd = cand_d + (size_t)row * 64 + run * 8;
    const int*   pi = cand_i + (size_t)row * 64 + run * 8;
    float d[8]; int ix[8];
#pragma unroll
    for (int k = 0; k < 8; ++k) { d[k] = pd[k]; ix[k] = pi[k]; }
    const float INF = __uint_as_float(0x7F800000u);
    int* op = nbr + (size_t)row * KNN;
    float hd = d[0]; int hi = ix[0];
#pragma unroll
    for (int sel = 0; sel < 8; ++sel) {
        float md = hd; int mi = hi;
#pragma unroll
        for (int m = 1; m < 8; m <<= 1) {
            float od = __shfl_xor(md, m, 8);
            int   oi = __shfl_xor(mi, m, 8);
            bool tk = (od < md) || (od == md && oi < mi);
            md = tk ? od : md; mi = tk ? oi : mi;
        }
        if (run == sel) op[sel] = mi;
        bool win = (hd == md) && (hi == mi);
        if (win) {
            d[0]=d[1]; ix[0]=ix[1]; d[1]=d[2]; ix[1]=ix[2];
            d[2]=d[3]; ix[2]=ix[3]; d[3]=d[4]; ix[3]=ix[4];
            d[4]=d[5]; ix[4]=ix[5]; d[5]=d[6]; ix[5]=ix[6];
            d[6]=d[7]; ix[6]=ix[7]; d[7]=INF;  ix[7]=0x7fffffff;
        }
        hd = d[0]; hi = ix[0];
    }
}

// ---------------- node GEMM: P = h@Wa_bot ; D = h@(Wa_top-Wa_bot) + ba ----------------
__global__ __launch_bounds__(256) void node_gemm(const unsigned short* __restrict__ hs,
                                                 const unsigned short* __restrict__ Wt,
                                                 const float* __restrict__ ba,
                                                 float* __restrict__ P,
                                                 float* __restrict__ D)
{
    __shared__ char lds[49152];
    const size_t plane = (size_t)NTOT * HD;
    const int t = threadIdx.x, wv = t >> 6, lane = t & 63;
    const int lrow = lane & 15, kg = lane >> 4;
    const int nodebase = blockIdx.x * 64 + wv * 16;

    const unsigned short* arow = hs + (size_t)(nodebase + lrow) * HD + kg * 8;
    bf16x8 A0[4], A1[4], A2[4];
#pragma unroll
    for (int kc = 0; kc < 4; ++kc) {
        A0[kc] = *(const bf16x8*)(arow + kc * 32);
        A1[kc] = *(const bf16x8*)(arow + plane + kc * 32);
        A2[kc] = *(const bf16x8*)(arow + 2 * plane + kc * 32);
    }

    char* ldsw = lds + wv * 1024;
    const unsigned short* wsrc = Wt + t * 8;
#pragma unroll
    for (int i = 0; i < 6; ++i)
        GLOAD_LDS16(wsrc + i * 2048, ldsw + i * 4096);
    __syncthreads();

    int cur = 0;
    for (int cs = 0; cs < 8; ++cs) {
        if (cs < 7) {
#pragma unroll
            for (int i = 0; i < 6; ++i)
                GLOAD_LDS16(wsrc + (size_t)(cs + 1) * 12288 + i * 2048,
                            ldsw + (cur ^ 1) * 24576 + i * 4096);
        }
        const char* pb = lds + cur * 24576 + kg * 256 + lrow * 16;   // conflict-free
        f32x4 acc0 = {0.f,0.f,0.f,0.f};
        f32x4 acc1 = {0.f,0.f,0.f,0.f};
#pragma unroll
        for (int kc = 0; kc < 4; ++kc) {
            const char* pk = pb + kc * 2048;
            bf16x8 b00 = *(const bf16x8*)(pk);
            bf16x8 b01 = *(const bf16x8*)(pk + 1024);
            bf16x8 b10 = *(const bf16x8*)(pk + 8192);
            bf16x8 b11 = *(const bf16x8*)(pk + 9216);
            bf16x8 b20 = *(const bf16x8*)(pk + 16384);
            bf16x8 b21 = *(const bf16x8*)(pk + 17408);
            SIXPASS(b00, b01, b10, b11, b20, b21)
        }
        int n0 = cs * 32 + lrow;
        if (cs < 4) {
#pragma unroll
            for (int r = 0; r < 4; ++r) {
                size_t row = (size_t)(nodebase + kg * 4 + r) * HD;
                P[row + n0]      = acc0[r];
                P[row + n0 + 16] = acc1[r];
            }
        } else {
            float ba0 = ba[n0 - 128], ba1 = ba[n0 - 112];
#pragma unroll
            for (int r = 0; r < 4; ++r) {
                size_t row = (size_t)(nodebase + kg * 4 + r) * HD;
                D[row + n0 - 128] = acc0[r] + ba0;
                D[row + n0 - 112] = acc1[r] + ba1;
            }
        }
        __syncthreads();
        cur ^= 1;
    }
}

// ---------------- fused edge kernel: H1=relu(D[i]+P[j]) -> GEMM2 -> max -> out ----------------
template<bool FINAL>
__global__ __launch_bounds__(256) void edge_mlp(const float* __restrict__ P,
                                                const float* __restrict__ D,
                                                const int* __restrict__ nbr,
                                                const unsigned short* __restrict__ Wbt,
                                                const float* __restrict__ bb,
                                                const float* __restrict__ w5,
                                                float* __restrict__ out)
{
    __shared__ char lds[49152];
    const int t = threadIdx.x, wv = t >> 6, lane = t & 63;
    const int lrow = lane & 15, kg = lane >> 4;
    const int nodeA = blockIdx.x * 8 + wv * 2;
    const int i_node = nodeA + (lrow >> 3);
    const int j = nbr[(size_t)i_node * KNN + (lrow & 7)];

    const float* dp = D + (size_t)i_node * HD + kg * 8;
    const float* pp = P + (size_t)j * HD + kg * 8;

    bf16x8 A0[4], A1[4], A2[4];
    float sdot = 0.f;
#pragma unroll
    for (int kc = 0; kc < 4; ++kc) {
        float4 d0 = *(const float4*)(dp + kc * 32);
        float4 d1 = *(const float4*)(dp + kc * 32 + 4);
        float4 p0 = *(const float4*)(pp + kc * 32);
        float4 p1 = *(const float4*)(pp + kc * 32 + 4);
        float v[8];
        v[0]=fmaxf(d0.x+p0.x,0.f); v[1]=fmaxf(d0.y+p0.y,0.f);
        v[2]=fmaxf(d0.z+p0.z,0.f); v[3]=fmaxf(d0.w+p0.w,0.f);
        v[4]=fmaxf(d1.x+p1.x,0.f); v[5]=fmaxf(d1.y+p1.y,0.f);
        v[6]=fmaxf(d1.z+p1.z,0.f); v[7]=fmaxf(d1.w+p1.w,0.f);
        if (FINAL) {
#pragma unroll
            for (int e = 0; e < 8; ++e)
                sdot = fmaf(v[e], w5[kc * 32 + kg * 8 + e], sdot);
        } else {
#pragma unroll
            for (int e = 0; e < 8; ++e) {
                unsigned short b1 = bf16rn(v[e]); float r1 = v[e] - bf16tof(b1);
                unsigned short b2 = bf16rn(r1);   float r2 = r1   - bf16tof(b2);
                unsigned short b3 = bf16rn(r2);
                A0[kc][e] = (short)b1; A1[kc][e] = (short)b2; A2[kc][e] = (short)b3;
            }
        }
    }

    if (!FINAL) {
        char* ldsw = lds + wv * 1024;
        const unsigned short* wsrc = Wbt + t * 8;
#pragma unroll
        for (int i = 0; i < 6; ++i)
            GLOAD_LDS16(wsrc + i * 2048, ldsw + i * 4096);
        __syncthreads();

        int cur = 0;
        for (int cs = 0; cs < 4; ++cs) {
            if (cs < 3) {
#pragma unroll
                for (int i = 0; i < 6; ++i)
                    GLOAD_LDS16(wsrc + (size_t)(cs + 1) * 12288 + i * 2048,
                                ldsw + (cur ^ 1) * 24576 + i * 4096);
            }
            const char* pb = lds + cur * 24576 + kg * 256 + lrow * 16;  // conflict-free
            f32x4 acc0 = {0.f,0.f,0.f,0.f};
            f32x4 acc1 = {0.f,0.f,0.f,0.f};
#pragma unroll
            for (int kc = 0; kc < 4; ++kc) {
                const char* pk = pb + kc * 2048;
                bf16x8 b00 = *(const bf16x8*)(pk);
                bf16x8 b01 = *(const bf16x8*)(pk + 1024);
                bf16x8 b10 = *(const bf16x8*)(pk + 8192);
                bf16x8 b11 = *(const bf16x8*)(pk + 9216);
                bf16x8 b20 = *(const bf16x8*)(pk + 16384);
                bf16x8 b21 = *(const bf16x8*)(pk + 17408);
                SIXPASS(b00, b01, b10, b11, b20, b21)
            }
            float bb0 = bb[cs * 32 + lrow];
            float bb1 = bb[cs * 32 + 16 + lrow];
            float m0 = fmaxf(fmaxf(acc0[0], acc0[1]), fmaxf(acc0[2], acc0[3]));
            float m1 = fmaxf(fmaxf(acc1[0], acc1[1]), fmaxf(acc1[2], acc1[3]));
            m0 = fmaxf(m0 + bb0, 0.f);
            m1 = fmaxf(m1 + bb1, 0.f);
            m0 = fmaxf(m0, __shfl_xor(m0, 16));
            m1 = fmaxf(m1, __shfl_xor(m1, 16));
            if (kg == 0) {
                out[(size_t)nodeA * HD + cs * 32 + lrow]      = m0;
                out[(size_t)nodeA * HD + cs * 32 + 16 + lrow] = m1;
            } else if (kg == 2) {
                out[(size_t)(nodeA + 1) * HD + cs * 32 + lrow]      = m0;
                out[(size_t)(nodeA + 1) * HD + cs * 32 + 16 + lrow] = m1;
            }
            __syncthreads();
            cur ^= 1;
        }
    } else {
        sdot += __shfl_xor(sdot, 16);
        sdot += __shfl_xor(sdot, 32);
        float s = fmaxf(sdot + bb[0], 0.f);
#pragma unroll
        for (int m = 1; m < 8; m <<= 1)
            s = fmaxf(s, __shfl_xor(s, m));
        if (lane == 0) out[nodeA]     = 1.f / (1.f + expf(-s));
        if (lane == 8) out[nodeA + 1] = 1.f / (1.f + expf(-s));
    }
}

extern "C" void kernel_launch(void* const* d_in, const int* in_sizes, int n_in,
                              void* d_out, int out_size, void* d_ws, size_t ws_size,
                              hipStream_t stream) {
    const float* x     = (const float*)d_in[0];
    const float* W_enc = (const float*)d_in[3];
    const float* b_enc = (const float*)d_in[4];
    const float* W1a = (const float*)d_in[5];
    const float* b1a = (const float*)d_in[6];
    const float* W1b = (const float*)d_in[7];
    const float* b1b = (const float*)d_in[8];
    const float* W2a = (const float*)d_in[9];
    const float* b2a = (const float*)d_in[10];
    const float* W2b = (const float*)d_in[11];
    const float* b2b = (const float*)d_in[12];
    const float* W5a = (const float*)d_in[13];
    const float* b5a = (const float*)d_in[14];
    const float* W5b = (const float*)d_in[15];
    const float* b5b = (const float*)d_in[16];

    float* h0   = (float*)d_ws;                                  // 16 MB
    float* h1   = h0 + (size_t)NTOT*HD;                          // 16 MB
    float* sqg  = h1 + (size_t)NTOT*HD;                          // 128 KB
    int*   idxb = (int*)(sqg + NTOT);                            // 1 MB
    unsigned short* hs = (unsigned short*)(idxb + (size_t)NTOT*KNN);  // 24 MB
    float* Dbuf = (float*)(hs + (size_t)3*NTOT*HD);              // 16 MB
    unsigned short* Wt1  = (unsigned short*)(Dbuf + (size_t)NTOT*HD);
    unsigned short* Wt2  = Wt1 + 98304;
    unsigned short* Wt5  = Wt2 + 98304;
    unsigned short* Wbt1 = Wt5 + 98304;
    unsigned short* Wbt2 = Wbt1 + 49152;

    float* cd = Dbuf;
    int*   ci = (int*)(Dbuf + (size_t)NTOT*64);

    prep_wcat<<<128, 256, 0, stream>>>(W1a, Wt1);
    prep_wcat<<<128, 256, 0, stream>>>(W2a, Wt2);
    prep_wcat<<<128, 256, 0, stream>>>(W5a, Wt5);
    prep_wb  <<< 64, 256, 0, stream>>>(W1b, Wbt1);
    prep_wb  <<< 64, 256, 0, stream>>>(W2b, Wbt2);

    enc_kernel<<<NTOT*HD/256, 256, 0, stream>>>(x, W_enc, b_enc, h0);

    // layer 1: h0 -> h1
    split_kernel<<<NTOT/4, 256, 0, stream>>>(h0, hs, sqg);
    knn_mfma   <<<1024, 256, 0, stream>>>(hs, sqg, cd, ci);
    knn_merge  <<<NTOT/32, 256, 0, stream>>>(cd, ci, idxb);
    node_gemm  <<<NTOT/64, 256, 0, stream>>>(hs, Wt1, b1a, h0, Dbuf);
    edge_mlp<false><<<NTOT/8, 256, 0, stream>>>(h0, Dbuf, idxb, Wbt1, b1b, nullptr, h1);

    // layer 2: h1 -> h0
    split_kernel<<<NTOT/4, 256, 0, stream>>>(h1, hs, sqg);
    knn_mfma   <<<1024, 256, 0, stream>>>(hs, sqg, cd, ci);
    knn_merge  <<<NTOT/32, 256, 0, stream>>>(cd, ci, idxb);
    node_gemm  <<<NTOT/64, 256, 0, stream>>>(hs, Wt2, b2a, h1, Dbuf);
    edge_mlp<false><<<NTOT/8, 256, 0, stream>>>(h1, Dbuf, idxb, Wbt2, b2b, nullptr, h0);

    // layer 5: h0 -> d_out
    split_kernel<<<NTOT/4, 256, 0, stream>>>(h0, hs, sqg);
    knn_mfma   <<<1024, 256, 0, stream>>>(hs, sqg, cd, ci);
    knn_merge  <<<NTOT/32, 256, 0, stream>>>(cd, ci, idxb);
    node_gemm  <<<NTOT/64, 256, 0, stream>>>(hs, Wt5, b5a, h0, Dbuf);
    edge_mlp<true><<<NTOT/8, 256, 0, stream>>>(h0, Dbuf, idxb, nullptr, b5b, W5b, (float*)d_out);
}

// Round 7
// 520.417 us; speedup vs baseline: 4.8099x; 1.1442x over previous
//
#include <hip/hip_runtime.h>
#include <hip/hip_bf16.h>
#include <math.h>

#define BGR 16
#define NPG 2048
#define HD  128
#define KNN 8
#define NTOT (BGR*NPG)   // 32768

using bf16x8 = __attribute__((ext_vector_type(8))) short;
using f32x4  = __attribute__((ext_vector_type(4))) float;
using f32x16 = __attribute__((ext_vector_type(16))) float;

typedef __attribute__((address_space(3))) unsigned int lds_uint;
typedef const __attribute__((address_space(1))) unsigned int glob_uint;
#define GLOAD_LDS16(g, l) __builtin_amdgcn_global_load_lds((glob_uint*)(g), (lds_uint*)(l), 16, 0, 0)

__device__ inline unsigned short bf16rn(float f) {
    unsigned u = __float_as_uint(f);
    unsigned r = (u + 0x7FFFu + ((u >> 16) & 1u)) >> 16;
    return (unsigned short)r;
}
__device__ inline float bf16tof(unsigned short h) {
    return __uint_as_float(((unsigned)h) << 16);
}

// ---------------- encoder ----------------
__global__ __launch_bounds__(256) void enc_kernel(const float* __restrict__ x,
                                                  const float* __restrict__ W,
                                                  const float* __restrict__ bias,
                                                  float* __restrict__ hout)
{
    int gid = blockIdx.x * 256 + threadIdx.x;
    int n = gid >> 7, o = gid & 127;
    float s = bias[o];
#pragma unroll
    for (int f = 0; f < 4; ++f)
        s = fmaf(x[n*4 + f], W[f*128 + o], s);
    hout[gid] = s;
}

// ---------------- exact f32 sq-norm + 3-way bf16 split ----------------
__global__ __launch_bounds__(256) void split_kernel(const float* __restrict__ h,
                                                    unsigned short* __restrict__ hs,
                                                    float* __restrict__ sqg)
{
    const size_t plane = (size_t)NTOT * HD;
    int node = (blockIdx.x * 256 + threadIdx.x) >> 6;
    int lane = threadIdx.x & 63;
    const float* hp = h + (size_t)node * HD;
    float v0 = hp[lane], v1 = hp[lane + 64];
    float s = fmaf(v0, v0, v1 * v1);
#pragma unroll
    for (int off = 32; off >= 1; off >>= 1)
        s += __shfl_xor(s, off);
    if (lane == 0) sqg[node] = s;
#pragma unroll
    for (int q = 0; q < 2; ++q) {
        float v = q ? v1 : v0;
        int   d = lane + q * 64;
        unsigned short b1 = bf16rn(v);  float r1 = v  - bf16tof(b1);
        unsigned short b2 = bf16rn(r1); float r2 = r1 - bf16tof(b2);
        unsigned short b3 = bf16rn(r2);
        size_t base = (size_t)node * HD + d;
        hs[base]             = b1;
        hs[base + plane]     = b2;
        hs[base + 2 * plane] = b3;
    }
}

// ---------------- weight prep (unchanged layout) ----------------
__global__ __launch_bounds__(256) void prep_wcat(const float* __restrict__ Wa,
                                                 unsigned short* __restrict__ Wt)
{
    int gid = blockIdx.x * 256 + threadIdx.x;   // 32768 = 128k x 256n
    int k = gid >> 8, n = gid & 255;
    float w;
    if (n < 128) w = Wa[(128 + k) * 128 + n];
    else { int nn = n - 128; w = Wa[k * 128 + nn] - Wa[(128 + k) * 128 + nn]; }
    unsigned short b1 = bf16rn(w);  float r1 = w  - bf16tof(b1);
    unsigned short b2 = bf16rn(r1); float r2 = r1 - bf16tof(b2);
    unsigned short b3 = bf16rn(r2);
    int cs = n >> 5, h = (n >> 4) & 1, c = n & 15, kc = k >> 5, kg = (k >> 3) & 3, e = k & 7;
    size_t off = (size_t)cs * 12288 + kc * 1024 + h * 512 + kg * 128 + c * 8 + e;
    Wt[off] = b1; Wt[off + 4096] = b2; Wt[off + 8192] = b3;
}

__global__ __launch_bounds__(256) void prep_wb(const float* __restrict__ Wb,
                                               unsigned short* __restrict__ Wt)
{
    int gid = blockIdx.x * 256 + threadIdx.x;   // 16384 = 128k x 128n
    int k = gid >> 7, n = gid & 127;
    float w = Wb[k * 128 + n];
    unsigned short b1 = bf16rn(w);  float r1 = w  - bf16tof(b1);
    unsigned short b2 = bf16rn(r1); float r2 = r1 - bf16tof(b2);
    unsigned short b3 = bf16rn(r2);
    int cs = n >> 5, h = (n >> 4) & 1, c = n & 15, kc = k >> 5, kg = (k >> 3) & 3, e = k & 7;
    size_t off = (size_t)cs * 12288 + kc * 1024 + h * 512 + kg * 128 + c * 8 + e;
    Wt[off] = b1; Wt[off + 4096] = b2; Wt[off + 8192] = b3;
}

#define SIXPASS(B00,B01,B10,B11,B20,B21) \
    acc0 = __builtin_amdgcn_mfma_f32_16x16x32_bf16(A0[kc], B00, acc0, 0, 0, 0); \
    acc1 = __builtin_amdgcn_mfma_f32_16x16x32_bf16(A0[kc], B01, acc1, 0, 0, 0); \
    acc0 = __builtin_amdgcn_mfma_f32_16x16x32_bf16(A0[kc], B10, acc0, 0, 0, 0); \
    acc1 = __builtin_amdgcn_mfma_f32_16x16x32_bf16(A0[kc], B11, acc1, 0, 0, 0); \
    acc0 = __builtin_amdgcn_mfma_f32_16x16x32_bf16(A1[kc], B00, acc0, 0, 0, 0); \
    acc1 = __builtin_amdgcn_mfma_f32_16x16x32_bf16(A1[kc], B01, acc1, 0, 0, 0); \
    acc0 = __builtin_amdgcn_mfma_f32_16x16x32_bf16(A0[kc], B20, acc0, 0, 0, 0); \
    acc1 = __builtin_amdgcn_mfma_f32_16x16x32_bf16(A0[kc], B21, acc1, 0, 0, 0); \
    acc0 = __builtin_amdgcn_mfma_f32_16x16x32_bf16(A1[kc], B10, acc0, 0, 0, 0); \
    acc1 = __builtin_amdgcn_mfma_f32_16x16x32_bf16(A1[kc], B11, acc1, 0, 0, 0); \
    acc0 = __builtin_amdgcn_mfma_f32_16x16x32_bf16(A2[kc], B00, acc0, 0, 0, 0); \
    acc1 = __builtin_amdgcn_mfma_f32_16x16x32_bf16(A2[kc], B01, acc1, 0, 0, 0);

// ---------------- kNN via 32x32x16 MFMA, rows-in-regs as B operand ----------------
// Round-7: index packed into low 8 mantissa bits of the distance key
// (lid = s*16 + grp*4 + e, unique per lane-candidate, ascending in j ->
// ladder needs only med3/min, no compares, no index array). Decode at write-out.
__global__ __launch_bounds__(256, 3) void knn_mfma(const unsigned short* __restrict__ hs,
                                                   const float* __restrict__ sqg,
                                                   float* __restrict__ cand_d,
                                                   int* __restrict__ cand_i)
{
    __shared__ ulong2 ldsraw[3200];   // 48KB dbuf + 2KB sq
    char* ldsc = (char*)ldsraw;
    float* sqs = (float*)(ldsc + 49152);

    const size_t plane = (size_t)NTOT * HD;
    const int t = threadIdx.x;
    const int b = blockIdx.x;           // 1024 blocks
    const int slot = b >> 3;
    const int g  = (b & 7) | ((slot & 1) << 3);
    const int rb = (slot >> 1) & 15;
    const int cs = (slot >> 5) & 3;
    const int gbase = g * NPG;
    const int cbase = cs * 512;
    const int wv = t >> 6, lane = t & 63;
    const int rl = lane & 31, kh = lane >> 5;
    const int myrow = rb * 128 + wv * 32 + rl;

    sqs[t]       = sqg[gbase + cbase + t];
    sqs[t + 256] = sqg[gbase + cbase + 256 + t];

    // row operand (B): hs * (-2), exact via exponent+1 & sign-flip
    bf16x8 RB[3][8];
    {
        const unsigned short* rrow = hs + (size_t)(gbase + myrow) * HD + kh * 8;
#pragma unroll
        for (int p = 0; p < 3; ++p)
#pragma unroll
            for (int kch = 0; kch < 8; ++kch) {
                bf16x8 v = *(const bf16x8*)(rrow + (size_t)p * plane + kch * 16);
                unsigned* u = (unsigned*)&v;
#pragma unroll
                for (int w = 0; w < 4; ++w)
                    u[w] = (u[w] + 0x00800080u) ^ 0x80008000u;
                RB[p][kch] = v;
            }
    }
    const float sqi = sqg[gbase + myrow];

    // staging: single per-thread base + compile-time chunk offsets
    const unsigned short* sb = hs + (size_t)(gbase + cbase + (t & 31)) * HD
                             + (t >> 6) * 16 + ((t >> 5) & 1) * 8;
    char* ldsw = ldsc + wv * 1024;

#pragma unroll
    for (int i = 0; i < 6; ++i)
        GLOAD_LDS16(sb + (size_t)(i >> 1) * plane + (i & 1) * 64, ldsw + i * 4096);
    __syncthreads();

    const float INF = __uint_as_float(0x7F800000u);
    float bd[8];
#pragma unroll
    for (int s = 0; s < 8; ++s) bd[s] = INF;

    int cur = 0;
    for (int s = 0; s < 16; ++s) {
        if (s < 15) {
            const unsigned short* sbn = sb + (size_t)(s + 1) * 32 * HD;
#pragma unroll
            for (int i = 0; i < 6; ++i)
                GLOAD_LDS16(sbn + (size_t)(i >> 1) * plane + (i & 1) * 64,
                            ldsw + (cur ^ 1) * 24576 + i * 4096);
        }
        const char* pstep = ldsc + cur * 24576 + lane * 16;
        f32x16 acc = {0.f,0.f,0.f,0.f,0.f,0.f,0.f,0.f,0.f,0.f,0.f,0.f,0.f,0.f,0.f,0.f};
        __builtin_amdgcn_s_setprio(1);
#pragma unroll
        for (int kch = 0; kch < 8; ++kch) {
            bf16x8 c0 = *(const bf16x8*)(pstep + kch * 1024);
            bf16x8 c1 = *(const bf16x8*)(pstep + 8192 + kch * 1024);
            bf16x8 c2 = *(const bf16x8*)(pstep + 16384 + kch * 1024);
            acc = __builtin_amdgcn_mfma_f32_32x32x16_bf16(c0, RB[0][kch], acc, 0, 0, 0);
            acc = __builtin_amdgcn_mfma_f32_32x32x16_bf16(c0, RB[1][kch], acc, 0, 0, 0);
            acc = __builtin_amdgcn_mfma_f32_32x32x16_bf16(c1, RB[0][kch], acc, 0, 0, 0);
            acc = __builtin_amdgcn_mfma_f32_32x32x16_bf16(c1, RB[1][kch], acc, 0, 0, 0);
            acc = __builtin_amdgcn_mfma_f32_32x32x16_bf16(c2, RB[0][kch], acc, 0, 0, 0);
            acc = __builtin_amdgcn_mfma_f32_32x32x16_bf16(c0, RB[2][kch], acc, 0, 0, 0);
        }
        __builtin_amdgcn_s_setprio(0);
        // packed-key top-8: key = (bits(sqi+sqj+acc) & ~0xFF) | (s*16+grp*4+e)
        const unsigned lidbase = (unsigned)(s << 4);
#pragma unroll
        for (int grp = 0; grp < 4; ++grp) {
            f32x4 sq4 = *(const f32x4*)(sqs + s * 32 + grp * 8 + kh * 4);
#pragma unroll
            for (int e = 0; e < 4; ++e) {
                float dp = (sqi + sq4[e]) + acc[grp * 4 + e];
                unsigned ku = (__float_as_uint(dp) & 0xFFFFFF00u)
                            | (lidbase + (unsigned)(grp * 4 + e));
                float k = __uint_as_float(ku);
                bd[7] = __builtin_amdgcn_fmed3f(bd[6], k, bd[7]);
                bd[6] = __builtin_amdgcn_fmed3f(bd[5], k, bd[6]);
                bd[5] = __builtin_amdgcn_fmed3f(bd[4], k, bd[5]);
                bd[4] = __builtin_amdgcn_fmed3f(bd[3], k, bd[4]);
                bd[3] = __builtin_amdgcn_fmed3f(bd[2], k, bd[3]);
                bd[2] = __builtin_amdgcn_fmed3f(bd[1], k, bd[2]);
                bd[1] = __builtin_amdgcn_fmed3f(bd[0], k, bd[1]);
                bd[0] = fminf(bd[0], k);
            }
        }
        __syncthreads();
        cur ^= 1;
    }

    // decode + write sorted run of 8 (row, col-half kh, slice cs)
    const size_t ob = (size_t)(gbase + myrow) * 64 + cs * 16 + kh * 8;
#pragma unroll
    for (int sel = 0; sel < 8; ++sel) {
        unsigned u = __float_as_uint(bd[sel]);
        unsigned lid = u & 255u;
        int j = cbase + (int)(lid >> 4) * 32 + (int)((lid >> 2) & 3u) * 8
              + kh * 4 + (int)(lid & 3u);
        cand_d[ob + sel] = bd[sel];
        cand_i[ob + sel] = gbase + j;
    }
}

// ---------------- merge 8 sorted runs of 8 per row -> final top-8 ----------------
__global__ __launch_bounds__(256) void knn_merge(const float* __restrict__ cand_d,
                                                 const int* __restrict__ cand_i,
                                                 int* __restrict__ nbr)
{
    const int t = threadIdx.x;
    const int row = blockIdx.x * 32 + (t >> 3);
    const int run = t & 7;
    const float* pd = cand_d + (size_t)row * 64 + run * 8;
    const int*   pi = cand_i + (size_t)row * 64 + run * 8;
    float d[8]; int ix[8];
#pragma unroll
    for (int k = 0; k < 8; ++k) { d[k] = pd[k]; ix[k] = pi[k]; }
    const float INF = __uint_as_float(0x7F800000u);
    int* op = nbr + (size_t)row * KNN;
    float hd = d[0]; int hi = ix[0];
#pragma unroll
    for (int sel = 0; sel < 8; ++sel) {
        float md = hd; int mi = hi;
#pragma unroll
        for (int m = 1; m < 8; m <<= 1) {
            float od = __shfl_xor(md, m, 8);
            int   oi = __shfl_xor(mi, m, 8);
            bool tk = (od < md) || (od == md && oi < mi);
            md = tk ? od : md; mi = tk ? oi : mi;
        }
        if (run == sel) op[sel] = mi;
        bool win = (hd == md) && (hi == mi);
        if (win) {
            d[0]=d[1]; ix[0]=ix[1]; d[1]=d[2]; ix[1]=ix[2];
            d[2]=d[3]; ix[2]=ix[3]; d[3]=d[4]; ix[3]=ix[4];
            d[4]=d[5]; ix[4]=ix[5]; d[5]=d[6]; ix[5]=ix[6];
            d[6]=d[7]; ix[6]=ix[7]; d[7]=INF;  ix[7]=0x7fffffff;
        }
        hd = d[0]; hi = ix[0];
    }
}

// ---------------- node GEMM: P = h@Wa_bot ; D = h@(Wa_top-Wa_bot) + ba ----------------
__global__ __launch_bounds__(256) void node_gemm(const unsigned short* __restrict__ hs,
                                                 const unsigned short* __restrict__ Wt,
                                                 const float* __restrict__ ba,
                                                 float* __restrict__ P,
                                                 float* __restrict__ D)
{
    __shared__ char lds[49152];
    const size_t plane = (size_t)NTOT * HD;
    const int t = threadIdx.x, wv = t >> 6, lane = t & 63;
    const int lrow = lane & 15, kg = lane >> 4;
    const int nodebase = blockIdx.x * 64 + wv * 16;

    const unsigned short* arow = hs + (size_t)(nodebase + lrow) * HD + kg * 8;
    bf16x8 A0[4], A1[4], A2[4];
#pragma unroll
    for (int kc = 0; kc < 4; ++kc) {
        A0[kc] = *(const bf16x8*)(arow + kc * 32);
        A1[kc] = *(const bf16x8*)(arow + plane + kc * 32);
        A2[kc] = *(const bf16x8*)(arow + 2 * plane + kc * 32);
    }

    char* ldsw = lds + wv * 1024;
    const unsigned short* wsrc = Wt + t * 8;
#pragma unroll
    for (int i = 0; i < 6; ++i)
        GLOAD_LDS16(wsrc + i * 2048, ldsw + i * 4096);
    __syncthreads();

    int cur = 0;
    for (int cs = 0; cs < 8; ++cs) {
        if (cs < 7) {
#pragma unroll
            for (int i = 0; i < 6; ++i)
                GLOAD_LDS16(wsrc + (size_t)(cs + 1) * 12288 + i * 2048,
                            ldsw + (cur ^ 1) * 24576 + i * 4096);
        }
        const char* pb = lds + cur * 24576 + kg * 256 + lrow * 16;   // conflict-free
        f32x4 acc0 = {0.f,0.f,0.f,0.f};
        f32x4 acc1 = {0.f,0.f,0.f,0.f};
#pragma unroll
        for (int kc = 0; kc < 4; ++kc) {
            const char* pk = pb + kc * 2048;
            bf16x8 b00 = *(const bf16x8*)(pk);
            bf16x8 b01 = *(const bf16x8*)(pk + 1024);
            bf16x8 b10 = *(const bf16x8*)(pk + 8192);
            bf16x8 b11 = *(const bf16x8*)(pk + 9216);
            bf16x8 b20 = *(const bf16x8*)(pk + 16384);
            bf16x8 b21 = *(const bf16x8*)(pk + 17408);
            SIXPASS(b00, b01, b10, b11, b20, b21)
        }
        int n0 = cs * 32 + lrow;
        if (cs < 4) {
#pragma unroll
            for (int r = 0; r < 4; ++r) {
                size_t row = (size_t)(nodebase + kg * 4 + r) * HD;
                P[row + n0]      = acc0[r];
                P[row + n0 + 16] = acc1[r];
            }
        } else {
            float ba0 = ba[n0 - 128], ba1 = ba[n0 - 112];
#pragma unroll
            for (int r = 0; r < 4; ++r) {
                size_t row = (size_t)(nodebase + kg * 4 + r) * HD;
                D[row + n0 - 128] = acc0[r] + ba0;
                D[row + n0 - 112] = acc1[r] + ba1;
            }
        }
        __syncthreads();
        cur ^= 1;
    }
}

// ---------------- fused edge kernel: H1=relu(D[i]+P[j]) -> GEMM2 -> max -> out ----------------
template<bool FINAL>
__global__ __launch_bounds__(256) void edge_mlp(const float* __restrict__ P,
                                                const float* __restrict__ D,
                                                const int* __restrict__ nbr,
                                                const unsigned short* __restrict__ Wbt,
                                                const float* __restrict__ bb,
                                                const float* __restrict__ w5,
                                                float* __restrict__ out)
{
    __shared__ char lds[49152];
    const int t = threadIdx.x, wv = t >> 6, lane = t & 63;
    const int lrow = lane & 15, kg = lane >> 4;
    const int nodeA = blockIdx.x * 8 + wv * 2;
    const int i_node = nodeA + (lrow >> 3);
    const int j = nbr[(size_t)i_node * KNN + (lrow & 7)];

    const float* dp = D + (size_t)i_node * HD + kg * 8;
    const float* pp = P + (size_t)j * HD + kg * 8;

    bf16x8 A0[4], A1[4], A2[4];
    float sdot = 0.f;
#pragma unroll
    for (int kc = 0; kc < 4; ++kc) {
        float4 d0 = *(const float4*)(dp + kc * 32);
        float4 d1 = *(const float4*)(dp + kc * 32 + 4);
        float4 p0 = *(const float4*)(pp + kc * 32);
        float4 p1 = *(const float4*)(pp + kc * 32 + 4);
        float v[8];
        v[0]=fmaxf(d0.x+p0.x,0.f); v[1]=fmaxf(d0.y+p0.y,0.f);
        v[2]=fmaxf(d0.z+p0.z,0.f); v[3]=fmaxf(d0.w+p0.w,0.f);
        v[4]=fmaxf(d1.x+p1.x,0.f); v[5]=fmaxf(d1.y+p1.y,0.f);
        v[6]=fmaxf(d1.z+p1.z,0.f); v[7]=fmaxf(d1.w+p1.w,0.f);
        if (FINAL) {
#pragma unroll
            for (int e = 0; e < 8; ++e)
                sdot = fmaf(v[e], w5[kc * 32 + kg * 8 + e], sdot);
        } else {
#pragma unroll
            for (int e = 0; e < 8; ++e) {
                unsigned short b1 = bf16rn(v[e]); float r1 = v[e] - bf16tof(b1);
                unsigned short b2 = bf16rn(r1);   float r2 = r1   - bf16tof(b2);
                unsigned short b3 = bf16rn(r2);
                A0[kc][e] = (short)b1; A1[kc][e] = (short)b2; A2[kc][e] = (short)b3;
            }
        }
    }

    if (!FINAL) {
        char* ldsw = lds + wv * 1024;
        const unsigned short* wsrc = Wbt + t * 8;
#pragma unroll
        for (int i = 0; i < 6; ++i)
            GLOAD_LDS16(wsrc + i * 2048, ldsw + i * 4096);
        __syncthreads();

        int cur = 0;
        for (int cs = 0; cs < 4; ++cs) {
            if (cs < 3) {
#pragma unroll
                for (int i = 0; i < 6; ++i)
                    GLOAD_LDS16(wsrc + (size_t)(cs + 1) * 12288 + i * 2048,
                                ldsw + (cur ^ 1) * 24576 + i * 4096);
            }
            const char* pb = lds + cur * 24576 + kg * 256 + lrow * 16;  // conflict-free
            f32x4 acc0 = {0.f,0.f,0.f,0.f};
            f32x4 acc1 = {0.f,0.f,0.f,0.f};
#pragma unroll
            for (int kc = 0; kc < 4; ++kc) {
                const char* pk = pb + kc * 2048;
                bf16x8 b00 = *(const bf16x8*)(pk);
                bf16x8 b01 = *(const bf16x8*)(pk + 1024);
                bf16x8 b10 = *(const bf16x8*)(pk + 8192);
                bf16x8 b11 = *(const bf16x8*)(pk + 9216);
                bf16x8 b20 = *(const bf16x8*)(pk + 16384);
                bf16x8 b21 = *(const bf16x8*)(pk + 17408);
                SIXPASS(b00, b01, b10, b11, b20, b21)
            }
            float bb0 = bb[cs * 32 + lrow];
            float bb1 = bb[cs * 32 + 16 + lrow];
            float m0 = fmaxf(fmaxf(acc0[0], acc0[1]), fmaxf(acc0[2], acc0[3]));
            float m1 = fmaxf(fmaxf(acc1[0], acc1[1]), fmaxf(acc1[2], acc1[3]));
            m0 = fmaxf(m0 + bb0, 0.f);
            m1 = fmaxf(m1 + bb1, 0.f);
            m0 = fmaxf(m0, __shfl_xor(m0, 16));
            m1 = fmaxf(m1, __shfl_xor(m1, 16));
            if (kg == 0) {
                out[(size_t)nodeA * HD + cs * 32 + lrow]      = m0;
                out[(size_t)nodeA * HD + cs * 32 + 16 + lrow] = m1;
            } else if (kg == 2) {
                out[(size_t)(nodeA + 1) * HD + cs * 32 + lrow]      = m0;
                out[(size_t)(nodeA + 1) * HD + cs * 32 + 16 + lrow] = m1;
            }
            __syncthreads();
            cur ^= 1;
        }
    } else {
        sdot += __shfl_xor(sdot, 16);
        sdot += __shfl_xor(sdot, 32);
        float s = fmaxf(sdot + bb[0], 0.f);
#pragma unroll
        for (int m = 1; m < 8; m <<= 1)
            s = fmaxf(s, __shfl_xor(s, m));
        if (lane == 0) out[nodeA]     = 1.f / (1.f + expf(-s));
        if (lane == 8) out[nodeA + 1] = 1.f / (1.f + expf(-s));
    }
}

extern "C" void kernel_launch(void* const* d_in, const int* in_sizes, int n_in,
                              void* d_out, int out_size, void* d_ws, size_t ws_size,
                              hipStream_t stream) {
    const float* x     = (const float*)d_in[0];
    const float* W_enc = (const float*)d_in[3];
    const float* b_enc = (const float*)d_in[4];
    const float* W1a = (const float*)d_in[5];
    const float* b1a = (const float*)d_in[6];
    const float* W1b = (const float*)d_in[7];
    const float* b1b = (const float*)d_in[8];
    const float* W2a = (const float*)d_in[9];
    const float* b2a = (const float*)d_in[10];
    const float* W2b = (const float*)d_in[11];
    const float* b2b = (const float*)d_in[12];
    const float* W5a = (const float*)d_in[13];
    const float* b5a = (const float*)d_in[14];
    const float* W5b = (const float*)d_in[15];
    const float* b5b = (const float*)d_in[16];

    float* h0   = (float*)d_ws;                                  // 16 MB
    float* h1   = h0 + (size_t)NTOT*HD;                          // 16 MB
    float* sqg  = h1 + (size_t)NTOT*HD;                          // 128 KB
    int*   idxb = (int*)(sqg + NTOT);                            // 1 MB
    unsigned short* hs = (unsigned short*)(idxb + (size_t)NTOT*KNN);  // 24 MB
    float* Dbuf = (float*)(hs + (size_t)3*NTOT*HD);              // 16 MB
    unsigned short* Wt1  = (unsigned short*)(Dbuf + (size_t)NTOT*HD);
    unsigned short* Wt2  = Wt1 + 98304;
    unsigned short* Wt5  = Wt2 + 98304;
    unsigned short* Wbt1 = Wt5 + 98304;
    unsigned short* Wbt2 = Wbt1 + 49152;

    float* cd = Dbuf;
    int*   ci = (int*)(Dbuf + (size_t)NTOT*64);

    prep_wcat<<<128, 256, 0, stream>>>(W1a, Wt1);
    prep_wcat<<<128, 256, 0, stream>>>(W2a, Wt2);
    prep_wcat<<<128, 256, 0, stream>>>(W5a, Wt5);
    prep_wb  <<< 64, 256, 0, stream>>>(W1b, Wbt1);
    prep_wb  <<< 64, 256, 0, stream>>>(W2b, Wbt2);

    enc_kernel<<<NTOT*HD/256, 256, 0, stream>>>(x, W_enc, b_enc, h0);

    // layer 1: h0 -> h1
    split_kernel<<<NTOT/4, 256, 0, stream>>>(h0, hs, sqg);
    knn_mfma   <<<1024, 256, 0, stream>>>(hs, sqg, cd, ci);
    knn_merge  <<<NTOT/32, 256, 0, stream>>>(cd, ci, idxb);
    node_gemm  <<<NTOT/64, 256, 0, stream>>>(hs, Wt1, b1a, h0, Dbuf);
    edge_mlp<false><<<NTOT/8, 256, 0, stream>>>(h0, Dbuf, idxb, Wbt1, b1b, nullptr, h1);

    // layer 2: h1 -> h0
    split_kernel<<<NTOT/4, 256, 0, stream>>>(h1, hs, sqg);
    knn_mfma   <<<1024, 256, 0, stream>>>(hs, sqg, cd, ci);
    knn_merge  <<<NTOT/32, 256, 0, stream>>>(cd, ci, idxb);
    node_gemm  <<<NTOT/64, 256, 0, stream>>>(hs, Wt2, b2a, h1, Dbuf);
    edge_mlp<false><<<NTOT/8, 256, 0, stream>>>(h1, Dbuf, idxb, Wbt2, b2b, nullptr, h0);

    // layer 5: h0 -> d_out
    split_kernel<<<NTOT/4, 256, 0, stream>>>(h0, hs, sqg);
    knn_mfma   <<<1024, 256, 0, stream>>>(hs, sqg, cd, ci);
    knn_merge  <<<NTOT/32, 256, 0, stream>>>(cd, ci, idxb);
    node_gemm  <<<NTOT/64, 256, 0, stream>>>(hs, Wt5, b5a, h0, Dbuf);
    edge_mlp<true><<<NTOT/8, 256, 0, stream>>>(h0, Dbuf, idxb, nullptr, b5b, W5b, (float*)d_out);
}

// Round 8
// 494.511 us; speedup vs baseline: 5.0619x; 1.0524x over previous
//
#include <hip/hip_runtime.h>
#include <hip/hip_bf16.h>
#include <math.h>

#define BGR 16
#define NPG 2048
#define HD  128
#define KNN 8
#define NTOT (BGR*NPG)   // 32768

using bf16x8 = __attribute__((ext_vector_type(8))) short;
using f32x4  = __attribute__((ext_vector_type(4))) float;
using f32x16 = __attribute__((ext_vector_type(16))) float;

typedef __attribute__((address_space(3))) unsigned int lds_uint;
typedef const __attribute__((address_space(1))) unsigned int glob_uint;
#define GLOAD_LDS16(g, l) __builtin_amdgcn_global_load_lds((glob_uint*)(g), (lds_uint*)(l), 16, 0, 0)

__device__ inline unsigned short bf16rn(float f) {
    unsigned u = __float_as_uint(f);
    unsigned r = (u + 0x7FFFu + ((u >> 16) & 1u)) >> 16;
    return (unsigned short)r;
}
__device__ inline float bf16tof(unsigned short h) {
    return __uint_as_float(((unsigned)h) << 16);
}

// ---------------- fused encoder + 3-way split + sq-norm ----------------
__global__ __launch_bounds__(256) void enc_split(const float* __restrict__ x,
                                                 const float* __restrict__ W,
                                                 const float* __restrict__ bias,
                                                 unsigned short* __restrict__ hs,
                                                 float* __restrict__ sqg)
{
    const size_t plane = (size_t)NTOT * HD;
    int node = (blockIdx.x * 256 + threadIdx.x) >> 6;
    int lane = threadIdx.x & 63;
    float4 xv = *(const float4*)(x + (size_t)node * 4);
    float v0 = bias[lane], v1 = bias[lane + 64];
    const float* xf = (const float*)&xv;
#pragma unroll
    for (int f = 0; f < 4; ++f) {
        v0 = fmaf(xf[f], W[f * 128 + lane], v0);
        v1 = fmaf(xf[f], W[f * 128 + lane + 64], v1);
    }
    float s = fmaf(v0, v0, v1 * v1);
#pragma unroll
    for (int off = 32; off >= 1; off >>= 1)
        s += __shfl_xor(s, off);
    if (lane == 0) sqg[node] = s;
#pragma unroll
    for (int q = 0; q < 2; ++q) {
        float v = q ? v1 : v0;
        int   d = lane + q * 64;
        unsigned short b1 = bf16rn(v);  float r1 = v  - bf16tof(b1);
        unsigned short b2 = bf16rn(r1); float r2 = r1 - bf16tof(b2);
        unsigned short b3 = bf16rn(r2);
        size_t base = (size_t)node * HD + d;
        hs[base]             = b1;
        hs[base + plane]     = b2;
        hs[base + 2 * plane] = b3;
    }
}

// ---------------- weight prep (unchanged layout) ----------------
__global__ __launch_bounds__(256) void prep_wcat(const float* __restrict__ Wa,
                                                 unsigned short* __restrict__ Wt)
{
    int gid = blockIdx.x * 256 + threadIdx.x;   // 32768 = 128k x 256n
    int k = gid >> 8, n = gid & 255;
    float w;
    if (n < 128) w = Wa[(128 + k) * 128 + n];
    else { int nn = n - 128; w = Wa[k * 128 + nn] - Wa[(128 + k) * 128 + nn]; }
    unsigned short b1 = bf16rn(w);  float r1 = w  - bf16tof(b1);
    unsigned short b2 = bf16rn(r1); float r2 = r1 - bf16tof(b2);
    unsigned short b3 = bf16rn(r2);
    int cs = n >> 5, h = (n >> 4) & 1, c = n & 15, kc = k >> 5, kg = (k >> 3) & 3, e = k & 7;
    size_t off = (size_t)cs * 12288 + kc * 1024 + h * 512 + kg * 128 + c * 8 + e;
    Wt[off] = b1; Wt[off + 4096] = b2; Wt[off + 8192] = b3;
}

__global__ __launch_bounds__(256) void prep_wb(const float* __restrict__ Wb,
                                               unsigned short* __restrict__ Wt)
{
    int gid = blockIdx.x * 256 + threadIdx.x;   // 16384 = 128k x 128n
    int k = gid >> 7, n = gid & 127;
    float w = Wb[k * 128 + n];
    unsigned short b1 = bf16rn(w);  float r1 = w  - bf16tof(b1);
    unsigned short b2 = bf16rn(r1); float r2 = r1 - bf16tof(b2);
    unsigned short b3 = bf16rn(r2);
    int cs = n >> 5, h = (n >> 4) & 1, c = n & 15, kc = k >> 5, kg = (k >> 3) & 3, e = k & 7;
    size_t off = (size_t)cs * 12288 + kc * 1024 + h * 512 + kg * 128 + c * 8 + e;
    Wt[off] = b1; Wt[off + 4096] = b2; Wt[off + 8192] = b3;
}

#define SIXPASS(B00,B01,B10,B11,B20,B21) \
    acc0 = __builtin_amdgcn_mfma_f32_16x16x32_bf16(A0[kc], B00, acc0, 0, 0, 0); \
    acc1 = __builtin_amdgcn_mfma_f32_16x16x32_bf16(A0[kc], B01, acc1, 0, 0, 0); \
    acc0 = __builtin_amdgcn_mfma_f32_16x16x32_bf16(A0[kc], B10, acc0, 0, 0, 0); \
    acc1 = __builtin_amdgcn_mfma_f32_16x16x32_bf16(A0[kc], B11, acc1, 0, 0, 0); \
    acc0 = __builtin_amdgcn_mfma_f32_16x16x32_bf16(A1[kc], B00, acc0, 0, 0, 0); \
    acc1 = __builtin_amdgcn_mfma_f32_16x16x32_bf16(A1[kc], B01, acc1, 0, 0, 0); \
    acc0 = __builtin_amdgcn_mfma_f32_16x16x32_bf16(A0[kc], B20, acc0, 0, 0, 0); \
    acc1 = __builtin_amdgcn_mfma_f32_16x16x32_bf16(A0[kc], B21, acc1, 0, 0, 0); \
    acc0 = __builtin_amdgcn_mfma_f32_16x16x32_bf16(A1[kc], B10, acc0, 0, 0, 0); \
    acc1 = __builtin_amdgcn_mfma_f32_16x16x32_bf16(A1[kc], B11, acc1, 0, 0, 0); \
    acc0 = __builtin_amdgcn_mfma_f32_16x16x32_bf16(A2[kc], B00, acc0, 0, 0, 0); \
    acc1 = __builtin_amdgcn_mfma_f32_16x16x32_bf16(A2[kc], B01, acc1, 0, 0, 0);

// ---------------- kNN via 32x32x16 MFMA ----------------
// Round-8: rows 2-plane (RB[2][8], 64 regs) x cols 3-plane = 6 passes cover ALL
// cross terms; dual accumulator chains halve MFMA dependency depth; 3 waves/SIMD.
__global__ __launch_bounds__(256, 3) void knn_mfma(const unsigned short* __restrict__ hs,
                                                   const float* __restrict__ sqg,
                                                   float* __restrict__ cand_d,
                                                   int* __restrict__ cand_i)
{
    __shared__ ulong2 ldsraw[3200];   // 48KB dbuf + 2KB sq
    char* ldsc = (char*)ldsraw;
    float* sqs = (float*)(ldsc + 49152);

    const size_t plane = (size_t)NTOT * HD;
    const int t = threadIdx.x;
    const int b = blockIdx.x;           // 1024 blocks
    const int slot = b >> 3;
    const int g  = (b & 7) | ((slot & 1) << 3);
    const int rb = (slot >> 1) & 15;
    const int cs = (slot >> 5) & 3;
    const int gbase = g * NPG;
    const int cbase = cs * 512;
    const int wv = t >> 6, lane = t & 63;
    const int rl = lane & 31, kh = lane >> 5;
    const int myrow = rb * 128 + wv * 32 + rl;

    sqs[t]       = sqg[gbase + cbase + t];
    sqs[t + 256] = sqg[gbase + cbase + 256 + t];

    // row operand (B): 2 planes, * (-2) exact via exponent+1 & sign-flip
    bf16x8 RB[2][8];
    {
        const unsigned short* rrow = hs + (size_t)(gbase + myrow) * HD + kh * 8;
#pragma unroll
        for (int p = 0; p < 2; ++p)
#pragma unroll
            for (int kch = 0; kch < 8; ++kch) {
                bf16x8 v = *(const bf16x8*)(rrow + (size_t)p * plane + kch * 16);
                unsigned* u = (unsigned*)&v;
#pragma unroll
                for (int w = 0; w < 4; ++w)
                    u[w] = (u[w] + 0x00800080u) ^ 0x80008000u;
                RB[p][kch] = v;
            }
    }
    const float sqi = sqg[gbase + myrow];

    // staging: single per-thread base + compile-time chunk offsets
    const unsigned short* sb = hs + (size_t)(gbase + cbase + (t & 31)) * HD
                             + (t >> 6) * 16 + ((t >> 5) & 1) * 8;
    char* ldsw = ldsc + wv * 1024;

#pragma unroll
    for (int i = 0; i < 6; ++i)
        GLOAD_LDS16(sb + (size_t)(i >> 1) * plane + (i & 1) * 64, ldsw + i * 4096);
    __syncthreads();

    const float INF = __uint_as_float(0x7F800000u);
    float bd[8];
#pragma unroll
    for (int s = 0; s < 8; ++s) bd[s] = INF;

    int cur = 0;
    for (int s = 0; s < 16; ++s) {
        if (s < 15) {
            const unsigned short* sbn = sb + (size_t)(s + 1) * 32 * HD;
#pragma unroll
            for (int i = 0; i < 6; ++i)
                GLOAD_LDS16(sbn + (size_t)(i >> 1) * plane + (i & 1) * 64,
                            ldsw + (cur ^ 1) * 24576 + i * 4096);
        }
        const char* pstep = ldsc + cur * 24576 + lane * 16;
        f32x16 acca = {0.f,0.f,0.f,0.f,0.f,0.f,0.f,0.f,0.f,0.f,0.f,0.f,0.f,0.f,0.f,0.f};
        f32x16 accb = acca;
        __builtin_amdgcn_s_setprio(1);
#pragma unroll
        for (int kch = 0; kch < 8; ++kch) {
            bf16x8 c0 = *(const bf16x8*)(pstep + kch * 1024);
            bf16x8 c1 = *(const bf16x8*)(pstep + 8192 + kch * 1024);
            bf16x8 c2 = *(const bf16x8*)(pstep + 16384 + kch * 1024);
            acca = __builtin_amdgcn_mfma_f32_32x32x16_bf16(c0, RB[0][kch], acca, 0, 0, 0);
            accb = __builtin_amdgcn_mfma_f32_32x32x16_bf16(c0, RB[1][kch], accb, 0, 0, 0);
            acca = __builtin_amdgcn_mfma_f32_32x32x16_bf16(c1, RB[0][kch], acca, 0, 0, 0);
            accb = __builtin_amdgcn_mfma_f32_32x32x16_bf16(c1, RB[1][kch], accb, 0, 0, 0);
            acca = __builtin_amdgcn_mfma_f32_32x32x16_bf16(c2, RB[0][kch], acca, 0, 0, 0);
            accb = __builtin_amdgcn_mfma_f32_32x32x16_bf16(c2, RB[1][kch], accb, 0, 0, 0);
        }
        __builtin_amdgcn_s_setprio(0);
        // packed-key top-8: key = (bits(sqi+sqj+acc) & ~0xFF) | (s*16+grp*4+e)
        const unsigned lidbase = (unsigned)(s << 4);
#pragma unroll
        for (int grp = 0; grp < 4; ++grp) {
            f32x4 sq4 = *(const f32x4*)(sqs + s * 32 + grp * 8 + kh * 4);
#pragma unroll
            for (int e = 0; e < 4; ++e) {
                float dsum = acca[grp * 4 + e] + accb[grp * 4 + e];
                float dp = (sqi + sq4[e]) + dsum;
                unsigned ku = (__float_as_uint(dp) & 0xFFFFFF00u)
                            | (lidbase + (unsigned)(grp * 4 + e));
                float k = __uint_as_float(ku);
                bd[7] = __builtin_amdgcn_fmed3f(bd[6], k, bd[7]);
                bd[6] = __builtin_amdgcn_fmed3f(bd[5], k, bd[6]);
                bd[5] = __builtin_amdgcn_fmed3f(bd[4], k, bd[5]);
                bd[4] = __builtin_amdgcn_fmed3f(bd[3], k, bd[4]);
                bd[3] = __builtin_amdgcn_fmed3f(bd[2], k, bd[3]);
                bd[2] = __builtin_amdgcn_fmed3f(bd[1], k, bd[2]);
                bd[1] = __builtin_amdgcn_fmed3f(bd[0], k, bd[1]);
                bd[0] = fminf(bd[0], k);
            }
        }
        __syncthreads();
        cur ^= 1;
    }

    // decode + write sorted run of 8 (row, col-half kh, slice cs)
    const size_t ob = (size_t)(gbase + myrow) * 64 + cs * 16 + kh * 8;
#pragma unroll
    for (int sel = 0; sel < 8; ++sel) {
        unsigned u = __float_as_uint(bd[sel]);
        unsigned lid = u & 255u;
        int j = cbase + (int)(lid >> 4) * 32 + (int)((lid >> 2) & 3u) * 8
              + kh * 4 + (int)(lid & 3u);
        cand_d[ob + sel] = bd[sel];
        cand_i[ob + sel] = gbase + j;
    }
}

// ---------------- merge 8 sorted runs of 8 per row -> final top-8 ----------------
__global__ __launch_bounds__(256) void knn_merge(const float* __restrict__ cand_d,
                                                 const int* __restrict__ cand_i,
                                                 int* __restrict__ nbr)
{
    const int t = threadIdx.x;
    const int row = blockIdx.x * 32 + (t >> 3);
    const int run = t & 7;
    const float* pd = cand_d + (size_t)row * 64 + run * 8;
    const int*   pi = cand_i + (size_t)row * 64 + run * 8;
    float d[8]; int ix[8];
#pragma unroll
    for (int k = 0; k < 8; ++k) { d[k] = pd[k]; ix[k] = pi[k]; }
    const float INF = __uint_as_float(0x7F800000u);
    int* op = nbr + (size_t)row * KNN;
    float hd = d[0]; int hi = ix[0];
#pragma unroll
    for (int sel = 0; sel < 8; ++sel) {
        float md = hd; int mi = hi;
#pragma unroll
        for (int m = 1; m < 8; m <<= 1) {
            float od = __shfl_xor(md, m, 8);
            int   oi = __shfl_xor(mi, m, 8);
            bool tk = (od < md) || (od == md && oi < mi);
            md = tk ? od : md; mi = tk ? oi : mi;
        }
        if (run == sel) op[sel] = mi;
        bool win = (hd == md) && (hi == mi);
        if (win) {
            d[0]=d[1]; ix[0]=ix[1]; d[1]=d[2]; ix[1]=ix[2];
            d[2]=d[3]; ix[2]=ix[3]; d[3]=d[4]; ix[3]=ix[4];
            d[4]=d[5]; ix[4]=ix[5]; d[5]=d[6]; ix[5]=ix[6];
            d[6]=d[7]; ix[6]=ix[7]; d[7]=INF;  ix[7]=0x7fffffff;
        }
        hd = d[0]; hi = ix[0];
    }
}

// ---------------- node GEMM: P = h@Wa_bot ; D = h@(Wa_top-Wa_bot) + ba ----------------
__global__ __launch_bounds__(256) void node_gemm(const unsigned short* __restrict__ hs,
                                                 const unsigned short* __restrict__ Wt,
                                                 const float* __restrict__ ba,
                                                 float* __restrict__ P,
                                                 float* __restrict__ D)
{
    __shared__ char lds[49152];
    const size_t plane = (size_t)NTOT * HD;
    const int t = threadIdx.x, wv = t >> 6, lane = t & 63;
    const int lrow = lane & 15, kg = lane >> 4;
    const int nodebase = blockIdx.x * 64 + wv * 16;

    const unsigned short* arow = hs + (size_t)(nodebase + lrow) * HD + kg * 8;
    bf16x8 A0[4], A1[4], A2[4];
#pragma unroll
    for (int kc = 0; kc < 4; ++kc) {
        A0[kc] = *(const bf16x8*)(arow + kc * 32);
        A1[kc] = *(const bf16x8*)(arow + plane + kc * 32);
        A2[kc] = *(const bf16x8*)(arow + 2 * plane + kc * 32);
    }

    char* ldsw = lds + wv * 1024;
    const unsigned short* wsrc = Wt + t * 8;
#pragma unroll
    for (int i = 0; i < 6; ++i)
        GLOAD_LDS16(wsrc + i * 2048, ldsw + i * 4096);
    __syncthreads();

    int cur = 0;
    for (int cs = 0; cs < 8; ++cs) {
        if (cs < 7) {
#pragma unroll
            for (int i = 0; i < 6; ++i)
                GLOAD_LDS16(wsrc + (size_t)(cs + 1) * 12288 + i * 2048,
                            ldsw + (cur ^ 1) * 24576 + i * 4096);
        }
        const char* pb = lds + cur * 24576 + kg * 256 + lrow * 16;   // conflict-free
        f32x4 acc0 = {0.f,0.f,0.f,0.f};
        f32x4 acc1 = {0.f,0.f,0.f,0.f};
#pragma unroll
        for (int kc = 0; kc < 4; ++kc) {
            const char* pk = pb + kc * 2048;
            bf16x8 b00 = *(const bf16x8*)(pk);
            bf16x8 b01 = *(const bf16x8*)(pk + 1024);
            bf16x8 b10 = *(const bf16x8*)(pk + 8192);
            bf16x8 b11 = *(const bf16x8*)(pk + 9216);
            bf16x8 b20 = *(const bf16x8*)(pk + 16384);
            bf16x8 b21 = *(const bf16x8*)(pk + 17408);
            SIXPASS(b00, b01, b10, b11, b20, b21)
        }
        int n0 = cs * 32 + lrow;
        if (cs < 4) {
#pragma unroll
            for (int r = 0; r < 4; ++r) {
                size_t row = (size_t)(nodebase + kg * 4 + r) * HD;
                P[row + n0]      = acc0[r];
                P[row + n0 + 16] = acc1[r];
            }
        } else {
            float ba0 = ba[n0 - 128], ba1 = ba[n0 - 112];
#pragma unroll
            for (int r = 0; r < 4; ++r) {
                size_t row = (size_t)(nodebase + kg * 4 + r) * HD;
                D[row + n0 - 128] = acc0[r] + ba0;
                D[row + n0 - 112] = acc1[r] + ba1;
            }
        }
        __syncthreads();
        cur ^= 1;
    }
}

// ---------------- fused edge kernel: H1=relu(D[i]+P[j]) -> GEMM2 -> max -> split-out ----------------
template<bool FINAL>
__global__ __launch_bounds__(256) void edge_mlp(const float* __restrict__ P,
                                                const float* __restrict__ D,
                                                const int* __restrict__ nbr,
                                                const unsigned short* __restrict__ Wbt,
                                                const float* __restrict__ bb,
                                                const float* __restrict__ w5,
                                                unsigned short* __restrict__ hsout,
                                                float* __restrict__ sqgout,
                                                float* __restrict__ out)
{
    __shared__ char lds[49152];
    const size_t plane = (size_t)NTOT * HD;
    const int t = threadIdx.x, wv = t >> 6, lane = t & 63;
    const int lrow = lane & 15, kg = lane >> 4;
    const int nodeA = blockIdx.x * 8 + wv * 2;
    const int i_node = nodeA + (lrow >> 3);
    const int j = nbr[(size_t)i_node * KNN + (lrow & 7)];

    const float* dp = D + (size_t)i_node * HD + kg * 8;
    const float* pp = P + (size_t)j * HD + kg * 8;

    bf16x8 A0[4], A1[4], A2[4];
    float sdot = 0.f;
#pragma unroll
    for (int kc = 0; kc < 4; ++kc) {
        float4 d0 = *(const float4*)(dp + kc * 32);
        float4 d1 = *(const float4*)(dp + kc * 32 + 4);
        float4 p0 = *(const float4*)(pp + kc * 32);
        float4 p1 = *(const float4*)(pp + kc * 32 + 4);
        float v[8];
        v[0]=fmaxf(d0.x+p0.x,0.f); v[1]=fmaxf(d0.y+p0.y,0.f);
        v[2]=fmaxf(d0.z+p0.z,0.f); v[3]=fmaxf(d0.w+p0.w,0.f);
        v[4]=fmaxf(d1.x+p1.x,0.f); v[5]=fmaxf(d1.y+p1.y,0.f);
        v[6]=fmaxf(d1.z+p1.z,0.f); v[7]=fmaxf(d1.w+p1.w,0.f);
        if (FINAL) {
#pragma unroll
            for (int e = 0; e < 8; ++e)
                sdot = fmaf(v[e], w5[kc * 32 + kg * 8 + e], sdot);
        } else {
#pragma unroll
            for (int e = 0; e < 8; ++e) {
                unsigned short b1 = bf16rn(v[e]); float r1 = v[e] - bf16tof(b1);
                unsigned short b2 = bf16rn(r1);   float r2 = r1   - bf16tof(b2);
                unsigned short b3 = bf16rn(r2);
                A0[kc][e] = (short)b1; A1[kc][e] = (short)b2; A2[kc][e] = (short)b3;
            }
        }
    }

    if (!FINAL) {
        char* ldsw = lds + wv * 1024;
        const unsigned short* wsrc = Wbt + t * 8;
#pragma unroll
        for (int i = 0; i < 6; ++i)
            GLOAD_LDS16(wsrc + i * 2048, ldsw + i * 4096);
        __syncthreads();

        const int mynode = nodeA + (kg >> 1);
        const bool writer = (kg & 1) == 0;
        float sqacc = 0.f;

        int cur = 0;
        for (int cs = 0; cs < 4; ++cs) {
            if (cs < 3) {
#pragma unroll
                for (int i = 0; i < 6; ++i)
                    GLOAD_LDS16(wsrc + (size_t)(cs + 1) * 12288 + i * 2048,
                                ldsw + (cur ^ 1) * 24576 + i * 4096);
            }
            const char* pb = lds + cur * 24576 + kg * 256 + lrow * 16;  // conflict-free
            f32x4 acc0 = {0.f,0.f,0.f,0.f};
            f32x4 acc1 = {0.f,0.f,0.f,0.f};
#pragma unroll
            for (int kc = 0; kc < 4; ++kc) {
                const char* pk = pb + kc * 2048;
                bf16x8 b00 = *(const bf16x8*)(pk);
                bf16x8 b01 = *(const bf16x8*)(pk + 1024);
                bf16x8 b10 = *(const bf16x8*)(pk + 8192);
                bf16x8 b11 = *(const bf16x8*)(pk + 9216);
                bf16x8 b20 = *(const bf16x8*)(pk + 16384);
                bf16x8 b21 = *(const bf16x8*)(pk + 17408);
                SIXPASS(b00, b01, b10, b11, b20, b21)
            }
            float bb0 = bb[cs * 32 + lrow];
            float bb1 = bb[cs * 32 + 16 + lrow];
            float m0 = fmaxf(fmaxf(acc0[0], acc0[1]), fmaxf(acc0[2], acc0[3]));
            float m1 = fmaxf(fmaxf(acc1[0], acc1[1]), fmaxf(acc1[2], acc1[3]));
            m0 = fmaxf(m0 + bb0, 0.f);
            m1 = fmaxf(m1 + bb1, 0.f);
            m0 = fmaxf(m0, __shfl_xor(m0, 16));
            m1 = fmaxf(m1, __shfl_xor(m1, 16));
            if (writer) {
                sqacc = fmaf(m0, m0, fmaf(m1, m1, sqacc));
                size_t base = (size_t)mynode * HD + cs * 32 + lrow;
                unsigned short c1 = bf16rn(m0); float r1 = m0 - bf16tof(c1);
                unsigned short c2 = bf16rn(r1); float r2 = r1 - bf16tof(c2);
                unsigned short c3 = bf16rn(r2);
                hsout[base]             = c1;
                hsout[base + plane]     = c2;
                hsout[base + 2 * plane] = c3;
                unsigned short e1 = bf16rn(m1); float s1 = m1 - bf16tof(e1);
                unsigned short e2 = bf16rn(s1); float s2 = s1 - bf16tof(e2);
                unsigned short e3 = bf16rn(s2);
                hsout[base + 16]             = e1;
                hsout[base + 16 + plane]     = e2;
                hsout[base + 16 + 2 * plane] = e3;
            }
            __syncthreads();
            cur ^= 1;
        }
        if (writer) {
#pragma unroll
            for (int m = 1; m < 16; m <<= 1)
                sqacc += __shfl_xor(sqacc, m, 16);
            if (lrow == 0) sqgout[mynode] = sqacc;
        }
    } else {
        sdot += __shfl_xor(sdot, 16);
        sdot += __shfl_xor(sdot, 32);
        float s = fmaxf(sdot + bb[0], 0.f);
#pragma unroll
        for (int m = 1; m < 8; m <<= 1)
            s = fmaxf(s, __shfl_xor(s, m));
        if (lane == 0) out[nodeA]     = 1.f / (1.f + expf(-s));
        if (lane == 8) out[nodeA + 1] = 1.f / (1.f + expf(-s));
    }
}

extern "C" void kernel_launch(void* const* d_in, const int* in_sizes, int n_in,
                              void* d_out, int out_size, void* d_ws, size_t ws_size,
                              hipStream_t stream) {
    const float* x     = (const float*)d_in[0];
    const float* W_enc = (const float*)d_in[3];
    const float* b_enc = (const float*)d_in[4];
    const float* W1a = (const float*)d_in[5];
    const float* b1a = (const float*)d_in[6];
    const float* W1b = (const float*)d_in[7];
    const float* b1b = (const float*)d_in[8];
    const float* W2a = (const float*)d_in[9];
    const float* b2a = (const float*)d_in[10];
    const float* W2b = (const float*)d_in[11];
    const float* b2b = (const float*)d_in[12];
    const float* W5a = (const float*)d_in[13];
    const float* b5a = (const float*)d_in[14];
    const float* W5b = (const float*)d_in[15];
    const float* b5b = (const float*)d_in[16];

    unsigned short* hs = (unsigned short*)d_ws;                  // 24 MB (3 planes)
    float* sqg  = (float*)(hs + (size_t)3*NTOT*HD);              // 128 KB
    int*   idxb = (int*)(sqg + NTOT);                            // 1 MB
    float* Dbuf = (float*)(idxb + (size_t)NTOT*KNN);             // 16 MB
    float* Pbuf = Dbuf + (size_t)NTOT*HD;                        // 16 MB
    unsigned short* Wt1  = (unsigned short*)(Pbuf + (size_t)NTOT*HD);
    unsigned short* Wt2  = Wt1 + 98304;
    unsigned short* Wt5  = Wt2 + 98304;
    unsigned short* Wbt1 = Wt5 + 98304;
    unsigned short* Wbt2 = Wbt1 + 49152;

    // cand buffers (8MB + 8MB) overlay Dbuf; node_gemm writes Dbuf after merge consumed them
    float* cd = Dbuf;
    int*   ci = (int*)(Dbuf + (size_t)NTOT*64);

    prep_wcat<<<128, 256, 0, stream>>>(W1a, Wt1);
    prep_wcat<<<128, 256, 0, stream>>>(W2a, Wt2);
    prep_wcat<<<128, 256, 0, stream>>>(W5a, Wt5);
    prep_wb  <<< 64, 256, 0, stream>>>(W1b, Wbt1);
    prep_wb  <<< 64, 256, 0, stream>>>(W2b, Wbt2);

    enc_split<<<NTOT/4, 256, 0, stream>>>(x, W_enc, b_enc, hs, sqg);

    // layer 1 (hs updated in place by edge_mlp)
    knn_mfma   <<<1024, 256, 0, stream>>>(hs, sqg, cd, ci);
    knn_merge  <<<NTOT/32, 256, 0, stream>>>(cd, ci, idxb);
    node_gemm  <<<NTOT/64, 256, 0, stream>>>(hs, Wt1, b1a, Pbuf, Dbuf);
    edge_mlp<false><<<NTOT/8, 256, 0, stream>>>(Pbuf, Dbuf, idxb, Wbt1, b1b, nullptr, hs, sqg, nullptr);

    // layer 2
    knn_mfma   <<<1024, 256, 0, stream>>>(hs, sqg, cd, ci);
    knn_merge  <<<NTOT/32, 256, 0, stream>>>(cd, ci, idxb);
    node_gemm  <<<NTOT/64, 256, 0, stream>>>(hs, Wt2, b2a, Pbuf, Dbuf);
    edge_mlp<false><<<NTOT/8, 256, 0, stream>>>(Pbuf, Dbuf, idxb, Wbt2, b2b, nullptr, hs, sqg, nullptr);

    // layer 5 (final)
    knn_mfma   <<<1024, 256, 0, stream>>>(hs, sqg, cd, ci);
    knn_merge  <<<NTOT/32, 256, 0, stream>>>(cd, ci, idxb);
    node_gemm  <<<NTOT/64, 256, 0, stream>>>(hs, Wt5, b5a, Pbuf, Dbuf);
    edge_mlp<true><<<NTOT/8, 256, 0, stream>>>(Pbuf, Dbuf, idxb, nullptr, b5b, W5b, nullptr, nullptr, (float*)d_out);
}

// Round 9
// 428.904 us; speedup vs baseline: 5.8361x; 1.1530x over previous
//
#include <hip/hip_runtime.h>
#include <hip/hip_bf16.h>
#include <math.h>

#define BGR 16
#define NPG 2048
#define HD  128
#define KNN 8
#define NTOT (BGR*NPG)   // 32768

using bf16x8 = __attribute__((ext_vector_type(8))) short;
using f32x4  = __attribute__((ext_vector_type(4))) float;
using f32x16 = __attribute__((ext_vector_type(16))) float;

typedef __attribute__((address_space(3))) unsigned int lds_uint;
typedef const __attribute__((address_space(1))) unsigned int glob_uint;
#define GLOAD_LDS16(g, l) __builtin_amdgcn_global_load_lds((glob_uint*)(g), (lds_uint*)(l), 16, 0, 0)

__device__ inline unsigned short bf16rn(float f) {
    unsigned u = __float_as_uint(f);
    unsigned r = (u + 0x7FFFu + ((u >> 16) & 1u)) >> 16;
    return (unsigned short)r;
}
__device__ inline float bf16tof(unsigned short h) {
    return __uint_as_float(((unsigned)h) << 16);
}

// ---------------- fused encoder + 2-way split + sq-norm ----------------
__global__ __launch_bounds__(256) void enc_split(const float* __restrict__ x,
                                                 const float* __restrict__ W,
                                                 const float* __restrict__ bias,
                                                 unsigned short* __restrict__ hs,
                                                 float* __restrict__ sqg)
{
    const size_t plane = (size_t)NTOT * HD;
    int node = (blockIdx.x * 256 + threadIdx.x) >> 6;
    int lane = threadIdx.x & 63;
    float4 xv = *(const float4*)(x + (size_t)node * 4);
    float v0 = bias[lane], v1 = bias[lane + 64];
    const float* xf = (const float*)&xv;
#pragma unroll
    for (int f = 0; f < 4; ++f) {
        v0 = fmaf(xf[f], W[f * 128 + lane], v0);
        v1 = fmaf(xf[f], W[f * 128 + lane + 64], v1);
    }
    float s = fmaf(v0, v0, v1 * v1);
#pragma unroll
    for (int off = 32; off >= 1; off >>= 1)
        s += __shfl_xor(s, off);
    if (lane == 0) sqg[node] = s;
#pragma unroll
    for (int q = 0; q < 2; ++q) {
        float v = q ? v1 : v0;
        int   d = lane + q * 64;
        unsigned short b1 = bf16rn(v);  float r1 = v - bf16tof(b1);
        unsigned short b2 = bf16rn(r1);
        size_t base = (size_t)node * HD + d;
        hs[base]         = b1;
        hs[base + plane] = b2;
    }
}

// ---------------- weight prep (layout unchanged; plane 2 written but unused) ----------------
__global__ __launch_bounds__(256) void prep_wcat(const float* __restrict__ Wa,
                                                 unsigned short* __restrict__ Wt)
{
    int gid = blockIdx.x * 256 + threadIdx.x;   // 32768 = 128k x 256n
    int k = gid >> 8, n = gid & 255;
    float w;
    if (n < 128) w = Wa[(128 + k) * 128 + n];
    else { int nn = n - 128; w = Wa[k * 128 + nn] - Wa[(128 + k) * 128 + nn]; }
    unsigned short b1 = bf16rn(w);  float r1 = w - bf16tof(b1);
    unsigned short b2 = bf16rn(r1);
    int cs = n >> 5, h = (n >> 4) & 1, c = n & 15, kc = k >> 5, kg = (k >> 3) & 3, e = k & 7;
    size_t off = (size_t)cs * 12288 + kc * 1024 + h * 512 + kg * 128 + c * 8 + e;
    Wt[off] = b1; Wt[off + 4096] = b2;
}

__global__ __launch_bounds__(256) void prep_wb(const float* __restrict__ Wb,
                                               unsigned short* __restrict__ Wt)
{
    int gid = blockIdx.x * 256 + threadIdx.x;   // 16384 = 128k x 128n
    int k = gid >> 7, n = gid & 127;
    float w = Wb[k * 128 + n];
    unsigned short b1 = bf16rn(w);  float r1 = w - bf16tof(b1);
    unsigned short b2 = bf16rn(r1);
    int cs = n >> 5, h = (n >> 4) & 1, c = n & 15, kc = k >> 5, kg = (k >> 3) & 3, e = k & 7;
    size_t off = (size_t)cs * 12288 + kc * 1024 + h * 512 + kg * 128 + c * 8 + e;
    Wt[off] = b1; Wt[off + 4096] = b2;
}

// 4-pass: (A0+A1)(B0+B1) complete
#define FOURPASS(B00,B01,B10,B11) \
    acc0 = __builtin_amdgcn_mfma_f32_16x16x32_bf16(A0[kc], B00, acc0, 0, 0, 0); \
    acc1 = __builtin_amdgcn_mfma_f32_16x16x32_bf16(A0[kc], B01, acc1, 0, 0, 0); \
    acc0 = __builtin_amdgcn_mfma_f32_16x16x32_bf16(A1[kc], B00, acc0, 0, 0, 0); \
    acc1 = __builtin_amdgcn_mfma_f32_16x16x32_bf16(A1[kc], B01, acc1, 0, 0, 0); \
    acc0 = __builtin_amdgcn_mfma_f32_16x16x32_bf16(A0[kc], B10, acc0, 0, 0, 0); \
    acc1 = __builtin_amdgcn_mfma_f32_16x16x32_bf16(A0[kc], B11, acc1, 0, 0, 0); \
    acc0 = __builtin_amdgcn_mfma_f32_16x16x32_bf16(A1[kc], B10, acc0, 0, 0, 0); \
    acc1 = __builtin_amdgcn_mfma_f32_16x16x32_bf16(A1[kc], B11, acc1, 0, 0, 0);

// ---------------- kNN via 32x32x16 MFMA, 2x2-plane (4 passes) ----------------
__global__ __launch_bounds__(256, 3) void knn_mfma(const unsigned short* __restrict__ hs,
                                                   const float* __restrict__ sqg,
                                                   float* __restrict__ cand_d,
                                                   int* __restrict__ cand_i)
{
    __shared__ ulong2 ldsraw[2176];   // 32KB dbuf + 2KB sq
    char* ldsc = (char*)ldsraw;
    float* sqs = (float*)(ldsc + 32768);

    const size_t plane = (size_t)NTOT * HD;
    const int t = threadIdx.x;
    const int b = blockIdx.x;           // 1024 blocks
    const int slot = b >> 3;
    const int g  = (b & 7) | ((slot & 1) << 3);
    const int rb = (slot >> 1) & 15;
    const int cs = (slot >> 5) & 3;
    const int gbase = g * NPG;
    const int cbase = cs * 512;
    const int wv = t >> 6, lane = t & 63;
    const int rl = lane & 31, kh = lane >> 5;
    const int myrow = rb * 128 + wv * 32 + rl;

    sqs[t]       = sqg[gbase + cbase + t];
    sqs[t + 256] = sqg[gbase + cbase + 256 + t];

    // row operand (B): 2 planes, * (-2) exact via exponent+1 & sign-flip
    bf16x8 RB[2][8];
    {
        const unsigned short* rrow = hs + (size_t)(gbase + myrow) * HD + kh * 8;
#pragma unroll
        for (int p = 0; p < 2; ++p)
#pragma unroll
            for (int kch = 0; kch < 8; ++kch) {
                bf16x8 v = *(const bf16x8*)(rrow + (size_t)p * plane + kch * 16);
                unsigned* u = (unsigned*)&v;
#pragma unroll
                for (int w = 0; w < 4; ++w)
                    u[w] = (u[w] + 0x00800080u) ^ 0x80008000u;
                RB[p][kch] = v;
            }
    }
    const float sqi = sqg[gbase + myrow];

    // staging: 4 chunks of 4KB per 16KB step-buffer
    const unsigned short* sb = hs + (size_t)(gbase + cbase + (t & 31)) * HD
                             + (t >> 6) * 16 + ((t >> 5) & 1) * 8;
    char* ldsw = ldsc + wv * 1024;

#pragma unroll
    for (int i = 0; i < 4; ++i)
        GLOAD_LDS16(sb + (size_t)(i >> 1) * plane + (i & 1) * 64, ldsw + i * 4096);
    __syncthreads();

    const float INF = __uint_as_float(0x7F800000u);
    float bd[8];
#pragma unroll
    for (int s = 0; s < 8; ++s) bd[s] = INF;

    int cur = 0;
    for (int s = 0; s < 16; ++s) {
        if (s < 15) {
            const unsigned short* sbn = sb + (size_t)(s + 1) * 32 * HD;
#pragma unroll
            for (int i = 0; i < 4; ++i)
                GLOAD_LDS16(sbn + (size_t)(i >> 1) * plane + (i & 1) * 64,
                            ldsw + (cur ^ 1) * 16384 + i * 4096);
        }
        const char* pstep = ldsc + cur * 16384 + lane * 16;
        f32x16 acca = {0.f,0.f,0.f,0.f,0.f,0.f,0.f,0.f,0.f,0.f,0.f,0.f,0.f,0.f,0.f,0.f};
        f32x16 accb = acca;
        __builtin_amdgcn_s_setprio(1);
#pragma unroll
        for (int kch = 0; kch < 8; ++kch) {
            bf16x8 c0 = *(const bf16x8*)(pstep + kch * 1024);
            bf16x8 c1 = *(const bf16x8*)(pstep + 8192 + kch * 1024);
            acca = __builtin_amdgcn_mfma_f32_32x32x16_bf16(c0, RB[0][kch], acca, 0, 0, 0);
            accb = __builtin_amdgcn_mfma_f32_32x32x16_bf16(c0, RB[1][kch], accb, 0, 0, 0);
            acca = __builtin_amdgcn_mfma_f32_32x32x16_bf16(c1, RB[0][kch], acca, 0, 0, 0);
            accb = __builtin_amdgcn_mfma_f32_32x32x16_bf16(c1, RB[1][kch], accb, 0, 0, 0);
        }
        __builtin_amdgcn_s_setprio(0);
        // packed-key top-8: key = (bits(sqi+sqj+acc) & ~0xFF) | (s*16+grp*4+e)
        const unsigned lidbase = (unsigned)(s << 4);
#pragma unroll
        for (int grp = 0; grp < 4; ++grp) {
            f32x4 sq4 = *(const f32x4*)(sqs + s * 32 + grp * 8 + kh * 4);
#pragma unroll
            for (int e = 0; e < 4; ++e) {
                float dsum = acca[grp * 4 + e] + accb[grp * 4 + e];
                float dp = (sqi + sq4[e]) + dsum;
                unsigned ku = (__float_as_uint(dp) & 0xFFFFFF00u)
                            | (lidbase + (unsigned)(grp * 4 + e));
                float k = __uint_as_float(ku);
                bd[7] = __builtin_amdgcn_fmed3f(bd[6], k, bd[7]);
                bd[6] = __builtin_amdgcn_fmed3f(bd[5], k, bd[6]);
                bd[5] = __builtin_amdgcn_fmed3f(bd[4], k, bd[5]);
                bd[4] = __builtin_amdgcn_fmed3f(bd[3], k, bd[4]);
                bd[3] = __builtin_amdgcn_fmed3f(bd[2], k, bd[3]);
                bd[2] = __builtin_amdgcn_fmed3f(bd[1], k, bd[2]);
                bd[1] = __builtin_amdgcn_fmed3f(bd[0], k, bd[1]);
                bd[0] = fminf(bd[0], k);
            }
        }
        __syncthreads();
        cur ^= 1;
    }

    // decode + write sorted run of 8 (row, col-half kh, slice cs)
    const size_t ob = (size_t)(gbase + myrow) * 64 + cs * 16 + kh * 8;
#pragma unroll
    for (int sel = 0; sel < 8; ++sel) {
        unsigned u = __float_as_uint(bd[sel]);
        unsigned lid = u & 255u;
        int j = cbase + (int)(lid >> 4) * 32 + (int)((lid >> 2) & 3u) * 8
              + kh * 4 + (int)(lid & 3u);
        cand_d[ob + sel] = bd[sel];
        cand_i[ob + sel] = gbase + j;
    }
}

// ---------------- merge 8 sorted runs of 8 per row -> final top-8 ----------------
__global__ __launch_bounds__(256) void knn_merge(const float* __restrict__ cand_d,
                                                 const int* __restrict__ cand_i,
                                                 int* __restrict__ nbr)
{
    const int t = threadIdx.x;
    const int row = blockIdx.x * 32 + (t >> 3);
    const int run = t & 7;
    const float* pd = cand_d + (size_t)row * 64 + run * 8;
    const int*   pi = cand_i + (size_t)row * 64 + run * 8;
    float d[8]; int ix[8];
#pragma unroll
    for (int k = 0; k < 8; ++k) { d[k] = pd[k]; ix[k] = pi[k]; }
    const float INF = __uint_as_float(0x7F800000u);
    int* op = nbr + (size_t)row * KNN;
    float hd = d[0]; int hi = ix[0];
#pragma unroll
    for (int sel = 0; sel < 8; ++sel) {
        float md = hd; int mi = hi;
#pragma unroll
        for (int m = 1; m < 8; m <<= 1) {
            float od = __shfl_xor(md, m, 8);
            int   oi = __shfl_xor(mi, m, 8);
            bool tk = (od < md) || (od == md && oi < mi);
            md = tk ? od : md; mi = tk ? oi : mi;
        }
        if (run == sel) op[sel] = mi;
        bool win = (hd == md) && (hi == mi);
        if (win) {
            d[0]=d[1]; ix[0]=ix[1]; d[1]=d[2]; ix[1]=ix[2];
            d[2]=d[3]; ix[2]=ix[3]; d[3]=d[4]; ix[3]=ix[4];
            d[4]=d[5]; ix[4]=ix[5]; d[5]=d[6]; ix[5]=ix[6];
            d[6]=d[7]; ix[6]=ix[7]; d[7]=INF;  ix[7]=0x7fffffff;
        }
        hd = d[0]; hi = ix[0];
    }
}

// ---------------- node GEMM: P = h@Wa_bot ; D = h@(Wa_top-Wa_bot) + ba ----------------
__global__ __launch_bounds__(256) void node_gemm(const unsigned short* __restrict__ hs,
                                                 const unsigned short* __restrict__ Wt,
                                                 const float* __restrict__ ba,
                                                 float* __restrict__ P,
                                                 float* __restrict__ D)
{
    __shared__ char lds[32768];
    const size_t plane = (size_t)NTOT * HD;
    const int t = threadIdx.x, wv = t >> 6, lane = t & 63;
    const int lrow = lane & 15, kg = lane >> 4;
    const int nodebase = blockIdx.x * 64 + wv * 16;

    const unsigned short* arow = hs + (size_t)(nodebase + lrow) * HD + kg * 8;
    bf16x8 A0[4], A1[4];
#pragma unroll
    for (int kc = 0; kc < 4; ++kc) {
        A0[kc] = *(const bf16x8*)(arow + kc * 32);
        A1[kc] = *(const bf16x8*)(arow + plane + kc * 32);
    }

    char* ldsw = lds + wv * 1024;
    const unsigned short* wsrc = Wt + t * 8;
#pragma unroll
    for (int i = 0; i < 4; ++i)
        GLOAD_LDS16(wsrc + i * 2048, ldsw + i * 4096);
    __syncthreads();

    int cur = 0;
    for (int cs = 0; cs < 8; ++cs) {
        if (cs < 7) {
#pragma unroll
            for (int i = 0; i < 4; ++i)
                GLOAD_LDS16(wsrc + (size_t)(cs + 1) * 12288 + i * 2048,
                            ldsw + (cur ^ 1) * 16384 + i * 4096);
        }
        const char* pb = lds + cur * 16384 + kg * 256 + lrow * 16;   // conflict-free
        f32x4 acc0 = {0.f,0.f,0.f,0.f};
        f32x4 acc1 = {0.f,0.f,0.f,0.f};
#pragma unroll
        for (int kc = 0; kc < 4; ++kc) {
            const char* pk = pb + kc * 2048;
            bf16x8 b00 = *(const bf16x8*)(pk);
            bf16x8 b01 = *(const bf16x8*)(pk + 1024);
            bf16x8 b10 = *(const bf16x8*)(pk + 8192);
            bf16x8 b11 = *(const bf16x8*)(pk + 9216);
            FOURPASS(b00, b01, b10, b11)
        }
        int n0 = cs * 32 + lrow;
        if (cs < 4) {
#pragma unroll
            for (int r = 0; r < 4; ++r) {
                size_t row = (size_t)(nodebase + kg * 4 + r) * HD;
                P[row + n0]      = acc0[r];
                P[row + n0 + 16] = acc1[r];
            }
        } else {
            float ba0 = ba[n0 - 128], ba1 = ba[n0 - 112];
#pragma unroll
            for (int r = 0; r < 4; ++r) {
                size_t row = (size_t)(nodebase + kg * 4 + r) * HD;
                D[row + n0 - 128] = acc0[r] + ba0;
                D[row + n0 - 112] = acc1[r] + ba1;
            }
        }
        __syncthreads();
        cur ^= 1;
    }
}

// ---------------- fused edge kernel: H1=relu(D[i]+P[j]) -> GEMM2 -> max -> split-out ----------------
template<bool FINAL>
__global__ __launch_bounds__(256) void edge_mlp(const float* __restrict__ P,
                                                const float* __restrict__ D,
                                                const int* __restrict__ nbr,
                                                const unsigned short* __restrict__ Wbt,
                                                const float* __restrict__ bb,
                                                const float* __restrict__ w5,
                                                unsigned short* __restrict__ hsout,
                                                float* __restrict__ sqgout,
                                                float* __restrict__ out)
{
    __shared__ char lds[32768];
    const size_t plane = (size_t)NTOT * HD;
    const int t = threadIdx.x, wv = t >> 6, lane = t & 63;
    const int lrow = lane & 15, kg = lane >> 4;
    const int nodeA = blockIdx.x * 8 + wv * 2;
    const int i_node = nodeA + (lrow >> 3);
    const int j = nbr[(size_t)i_node * KNN + (lrow & 7)];

    const float* dp = D + (size_t)i_node * HD + kg * 8;
    const float* pp = P + (size_t)j * HD + kg * 8;

    bf16x8 A0[4], A1[4];
    float sdot = 0.f;
#pragma unroll
    for (int kc = 0; kc < 4; ++kc) {
        float4 d0 = *(const float4*)(dp + kc * 32);
        float4 d1 = *(const float4*)(dp + kc * 32 + 4);
        float4 p0 = *(const float4*)(pp + kc * 32);
        float4 p1 = *(const float4*)(pp + kc * 32 + 4);
        float v[8];
        v[0]=fmaxf(d0.x+p0.x,0.f); v[1]=fmaxf(d0.y+p0.y,0.f);
        v[2]=fmaxf(d0.z+p0.z,0.f); v[3]=fmaxf(d0.w+p0.w,0.f);
        v[4]=fmaxf(d1.x+p1.x,0.f); v[5]=fmaxf(d1.y+p1.y,0.f);
        v[6]=fmaxf(d1.z+p1.z,0.f); v[7]=fmaxf(d1.w+p1.w,0.f);
        if (FINAL) {
#pragma unroll
            for (int e = 0; e < 8; ++e)
                sdot = fmaf(v[e], w5[kc * 32 + kg * 8 + e], sdot);
        } else {
#pragma unroll
            for (int e = 0; e < 8; ++e) {
                unsigned short b1 = bf16rn(v[e]); float r1 = v[e] - bf16tof(b1);
                unsigned short b2 = bf16rn(r1);
                A0[kc][e] = (short)b1; A1[kc][e] = (short)b2;
            }
        }
    }

    if (!FINAL) {
        char* ldsw = lds + wv * 1024;
        const unsigned short* wsrc = Wbt + t * 8;
#pragma unroll
        for (int i = 0; i < 4; ++i)
            GLOAD_LDS16(wsrc + i * 2048, ldsw + i * 4096);
        __syncthreads();

        const int mynode = nodeA + (kg >> 1);
        const bool writer = (kg & 1) == 0;
        float sqacc = 0.f;

        int cur = 0;
        for (int cs = 0; cs < 4; ++cs) {
            if (cs < 3) {
#pragma unroll
                for (int i = 0; i < 4; ++i)
                    GLOAD_LDS16(wsrc + (size_t)(cs + 1) * 12288 + i * 2048,
                                ldsw + (cur ^ 1) * 16384 + i * 4096);
            }
            const char* pb = lds + cur * 16384 + kg * 256 + lrow * 16;  // conflict-free
            f32x4 acc0 = {0.f,0.f,0.f,0.f};
            f32x4 acc1 = {0.f,0.f,0.f,0.f};
#pragma unroll
            for (int kc = 0; kc < 4; ++kc) {
                const char* pk = pb + kc * 2048;
                bf16x8 b00 = *(const bf16x8*)(pk);
                bf16x8 b01 = *(const bf16x8*)(pk + 1024);
                bf16x8 b10 = *(const bf16x8*)(pk + 8192);
                bf16x8 b11 = *(const bf16x8*)(pk + 9216);
                FOURPASS(b00, b01, b10, b11)
            }
            float bb0 = bb[cs * 32 + lrow];
            float bb1 = bb[cs * 32 + 16 + lrow];
            float m0 = fmaxf(fmaxf(acc0[0], acc0[1]), fmaxf(acc0[2], acc0[3]));
            float m1 = fmaxf(fmaxf(acc1[0], acc1[1]), fmaxf(acc1[2], acc1[3]));
            m0 = fmaxf(m0 + bb0, 0.f);
            m1 = fmaxf(m1 + bb1, 0.f);
            m0 = fmaxf(m0, __shfl_xor(m0, 16));
            m1 = fmaxf(m1, __shfl_xor(m1, 16));
            if (writer) {
                sqacc = fmaf(m0, m0, fmaf(m1, m1, sqacc));
                size_t base = (size_t)mynode * HD + cs * 32 + lrow;
                unsigned short c1 = bf16rn(m0); float r1 = m0 - bf16tof(c1);
                unsigned short c2 = bf16rn(r1);
                hsout[base]         = c1;
                hsout[base + plane] = c2;
                unsigned short e1 = bf16rn(m1); float s1 = m1 - bf16tof(e1);
                unsigned short e2 = bf16rn(s1);
                hsout[base + 16]         = e1;
                hsout[base + 16 + plane] = e2;
            }
            __syncthreads();
            cur ^= 1;
        }
        if (writer) {
#pragma unroll
            for (int m = 1; m < 16; m <<= 1)
                sqacc += __shfl_xor(sqacc, m, 16);
            if (lrow == 0) sqgout[mynode] = sqacc;
        }
    } else {
        sdot += __shfl_xor(sdot, 16);
        sdot += __shfl_xor(sdot, 32);
        float s = fmaxf(sdot + bb[0], 0.f);
#pragma unroll
        for (int m = 1; m < 8; m <<= 1)
            s = fmaxf(s, __shfl_xor(s, m));
        if (lane == 0) out[nodeA]     = 1.f / (1.f + expf(-s));
        if (lane == 8) out[nodeA + 1] = 1.f / (1.f + expf(-s));
    }
}

extern "C" void kernel_launch(void* const* d_in, const int* in_sizes, int n_in,
                              void* d_out, int out_size, void* d_ws, size_t ws_size,
                              hipStream_t stream) {
    const float* x     = (const float*)d_in[0];
    const float* W_enc = (const float*)d_in[3];
    const float* b_enc = (const float*)d_in[4];
    const float* W1a = (const float*)d_in[5];
    const float* b1a = (const float*)d_in[6];
    const float* W1b = (const float*)d_in[7];
    const float* b1b = (const float*)d_in[8];
    const float* W2a = (const float*)d_in[9];
    const float* b2a = (const float*)d_in[10];
    const float* W2b = (const float*)d_in[11];
    const float* b2b = (const float*)d_in[12];
    const float* W5a = (const float*)d_in[13];
    const float* b5a = (const float*)d_in[14];
    const float* W5b = (const float*)d_in[15];
    const float* b5b = (const float*)d_in[16];

    unsigned short* hs = (unsigned short*)d_ws;                  // 16 MB (2 planes)
    float* sqg  = (float*)(hs + (size_t)2*NTOT*HD);              // 128 KB
    int*   idxb = (int*)(sqg + NTOT);                            // 1 MB
    float* Dbuf = (float*)(idxb + (size_t)NTOT*KNN);             // 16 MB
    float* Pbuf = Dbuf + (size_t)NTOT*HD;                        // 16 MB
    unsigned short* Wt1  = (unsigned short*)(Pbuf + (size_t)NTOT*HD);
    unsigned short* Wt2  = Wt1 + 98304;
    unsigned short* Wt5  = Wt2 + 98304;
    unsigned short* Wbt1 = Wt5 + 98304;
    unsigned short* Wbt2 = Wbt1 + 49152;

    // cand buffers (8MB + 8MB) overlay Dbuf; node_gemm writes Dbuf after merge consumed them
    float* cd = Dbuf;
    int*   ci = (int*)(Dbuf + (size_t)NTOT*64);

    prep_wcat<<<128, 256, 0, stream>>>(W1a, Wt1);
    prep_wcat<<<128, 256, 0, stream>>>(W2a, Wt2);
    prep_wcat<<<128, 256, 0, stream>>>(W5a, Wt5);
    prep_wb  <<< 64, 256, 0, stream>>>(W1b, Wbt1);
    prep_wb  <<< 64, 256, 0, stream>>>(W2b, Wbt2);

    enc_split<<<NTOT/4, 256, 0, stream>>>(x, W_enc, b_enc, hs, sqg);

    // layer 1 (hs updated in place by edge_mlp)
    knn_mfma   <<<1024, 256, 0, stream>>>(hs, sqg, cd, ci);
    knn_merge  <<<NTOT/32, 256, 0, stream>>>(cd, ci, idxb);
    node_gemm  <<<NTOT/64, 256, 0, stream>>>(hs, Wt1, b1a, Pbuf, Dbuf);
    edge_mlp<false><<<NTOT/8, 256, 0, stream>>>(Pbuf, Dbuf, idxb, Wbt1, b1b, nullptr, hs, sqg, nullptr);

    // layer 2
    knn_mfma   <<<1024, 256, 0, stream>>>(hs, sqg, cd, ci);
    knn_merge  <<<NTOT/32, 256, 0, stream>>>(cd, ci, idxb);
    node_gemm  <<<NTOT/64, 256, 0, stream>>>(hs, Wt2, b2a, Pbuf, Dbuf);
    edge_mlp<false><<<NTOT/8, 256, 0, stream>>>(Pbuf, Dbuf, idxb, Wbt2, b2b, nullptr, hs, sqg, nullptr);

    // layer 5 (final)
    knn_mfma   <<<1024, 256, 0, stream>>>(hs, sqg, cd, ci);
    knn_merge  <<<NTOT/32, 256, 0, stream>>>(cd, ci, idxb);
    node_gemm  <<<NTOT/64, 256, 0, stream>>>(hs, Wt5, b5a, Pbuf, Dbuf);
    edge_mlp<true><<<NTOT/8, 256, 0, stream>>>(Pbuf, Dbuf, idxb, nullptr, b5b, W5b, nullptr, nullptr, (float*)d_out);
}

// Round 10
// 399.286 us; speedup vs baseline: 6.2690x; 1.0742x over previous
//
#include <hip/hip_runtime.h>
#include <hip/hip_bf16.h>
#include <math.h>

#define BGR 16
#define NPG 2048
#define HD  128
#define KNN 8
#define NTOT (BGR*NPG)   // 32768

using bf16x8 = __attribute__((ext_vector_type(8))) short;
using f32x4  = __attribute__((ext_vector_type(4))) float;
using f32x16 = __attribute__((ext_vector_type(16))) float;

typedef __attribute__((address_space(3))) unsigned int lds_uint;
typedef const __attribute__((address_space(1))) unsigned int glob_uint;
#define GLOAD_LDS16(g, l) __builtin_amdgcn_global_load_lds((glob_uint*)(g), (lds_uint*)(l), 16, 0, 0)

__device__ inline unsigned short bf16rn(float f) {
    unsigned u = __float_as_uint(f);
    unsigned r = (u + 0x7FFFu + ((u >> 16) & 1u)) >> 16;
    return (unsigned short)r;
}
__device__ inline float bf16tof(unsigned short h) {
    return __uint_as_float(((unsigned)h) << 16);
}

// ---------------- fused encoder + 2-way split + sq-norm ----------------
__global__ __launch_bounds__(256) void enc_split(const float* __restrict__ x,
                                                 const float* __restrict__ W,
                                                 const float* __restrict__ bias,
                                                 unsigned short* __restrict__ hs,
                                                 float* __restrict__ sqg)
{
    const size_t plane = (size_t)NTOT * HD;
    int node = (blockIdx.x * 256 + threadIdx.x) >> 6;
    int lane = threadIdx.x & 63;
    float4 xv = *(const float4*)(x + (size_t)node * 4);
    float v0 = bias[lane], v1 = bias[lane + 64];
    const float* xf = (const float*)&xv;
#pragma unroll
    for (int f = 0; f < 4; ++f) {
        v0 = fmaf(xf[f], W[f * 128 + lane], v0);
        v1 = fmaf(xf[f], W[f * 128 + lane + 64], v1);
    }
    float s = fmaf(v0, v0, v1 * v1);
#pragma unroll
    for (int off = 32; off >= 1; off >>= 1)
        s += __shfl_xor(s, off);
    if (lane == 0) sqg[node] = s;
#pragma unroll
    for (int q = 0; q < 2; ++q) {
        float v = q ? v1 : v0;
        int   d = lane + q * 64;
        unsigned short b1 = bf16rn(v);  float r1 = v - bf16tof(b1);
        unsigned short b2 = bf16rn(r1);
        size_t base = (size_t)node * HD + d;
        hs[base]         = b1;
        hs[base + plane] = b2;
    }
}

// ---------------- weight prep ----------------
__global__ __launch_bounds__(256) void prep_wcat(const float* __restrict__ Wa,
                                                 unsigned short* __restrict__ Wt)
{
    int gid = blockIdx.x * 256 + threadIdx.x;   // 32768 = 128k x 256n
    int k = gid >> 8, n = gid & 255;
    float w;
    if (n < 128) w = Wa[(128 + k) * 128 + n];
    else { int nn = n - 128; w = Wa[k * 128 + nn] - Wa[(128 + k) * 128 + nn]; }
    unsigned short b1 = bf16rn(w);  float r1 = w - bf16tof(b1);
    unsigned short b2 = bf16rn(r1);
    int cs = n >> 5, h = (n >> 4) & 1, c = n & 15, kc = k >> 5, kg = (k >> 3) & 3, e = k & 7;
    size_t off = (size_t)cs * 12288 + kc * 1024 + h * 512 + kg * 128 + c * 8 + e;
    Wt[off] = b1; Wt[off + 4096] = b2;
}

__global__ __launch_bounds__(256) void prep_wb(const float* __restrict__ Wb,
                                               unsigned short* __restrict__ Wt)
{
    int gid = blockIdx.x * 256 + threadIdx.x;   // 16384 = 128k x 128n
    int k = gid >> 7, n = gid & 127;
    float w = Wb[k * 128 + n];
    unsigned short b1 = bf16rn(w);  float r1 = w - bf16tof(b1);
    unsigned short b2 = bf16rn(r1);
    int cs = n >> 5, h = (n >> 4) & 1, c = n & 15, kc = k >> 5, kg = (k >> 3) & 3, e = k & 7;
    size_t off = (size_t)cs * 12288 + kc * 1024 + h * 512 + kg * 128 + c * 8 + e;
    Wt[off] = b1; Wt[off + 4096] = b2;
}

// 4-pass: (A0+A1)(B0+B1) complete
#define FOURPASS(B00,B01,B10,B11) \
    acc0 = __builtin_amdgcn_mfma_f32_16x16x32_bf16(A0[kc], B00, acc0, 0, 0, 0); \
    acc1 = __builtin_amdgcn_mfma_f32_16x16x32_bf16(A0[kc], B01, acc1, 0, 0, 0); \
    acc0 = __builtin_amdgcn_mfma_f32_16x16x32_bf16(A1[kc], B00, acc0, 0, 0, 0); \
    acc1 = __builtin_amdgcn_mfma_f32_16x16x32_bf16(A1[kc], B01, acc1, 0, 0, 0); \
    acc0 = __builtin_amdgcn_mfma_f32_16x16x32_bf16(A0[kc], B10, acc0, 0, 0, 0); \
    acc1 = __builtin_amdgcn_mfma_f32_16x16x32_bf16(A0[kc], B11, acc1, 0, 0, 0); \
    acc0 = __builtin_amdgcn_mfma_f32_16x16x32_bf16(A1[kc], B10, acc0, 0, 0, 0); \
    acc1 = __builtin_amdgcn_mfma_f32_16x16x32_bf16(A1[kc], B11, acc1, 0, 0, 0);

// ---------------- kNN via 32x32x16 MFMA, 2x2-plane, SINGLE acc chain ----------------
__global__ __launch_bounds__(256, 3) void knn_mfma(const unsigned short* __restrict__ hs,
                                                   const float* __restrict__ sqg,
                                                   float* __restrict__ cand_d,
                                                   int* __restrict__ cand_i)
{
    __shared__ ulong2 ldsraw[2176];   // 32KB dbuf + 2KB sq
    char* ldsc = (char*)ldsraw;
    float* sqs = (float*)(ldsc + 32768);

    const size_t plane = (size_t)NTOT * HD;
    const int t = threadIdx.x;
    const int b = blockIdx.x;           // 1024 blocks
    const int slot = b >> 3;
    const int g  = (b & 7) | ((slot & 1) << 3);
    const int rb = (slot >> 1) & 15;
    const int cs = (slot >> 5) & 3;
    const int gbase = g * NPG;
    const int cbase = cs * 512;
    const int wv = t >> 6, lane = t & 63;
    const int rl = lane & 31, kh = lane >> 5;
    const int myrow = rb * 128 + wv * 32 + rl;

    sqs[t]       = sqg[gbase + cbase + t];
    sqs[t + 256] = sqg[gbase + cbase + 256 + t];

    // row operand (B): 2 planes, * (-2) exact via exponent+1 & sign-flip
    bf16x8 RB[2][8];
    {
        const unsigned short* rrow = hs + (size_t)(gbase + myrow) * HD + kh * 8;
#pragma unroll
        for (int p = 0; p < 2; ++p)
#pragma unroll
            for (int kch = 0; kch < 8; ++kch) {
                bf16x8 v = *(const bf16x8*)(rrow + (size_t)p * plane + kch * 16);
                unsigned* u = (unsigned*)&v;
#pragma unroll
                for (int w = 0; w < 4; ++w)
                    u[w] = (u[w] + 0x00800080u) ^ 0x80008000u;
                RB[p][kch] = v;
            }
    }
    const float sqi = sqg[gbase + myrow];

    // staging: 4 chunks of 4KB per 16KB step-buffer
    const unsigned short* sb = hs + (size_t)(gbase + cbase + (t & 31)) * HD
                             + (t >> 6) * 16 + ((t >> 5) & 1) * 8;
    char* ldsw = ldsc + wv * 1024;

#pragma unroll
    for (int i = 0; i < 4; ++i)
        GLOAD_LDS16(sb + (size_t)(i >> 1) * plane + (i & 1) * 64, ldsw + i * 4096);
    __syncthreads();

    const float INF = __uint_as_float(0x7F800000u);
    float bd[8];
#pragma unroll
    for (int s = 0; s < 8; ++s) bd[s] = INF;

    int cur = 0;
    for (int s = 0; s < 16; ++s) {
        if (s < 15) {
            const unsigned short* sbn = sb + (size_t)(s + 1) * 32 * HD;
#pragma unroll
            for (int i = 0; i < 4; ++i)
                GLOAD_LDS16(sbn + (size_t)(i >> 1) * plane + (i & 1) * 64,
                            ldsw + (cur ^ 1) * 16384 + i * 4096);
        }
        const char* pstep = ldsc + cur * 16384 + lane * 16;
        f32x16 acc = {0.f,0.f,0.f,0.f,0.f,0.f,0.f,0.f,0.f,0.f,0.f,0.f,0.f,0.f,0.f,0.f};
        __builtin_amdgcn_s_setprio(1);
#pragma unroll
        for (int kch = 0; kch < 8; ++kch) {
            bf16x8 c0 = *(const bf16x8*)(pstep + kch * 1024);
            bf16x8 c1 = *(const bf16x8*)(pstep + 8192 + kch * 1024);
            acc = __builtin_amdgcn_mfma_f32_32x32x16_bf16(c0, RB[0][kch], acc, 0, 0, 0);
            acc = __builtin_amdgcn_mfma_f32_32x32x16_bf16(c1, RB[0][kch], acc, 0, 0, 0);
            acc = __builtin_amdgcn_mfma_f32_32x32x16_bf16(c0, RB[1][kch], acc, 0, 0, 0);
            acc = __builtin_amdgcn_mfma_f32_32x32x16_bf16(c1, RB[1][kch], acc, 0, 0, 0);
        }
        __builtin_amdgcn_s_setprio(0);
        // packed-key top-8: key = (bits(sqi+sqj+acc) & ~0xFF) | (s*16+grp*4+e)
        const unsigned lidbase = (unsigned)(s << 4);
#pragma unroll
        for (int grp = 0; grp < 4; ++grp) {
            f32x4 sq4 = *(const f32x4*)(sqs + s * 32 + grp * 8 + kh * 4);
#pragma unroll
            for (int e = 0; e < 4; ++e) {
                float dp = (sqi + sq4[e]) + acc[grp * 4 + e];
                unsigned ku = (__float_as_uint(dp) & 0xFFFFFF00u)
                            | (lidbase + (unsigned)(grp * 4 + e));
                float k = __uint_as_float(ku);
                bd[7] = __builtin_amdgcn_fmed3f(bd[6], k, bd[7]);
                bd[6] = __builtin_amdgcn_fmed3f(bd[5], k, bd[6]);
                bd[5] = __builtin_amdgcn_fmed3f(bd[4], k, bd[5]);
                bd[4] = __builtin_amdgcn_fmed3f(bd[3], k, bd[4]);
                bd[3] = __builtin_amdgcn_fmed3f(bd[2], k, bd[3]);
                bd[2] = __builtin_amdgcn_fmed3f(bd[1], k, bd[2]);
                bd[1] = __builtin_amdgcn_fmed3f(bd[0], k, bd[1]);
                bd[0] = fminf(bd[0], k);
            }
        }
        __syncthreads();
        cur ^= 1;
    }

    // decode + write sorted run of 8 (row, col-half kh, slice cs)
    const size_t ob = (size_t)(gbase + myrow) * 64 + cs * 16 + kh * 8;
#pragma unroll
    for (int sel = 0; sel < 8; ++sel) {
        unsigned u = __float_as_uint(bd[sel]);
        unsigned lid = u & 255u;
        int j = cbase + (int)(lid >> 4) * 32 + (int)((lid >> 2) & 3u) * 8
              + kh * 4 + (int)(lid & 3u);
        cand_d[ob + sel] = bd[sel];
        cand_i[ob + sel] = gbase + j;
    }
}

// ---------------- merge 8 sorted runs of 8 per row -> final top-8 ----------------
__global__ __launch_bounds__(256) void knn_merge(const float* __restrict__ cand_d,
                                                 const int* __restrict__ cand_i,
                                                 int* __restrict__ nbr)
{
    const int t = threadIdx.x;
    const int row = blockIdx.x * 32 + (t >> 3);
    const int run = t & 7;
    const float* pd = cand_d + (size_t)row * 64 + run * 8;
    const int*   pi = cand_i + (size_t)row * 64 + run * 8;
    float d[8]; int ix[8];
#pragma unroll
    for (int k = 0; k < 8; ++k) { d[k] = pd[k]; ix[k] = pi[k]; }
    const float INF = __uint_as_float(0x7F800000u);
    int* op = nbr + (size_t)row * KNN;
    float hd = d[0]; int hi = ix[0];
#pragma unroll
    for (int sel = 0; sel < 8; ++sel) {
        float md = hd; int mi = hi;
#pragma unroll
        for (int m = 1; m < 8; m <<= 1) {
            float od = __shfl_xor(md, m, 8);
            int   oi = __shfl_xor(mi, m, 8);
            bool tk = (od < md) || (od == md && oi < mi);
            md = tk ? od : md; mi = tk ? oi : mi;
        }
        if (run == sel) op[sel] = mi;
        bool win = (hd == md) && (hi == mi);
        if (win) {
            d[0]=d[1]; ix[0]=ix[1]; d[1]=d[2]; ix[1]=ix[2];
            d[2]=d[3]; ix[2]=ix[3]; d[3]=d[4]; ix[3]=ix[4];
            d[4]=d[5]; ix[4]=ix[5]; d[5]=d[6]; ix[5]=ix[6];
            d[6]=d[7]; ix[6]=ix[7]; d[7]=INF;  ix[7]=0x7fffffff;
        }
        hd = d[0]; hi = ix[0];
    }
}

// ---------------- node GEMM: P = h@Wa_bot ; D = h@(Wa_top-Wa_bot) + ba ----------------
__global__ __launch_bounds__(256) void node_gemm(const unsigned short* __restrict__ hs,
                                                 const unsigned short* __restrict__ Wt,
                                                 const float* __restrict__ ba,
                                                 float* __restrict__ P,
                                                 float* __restrict__ D)
{
    __shared__ char lds[32768];
    const size_t plane = (size_t)NTOT * HD;
    const int t = threadIdx.x, wv = t >> 6, lane = t & 63;
    const int lrow = lane & 15, kg = lane >> 4;
    const int nodebase = blockIdx.x * 64 + wv * 16;

    const unsigned short* arow = hs + (size_t)(nodebase + lrow) * HD + kg * 8;
    bf16x8 A0[4], A1[4];
#pragma unroll
    for (int kc = 0; kc < 4; ++kc) {
        A0[kc] = *(const bf16x8*)(arow + kc * 32);
        A1[kc] = *(const bf16x8*)(arow + plane + kc * 32);
    }

    char* ldsw = lds + wv * 1024;
    const unsigned short* wsrc = Wt + t * 8;
#pragma unroll
    for (int i = 0; i < 4; ++i)
        GLOAD_LDS16(wsrc + i * 2048, ldsw + i * 4096);
    __syncthreads();

    int cur = 0;
    for (int cs = 0; cs < 8; ++cs) {
        if (cs < 7) {
#pragma unroll
            for (int i = 0; i < 4; ++i)
                GLOAD_LDS16(wsrc + (size_t)(cs + 1) * 12288 + i * 2048,
                            ldsw + (cur ^ 1) * 16384 + i * 4096);
        }
        const char* pb = lds + cur * 16384 + kg * 256 + lrow * 16;   // conflict-free
        f32x4 acc0 = {0.f,0.f,0.f,0.f};
        f32x4 acc1 = {0.f,0.f,0.f,0.f};
#pragma unroll
        for (int kc = 0; kc < 4; ++kc) {
            const char* pk = pb + kc * 2048;
            bf16x8 b00 = *(const bf16x8*)(pk);
            bf16x8 b01 = *(const bf16x8*)(pk + 1024);
            bf16x8 b10 = *(const bf16x8*)(pk + 8192);
            bf16x8 b11 = *(const bf16x8*)(pk + 9216);
            FOURPASS(b00, b01, b10, b11)
        }
        int n0 = cs * 32 + lrow;
        if (cs < 4) {
#pragma unroll
            for (int r = 0; r < 4; ++r) {
                size_t row = (size_t)(nodebase + kg * 4 + r) * HD;
                P[row + n0]      = acc0[r];
                P[row + n0 + 16] = acc1[r];
            }
        } else {
            float ba0 = ba[n0 - 128], ba1 = ba[n0 - 112];
#pragma unroll
            for (int r = 0; r < 4; ++r) {
                size_t row = (size_t)(nodebase + kg * 4 + r) * HD;
                D[row + n0 - 128] = acc0[r] + ba0;
                D[row + n0 - 112] = acc1[r] + ba1;
            }
        }
        __syncthreads();
        cur ^= 1;
    }
}

// ---------------- fused edge kernel: H1=relu(D[i]+P[j]) -> GEMM2 -> max -> split-out ----------------
template<bool FINAL>
__global__ __launch_bounds__(256) void edge_mlp(const float* __restrict__ P,
                                                const float* __restrict__ D,
                                                const int* __restrict__ nbr,
                                                const unsigned short* __restrict__ Wbt,
                                                const float* __restrict__ bb,
                                                const float* __restrict__ w5,
                                                unsigned short* __restrict__ hsout,
                                                float* __restrict__ sqgout,
                                                float* __restrict__ out)
{
    __shared__ char lds[32768];
    const size_t plane = (size_t)NTOT * HD;
    const int t = threadIdx.x, wv = t >> 6, lane = t & 63;
    const int lrow = lane & 15, kg = lane >> 4;
    const int nodeA = blockIdx.x * 8 + wv * 2;
    const int i_node = nodeA + (lrow >> 3);
    const int j = nbr[(size_t)i_node * KNN + (lrow & 7)];

    const float* dp = D + (size_t)i_node * HD + kg * 8;
    const float* pp = P + (size_t)j * HD + kg * 8;

    bf16x8 A0[4], A1[4];
    float sdot = 0.f;
#pragma unroll
    for (int kc = 0; kc < 4; ++kc) {
        float4 d0 = *(const float4*)(dp + kc * 32);
        float4 d1 = *(const float4*)(dp + kc * 32 + 4);
        float4 p0 = *(const float4*)(pp + kc * 32);
        float4 p1 = *(const float4*)(pp + kc * 32 + 4);
        float v[8];
        v[0]=fmaxf(d0.x+p0.x,0.f); v[1]=fmaxf(d0.y+p0.y,0.f);
        v[2]=fmaxf(d0.z+p0.z,0.f); v[3]=fmaxf(d0.w+p0.w,0.f);
        v[4]=fmaxf(d1.x+p1.x,0.f); v[5]=fmaxf(d1.y+p1.y,0.f);
        v[6]=fmaxf(d1.z+p1.z,0.f); v[7]=fmaxf(d1.w+p1.w,0.f);
        if (FINAL) {
#pragma unroll
            for (int e = 0; e < 8; ++e)
                sdot = fmaf(v[e], w5[kc * 32 + kg * 8 + e], sdot);
        } else {
#pragma unroll
            for (int e = 0; e < 8; ++e) {
                unsigned short b1 = bf16rn(v[e]); float r1 = v[e] - bf16tof(b1);
                unsigned short b2 = bf16rn(r1);
                A0[kc][e] = (short)b1; A1[kc][e] = (short)b2;
            }
        }
    }

    if (!FINAL) {
        char* ldsw = lds + wv * 1024;
        const unsigned short* wsrc = Wbt + t * 8;
#pragma unroll
        for (int i = 0; i < 4; ++i)
            GLOAD_LDS16(wsrc + i * 2048, ldsw + i * 4096);
        __syncthreads();

        const int mynode = nodeA + (kg >> 1);
        const bool writer = (kg & 1) == 0;
        float sqacc = 0.f;

        int cur = 0;
        for (int cs = 0; cs < 4; ++cs) {
            if (cs < 3) {
#pragma unroll
                for (int i = 0; i < 4; ++i)
                    GLOAD_LDS16(wsrc + (size_t)(cs + 1) * 12288 + i * 2048,
                                ldsw + (cur ^ 1) * 16384 + i * 4096);
            }
            const char* pb = lds + cur * 16384 + kg * 256 + lrow * 16;  // conflict-free
            f32x4 acc0 = {0.f,0.f,0.f,0.f};
            f32x4 acc1 = {0.f,0.f,0.f,0.f};
#pragma unroll
            for (int kc = 0; kc < 4; ++kc) {
                const char* pk = pb + kc * 2048;
                bf16x8 b00 = *(const bf16x8*)(pk);
                bf16x8 b01 = *(const bf16x8*)(pk + 1024);
                bf16x8 b10 = *(const bf16x8*)(pk + 8192);
                bf16x8 b11 = *(const bf16x8*)(pk + 9216);
                FOURPASS(b00, b01, b10, b11)
            }
            float bb0 = bb[cs * 32 + lrow];
            float bb1 = bb[cs * 32 + 16 + lrow];
            float m0 = fmaxf(fmaxf(acc0[0], acc0[1]), fmaxf(acc0[2], acc0[3]));
            float m1 = fmaxf(fmaxf(acc1[0], acc1[1]), fmaxf(acc1[2], acc1[3]));
            m0 = fmaxf(m0 + bb0, 0.f);
            m1 = fmaxf(m1 + bb1, 0.f);
            m0 = fmaxf(m0, __shfl_xor(m0, 16));
            m1 = fmaxf(m1, __shfl_xor(m1, 16));
            if (writer) {
                sqacc = fmaf(m0, m0, fmaf(m1, m1, sqacc));
                size_t base = (size_t)mynode * HD + cs * 32 + lrow;
                unsigned short c1 = bf16rn(m0); float r1 = m0 - bf16tof(c1);
                unsigned short c2 = bf16rn(r1);
                hsout[base]         = c1;
                hsout[base + plane] = c2;
                unsigned short e1 = bf16rn(m1); float s1 = m1 - bf16tof(e1);
                unsigned short e2 = bf16rn(s1);
                hsout[base + 16]         = e1;
                hsout[base + 16 + plane] = e2;
            }
            __syncthreads();
            cur ^= 1;
        }
        if (writer) {
#pragma unroll
            for (int m = 1; m < 16; m <<= 1)
                sqacc += __shfl_xor(sqacc, m, 16);
            if (lrow == 0) sqgout[mynode] = sqacc;
        }
    } else {
        sdot += __shfl_xor(sdot, 16);
        sdot += __shfl_xor(sdot, 32);
        float s = fmaxf(sdot + bb[0], 0.f);
#pragma unroll
        for (int m = 1; m < 8; m <<= 1)
            s = fmaxf(s, __shfl_xor(s, m));
        if (lane == 0) out[nodeA]     = 1.f / (1.f + expf(-s));
        if (lane == 8) out[nodeA + 1] = 1.f / (1.f + expf(-s));
    }
}

extern "C" void kernel_launch(void* const* d_in, const int* in_sizes, int n_in,
                              void* d_out, int out_size, void* d_ws, size_t ws_size,
                              hipStream_t stream) {
    const float* x     = (const float*)d_in[0];
    const float* W_enc = (const float*)d_in[3];
    const float* b_enc = (const float*)d_in[4];
    const float* W1a = (const float*)d_in[5];
    const float* b1a = (const float*)d_in[6];
    const float* W1b = (const float*)d_in[7];
    const float* b1b = (const float*)d_in[8];
    const float* W2a = (const float*)d_in[9];
    const float* b2a = (const float*)d_in[10];
    const float* W2b = (const float*)d_in[11];
    const float* b2b = (const float*)d_in[12];
    const float* W5a = (const float*)d_in[13];
    const float* b5a = (const float*)d_in[14];
    const float* W5b = (const float*)d_in[15];
    const float* b5b = (const float*)d_in[16];

    unsigned short* hs = (unsigned short*)d_ws;                  // 16 MB (2 planes)
    float* sqg  = (float*)(hs + (size_t)2*NTOT*HD);              // 128 KB
    int*   idxb = (int*)(sqg + NTOT);                            // 1 MB
    float* Dbuf = (float*)(idxb + (size_t)NTOT*KNN);             // 16 MB
    float* Pbuf = Dbuf + (size_t)NTOT*HD;                        // 16 MB
    unsigned short* Wt1  = (unsigned short*)(Pbuf + (size_t)NTOT*HD);
    unsigned short* Wt2  = Wt1 + 98304;
    unsigned short* Wt5  = Wt2 + 98304;
    unsigned short* Wbt1 = Wt5 + 98304;
    unsigned short* Wbt2 = Wbt1 + 49152;

    // cand buffers (8MB + 8MB) overlay Dbuf; node_gemm writes Dbuf after merge consumed them
    float* cd = Dbuf;
    int*   ci = (int*)(Dbuf + (size_t)NTOT*64);

    prep_wcat<<<128, 256, 0, stream>>>(W1a, Wt1);
    prep_wcat<<<128, 256, 0, stream>>>(W2a, Wt2);
    prep_wcat<<<128, 256, 0, stream>>>(W5a, Wt5);
    prep_wb  <<< 64, 256, 0, stream>>>(W1b, Wbt1);
    prep_wb  <<< 64, 256, 0, stream>>>(W2b, Wbt2);

    enc_split<<<NTOT/4, 256, 0, stream>>>(x, W_enc, b_enc, hs, sqg);

    // layer 1 (hs updated in place by edge_mlp)
    knn_mfma   <<<1024, 256, 0, stream>>>(hs, sqg, cd, ci);
    knn_merge  <<<NTOT/32, 256, 0, stream>>>(cd, ci, idxb);
    node_gemm  <<<NTOT/64, 256, 0, stream>>>(hs, Wt1, b1a, Pbuf, Dbuf);
    edge_mlp<false><<<NTOT/8, 256, 0, stream>>>(Pbuf, Dbuf, idxb, Wbt1, b1b, nullptr, hs, sqg, nullptr);

    // layer 2
    knn_mfma   <<<1024, 256, 0, stream>>>(hs, sqg, cd, ci);
    knn_merge  <<<NTOT/32, 256, 0, stream>>>(cd, ci, idxb);
    node_gemm  <<<NTOT/64, 256, 0, stream>>>(hs, Wt2, b2a, Pbuf, Dbuf);
    edge_mlp<false><<<NTOT/8, 256, 0, stream>>>(Pbuf, Dbuf, idxb, Wbt2, b2b, nullptr, hs, sqg, nullptr);

    // layer 5 (final)
    knn_mfma   <<<1024, 256, 0, stream>>>(hs, sqg, cd, ci);
    knn_merge  <<<NTOT/32, 256, 0, stream>>>(cd, ci, idxb);
    node_gemm  <<<NTOT/64, 256, 0, stream>>>(hs, Wt5, b5a, Pbuf, Dbuf);
    edge_mlp<true><<<NTOT/8, 256, 0, stream>>>(Pbuf, Dbuf, idxb, nullptr, b5b, W5b, nullptr, nullptr, (float*)d_out);
}